// Round 9
// baseline (411.301 us; speedup 1.0000x reference)
//
#include <hip/hip_runtime.h>

#define EPS 1e-5f
#define SP 16   // stat padding stride: one float per 64B line

typedef __attribute__((ext_vector_type(4))) _Float16 h4;
typedef __attribute__((ext_vector_type(8))) _Float16 h8;
typedef __attribute__((ext_vector_type(4))) float f4;
typedef __attribute__((ext_vector_type(4))) unsigned int u4;

// ---- workspace float offsets. Stat arrays are SP-strided.
#define WS_SB1        0
#define WS_SB2        128
#define WS_STAT_C1    256
#define WS_STAT_QKV0  2304
#define WS_STAT_QKV1  6400
#define WS_STAT_SIM0  10496
#define WS_STAT_SIM1  10880
#define WS_STAT_OUT0  11264
#define WS_STAT_OUT1  15360
#define WS_STAT_C2    19456
#define WS_STAT_END   21504

// ---- buffer regions (float offsets) ----
#define WS_R1  32768
#define WS_R2  (WS_R1 + 8388608)
#define WS_R3  (WS_R2 + 8388608)

// ---- pass-kernel LDS byte offsets (80 KiB -> 2 blocks/CU) ----
#define L_QEA 0
#define L_KEB 32768
#define L_RET 65536
#define L_AQ  73728
#define L_AK  77824
#define L_V   73728

__device__ __forceinline__ float wred(float v) {
    #pragma unroll
    for (int off = 32; off > 0; off >>= 1) v += __shfl_down(v, off, 64);
    return v;
}

__global__ void k_prep0(const float* __restrict__ lin1, const float* __restrict__ lin2,
                        const float* __restrict__ latent, float* __restrict__ ws) {
    int t = threadIdx.x;
    for (int i = 256 + t; i < WS_STAT_END; i += 256) ws[i] = 0.f;
    const float* lin = (t < 128) ? lin1 : lin2;
    int row = t & 127;
    float s = 0.f;
    for (int l = 0; l < 256; ++l) s += lin[row * 256 + l] * latent[l];
    ws[(t < 128 ? WS_SB1 : WS_SB2) + row] = s;
}

__global__ __launch_bounds__(256) void k_conv1(const float* __restrict__ in,
                                               const float* __restrict__ w,
                                               float* __restrict__ out) {
    __shared__ float ws_[4096];
    int t = threadIdx.x;
    for (int i = t; i < 4096; i += 256) ws_[i] = w[i];
    __syncthreads();
    int p  = blockIdx.x * 256 + t;
    int b  = p >> 14, hw = p & 16383;
    const float* ip = in + b * 64 * 16384 + hw;
    float x[64];
    #pragma unroll
    for (int c = 0; c < 64; ++c) x[c] = ip[c * 16384];
    float* op = out + b * 64 * 16384 + hw;
    for (int o = 0; o < 64; ++o) {
        float acc = 0.f;
        #pragma unroll
        for (int c = 0; c < 64; ++c) acc += ws_[o * 64 + c] * x[c];
        op[o * 16384] = acc;
    }
}

// f32 per-channel stats over [M][C][K]; SP-strided output (out0 only)
__global__ void k_stats(const float* __restrict__ src, int C, int logK, int MK, int split,
                        float* __restrict__ stat) {
    int c = blockIdx.x % C;
    int chunk = blockIdx.x / C;
    int per = MK / split;
    int base = chunk * per;
    int Km1 = (1 << logK) - 1;
    float s = 0.f, ss = 0.f;
    for (int i = base + threadIdx.x; i < base + per; i += blockDim.x) {
        int m = i >> logK, k = i & Km1;
        float v = src[((m * C + c) << logK) + k];
        s += v; ss += v * v;
    }
    s = wred(s); ss = wred(ss);
    if ((threadIdx.x & 63) == 0) { atomicAdd(&stat[c * SP], s); atomicAdd(&stat[(C + c) * SP], ss); }
}

// out0[b][c][h][w] -> t1t[b][w][c][h], inline cbn1 coef + prelu
__global__ __launch_bounds__(256) void k_t1t(const float* __restrict__ src, float* __restrict__ dst,
                                             const float* __restrict__ ws,
                                             const float* __restrict__ g1,
                                             const float* __restrict__ b1,
                                             const float* __restrict__ prelu1) {
    __shared__ float tile[32][33];
    int bid = blockIdx.x;
    int wt = bid & 3, ht = (bid >> 2) & 3, c = (bid >> 4) & 63, b = bid >> 10;
    float mean = ws[WS_STAT_C1 + c * SP] * (1.f / 65536.f);
    float var  = ws[WS_STAT_C1 + (64 + c) * SP] * (1.f / 65536.f) - mean * mean;
    float ab = g1[c] * rsqrtf(var + EPS);
    float sc = ws[WS_SB1 + c], bi = ws[WS_SB1 + 64 + c];
    float A = sc * ab;
    float Bb = sc * (b1[c] - mean * ab) + bi;
    float slope = *prelu1;
    int tx = threadIdx.x & 31, ty = threadIdx.x >> 5;
    const float* sp = src + ((b * 64 + c) * 128 + ht * 32) * 128 + wt * 32;
    for (int r = 0; r < 4; ++r) {
        float v = sp[(ty + r * 8) * 128 + tx];
        v = A * v + Bb;
        v = v >= 0.f ? v : slope * v;
        tile[ty + r * 8][tx] = v;
    }
    __syncthreads();
    float* dp = dst + b * 1048576 + (wt * 32) * 8192 + c * 128 + ht * 32;
    for (int r = 0; r < 4; ++r)
        dp[(ty + r * 8) * 8192 + tx] = tile[tx][ty + r * 8];
}

// MFMA qkv GEMM + fused SP-padded stats (from f32 acc); XCD-swizzled n
__global__ __launch_bounds__(256) void k_qkvm(const float* __restrict__ x, const float* __restrict__ w,
                                              _Float16* __restrict__ out, float* __restrict__ statq,
                                              int SB, int SR, int SC) {
    __shared__ __align__(16) _Float16 Wh[8192];
    __shared__ __align__(16) _Float16 Xt[8192];
    int t = threadIdx.x;
    int lane = t & 63, wv = t >> 6;
    int l15 = lane & 15, g4 = lane >> 4;
    int n = (blockIdx.x & 7) * 64 + (blockIdx.x >> 3);   // XCD swizzle (512 blocks)
    int b = n >> 7, r = n & 127;
    for (int i = t; i < 8192; i += 256) {
        int o = i >> 6, c = i & 63;
        Wh[o * 64 + (c ^ ((o & 7) << 3))] = (_Float16)w[i];
    }
    const float* xp = x + b * SB + r * SR;
    for (int i = t; i < 8192; i += 256) {
        int c = i >> 7, a = i & 127;
        Xt[a * 64 + (c ^ ((a & 7) << 3))] = (_Float16)xp[c * SC + a];
    }
    __syncthreads();
    _Float16* op = out + n * 16384;
    float sA[2][4] = {{0.f,0.f,0.f,0.f},{0.f,0.f,0.f,0.f}};
    float qA[2][4] = {{0.f,0.f,0.f,0.f},{0.f,0.f,0.f,0.f}};
    #pragma unroll
    for (int ot2 = 0; ot2 < 2; ++ot2) {
        int orow = (wv * 2 + ot2) * 16 + l15;
        h8 af[2];
        #pragma unroll
        for (int kk = 0; kk < 2; ++kk)
            af[kk] = *(const h8*)&Wh[orow * 64 + ((kk * 32 + g4 * 8) ^ ((orow & 7) << 3))];
        #pragma unroll
        for (int at = 0; at < 8; ++at) {
            int arow = at * 16 + l15;
            f4 c4 = {0.f, 0.f, 0.f, 0.f};
            #pragma unroll
            for (int kk = 0; kk < 2; ++kk) {
                h8 bf = *(const h8*)&Xt[arow * 64 + ((kk * 32 + g4 * 8) ^ ((arow & 7) << 3))];
                c4 = __builtin_amdgcn_mfma_f32_16x16x32_f16(af[kk], bf, c4, 0, 0, 0);
            }
            #pragma unroll
            for (int r4 = 0; r4 < 4; ++r4) {
                int o = (wv * 2 + ot2) * 16 + g4 * 4 + r4;
                float v = c4[r4];
                op[o * 128 + at * 16 + l15] = (_Float16)v;
                sA[ot2][r4] += v; qA[ot2][r4] += v * v;
            }
        }
    }
    #pragma unroll
    for (int ot2 = 0; ot2 < 2; ++ot2)
        #pragma unroll
        for (int r4 = 0; r4 < 4; ++r4) {
            float s = sA[ot2][r4], ss = qA[ot2][r4];
            #pragma unroll
            for (int msk = 1; msk < 16; msk <<= 1) {
                s += __shfl_xor(s, msk, 64); ss += __shfl_xor(ss, msk, 64);
            }
            if (l15 == 0) {
                int o = (wv * 2 + ot2) * 16 + g4 * 4 + r4;
                atomicAdd(&statq[o * SP], s);
                atomicAdd(&statq[(128 + o) * SP], ss);
            }
        }
}

// ---- pass helpers (512 threads) ----
__device__ __forceinline__ void stage_aqk(unsigned char* L, const _Float16* qkv,
                                          const float* statq, const float* qg, const float* qb,
                                          int n, int g, int t) {
    const _Float16* qp = qkv + n * 16384 + g * 32 * 128;
    #pragma unroll
    for (int k = 0; k < 4; ++k) {
        int i = t + k * 512;
        int a = i & 127, cc = i >> 7;
        int ch = g * 32 + cc;
        float mean = statq[ch * SP] * (1.f / 65536.f);
        float var  = statq[(128 + ch) * SP] * (1.f / 65536.f) - mean * mean;
        float A = qg[ch] * rsqrtf(var + EPS);
        float B = qb[ch] - mean * A;
        float v = A * (float)qp[cc * 128 + a] + B;
        _Float16 h = (_Float16)v;
        int off = a * 32 + ((cc * 2) ^ ((a & 4) << 2));
        *(_Float16*)(L + L_AQ + off) = (cc < 8) ? h : (_Float16)0.f;
        *(_Float16*)(L + L_AK + off) = (cc < 8) ? (_Float16)0.f : h;
    }
}

__device__ __forceinline__ void stage_ret(unsigned char* L, const float* remb, int crow0, int t) {
    #pragma unroll
    for (int k = 0; k < 8; ++k) {
        int i = t + k * 512;
        int d = i & 255, c = i >> 8;
        float v = (d < 255) ? remb[(crow0 + c) * 255 + d] : 0.f;
        *(_Float16*)(L + L_RET + d * 32 + ((c * 2) ^ ((d & 4) << 2))) = (_Float16)v;
    }
}

template <bool STATS>
__device__ __forceinline__ void build_emb(unsigned char* L, int w, int l15, int g4, float* s) {
    int at = w;
    int arow = at * 16 + l15;
    int aoff = arow * 32 + ((g4 * 8) ^ ((arow & 4) << 2));
    h4 aq = *(const h4*)(L + L_AQ + aoff);
    h4 ak = *(const h4*)(L + L_AK + aoff);
    int abase = at * 16 + g4 * 4;
    #pragma unroll
    for (int m = 0; m < 9; ++m) {
        int drow = (at + m) * 16 + l15;
        h4 bf = *(const h4*)(L + L_RET + drow * 32 + ((g4 * 8) ^ ((drow & 4) << 2)));
        f4 z = {0.f, 0.f, 0.f, 0.f};
        f4 dq = __builtin_amdgcn_mfma_f32_16x16x16f16(aq, bf, z, 0, 0, 0);
        f4 dk = __builtin_amdgcn_mfma_f32_16x16x16f16(ak, bf, z, 0, 0, 0);
        #pragma unroll
        for (int r = 0; r < 4; ++r) {
            int a = abase + r;
            int b = 127 + a - drow;
            bool ok = (m == 0 || m == 8) ? (b >= 0 && b < 128) : true;
            if (ok) {
                int off = b * 256 + ((a * 2) ^ ((b & 7) << 4));
                *(_Float16*)(L + L_QEA + off) = (_Float16)dq[r];
                *(_Float16*)(L + L_KEB + off) = (_Float16)dk[r];
                if (STATS) {
                    s[0] += dq[r]; s[1] += dq[r] * dq[r];
                    s[2] += dk[r]; s[3] += dk[r] * dk[r];
                }
            }
        }
    }
}

__device__ __forceinline__ void qk_mfma(unsigned char* L, int i0, int l15, int g4, f4 acc[8]) {
    h8 af[4];
    #pragma unroll
    for (int ks = 0; ks < 4; ++ks) {
        int row = i0 + l15;
        af[ks] = *(const h8*)(L + L_QEA + row * 256 + ((ks * 64 + g4 * 16) ^ ((row & 7) << 4)));
    }
    #pragma unroll
    for (int tj = 0; tj < 8; ++tj) {
        h8 bf[4];
        #pragma unroll
        for (int ks = 0; ks < 4; ++ks) {
            int row = tj * 16 + l15;
            bf[ks] = *(const h8*)(L + L_KEB + row * 256 + ((ks * 64 + g4 * 16) ^ ((row & 7) << 4)));
        }
        f4 c = {0.f, 0.f, 0.f, 0.f};
        #pragma unroll
        for (int ks = 0; ks < 4; ++ks)
            c = __builtin_amdgcn_mfma_f32_16x16x32_f16(af[ks], bf[ks], c, 0, 0, 0);
        acc[tj] = c;
    }
}

__global__ __launch_bounds__(512, 4) void k_passA(const _Float16* __restrict__ qkv,
                                                  const float* __restrict__ remb,
                                                  const float* __restrict__ statq,
                                                  const float* __restrict__ qg,
                                                  const float* __restrict__ qb,
                                                  float* __restrict__ statsim) {
    __shared__ __align__(16) unsigned char L[81920];
    int t = threadIdx.x;
    int lane = t & 63, w = t >> 6;
    int l15 = lane & 15, g4 = lane >> 4;
    int s0 = (blockIdx.x & 7) * 256 + (blockIdx.x >> 3);   // XCD swizzle (2048 blocks)
    int n = s0 >> 2, g = s0 & 3;

    stage_aqk(L, qkv, statq, qg, qb, n, g, t);
    stage_ret(L, remb, 0, t);
    __syncthreads();

    float es[4] = {0.f, 0.f, 0.f, 0.f};
    build_emb<true>(L, w, l15, g4, es);
    __syncthreads();

    float* red = (float*)(L + L_AK);
    #pragma unroll
    for (int k = 0; k < 4; ++k) es[k] = wred(es[k]);
    if (lane == 0) {
        red[w * 4 + 0] = es[0]; red[w * 4 + 1] = es[1];
        red[w * 4 + 2] = es[2]; red[w * 4 + 3] = es[3];
    }

    f4 acc[8];
    qk_mfma(L, w * 16, l15, g4, acc);

    float s = 0.f, ss = 0.f;
    #pragma unroll
    for (int tj = 0; tj < 8; ++tj)
        #pragma unroll
        for (int r = 0; r < 4; ++r) { float x = acc[tj][r]; s += x; ss += x * x; }
    s = wred(s); ss = wred(ss);
    if (lane == 0) { red[32 + w * 2] = s; red[33 + w * 2] = ss; }
    __syncthreads();

    if (t < 6) {
        float v = 0.f;
        int dst;
        if (t == 0)      { for (int k = 0; k < 8; ++k) v += red[32 + 2 * k]; dst = g; }
        else if (t == 1) { for (int k = 0; k < 8; ++k) v += red[33 + 2 * k]; dst = 12 + g; }
        else if (t == 2) { for (int k = 0; k < 8; ++k) v += red[k * 4 + 0];  dst = 4 + g; }
        else if (t == 3) { for (int k = 0; k < 8; ++k) v += red[k * 4 + 1];  dst = 16 + g; }
        else if (t == 4) { for (int k = 0; k < 8; ++k) v += red[k * 4 + 2];  dst = 8 + g; }
        else             { for (int k = 0; k < 8; ++k) v += red[k * 4 + 3];  dst = 20 + g; }
        atomicAdd(&statsim[dst * SP], v);
    }
}

// passB: rebuild, combine+softmax, am+ame MFMA, LDS-staged coalesced att store, fused out-stats
__global__ __launch_bounds__(512, 4) void k_passB(const _Float16* __restrict__ qkv,
                                                  const float* __restrict__ remb,
                                                  const float* __restrict__ statq,
                                                  const float* __restrict__ qg,
                                                  const float* __restrict__ qb,
                                                  const float* __restrict__ statsim,
                                                  const float* __restrict__ simg,
                                                  const float* __restrict__ simb,
                                                  unsigned int* __restrict__ att2,
                                                  float* __restrict__ statout) {
    __shared__ __align__(16) unsigned char L[81920];
    int t = threadIdx.x;
    int lane = t & 63, w = t >> 6;
    int l15 = lane & 15, g4 = lane >> 4;
    int s0 = (blockIdx.x & 7) * 256 + (blockIdx.x >> 3);   // XCD swizzle (2048 blocks)
    int n = s0 >> 2, g = s0 & 3;

    stage_aqk(L, qkv, statq, qg, qb, n, g, t);
    stage_ret(L, remb, 0, t);
    __syncthreads();

    build_emb<false>(L, w, l15, g4, nullptr);
    __syncthreads();

    #pragma unroll
    for (int k = 0; k < 4; ++k) {
        int i = t + k * 512;
        int j = i & 127, c = i >> 7;
        int ch = g * 32 + 16 + c;
        float mean = statq[ch * SP] * (1.f / 65536.f);
        float var  = statq[(128 + ch) * SP] * (1.f / 65536.f) - mean * mean;
        float A = qg[ch] * rsqrtf(var + EPS);
        float B = qb[ch] - mean * A;
        float v = A * (float)qkv[n * 16384 + ch * 128 + j] + B;
        *(_Float16*)(L + L_V + c * 256 + ((j * 2) ^ ((c & 7) << 4))) = (_Float16)v;
    }
    #pragma unroll
    for (int k = 0; k < 8; ++k) {
        int i = t + k * 512;
        int d = i & 255, c = i >> 8;
        float v = (d < 255) ? remb[(16 + c) * 255 + d] : 0.f;
        *(_Float16*)(L + L_RET + c * 512 + ((d * 2) ^ ((c & 7) << 4))) = (_Float16)v;
    }

    int i0 = w * 16;
    f4 acc[8];
    qk_mfma(L, i0, l15, g4, acc);

    float Aqk, Aqe, Ake, Cst = 0.f;
    {
        float cnt = 1.f / 8388608.f;
        float A3[3];
        #pragma unroll
        for (int k = 0; k < 3; ++k) {
            int ch = k * 4 + g;
            float mean = statsim[ch * SP] * cnt;
            float var  = statsim[(12 + ch) * SP] * cnt - mean * mean;
            float A = simg[ch] * rsqrtf(var + EPS);
            A3[k] = A;
            Cst += simb[ch] - mean * A;
        }
        Aqk = A3[0]; Aqe = A3[1]; Ake = A3[2];
    }
    int ib = (i0 + g4 * 4) * 2;
    #pragma unroll
    for (int tj = 0; tj < 8; ++tj) {
        int j = tj * 16 + l15;
        h4 q4 = *(const h4*)(L + L_QEA + j * 256 + (ib ^ ((j & 7) << 4)));
        h4 k4 = *(const h4*)(L + L_KEB + j * 256 + (ib ^ ((j & 7) << 4)));
        #pragma unroll
        for (int r = 0; r < 4; ++r)
            acc[tj][r] = Aqk * acc[tj][r] + Aqe * (float)q4[r] + Ake * (float)k4[r] + Cst;
    }

    float inv4[4];
    #pragma unroll
    for (int r = 0; r < 4; ++r) {
        float m = acc[0][r];
        #pragma unroll
        for (int tj = 1; tj < 8; ++tj) m = fmaxf(m, acc[tj][r]);
        #pragma unroll
        for (int msk = 1; msk < 16; msk <<= 1) m = fmaxf(m, __shfl_xor(m, msk, 64));
        float s = 0.f;
        #pragma unroll
        for (int tj = 0; tj < 8; ++tj) {
            float e = __expf(acc[tj][r] - m);
            acc[tj][r] = e; s += e;
        }
        #pragma unroll
        for (int msk = 1; msk < 16; msk <<= 1) s += __shfl_xor(s, msk, 64);
        inv4[r] = 1.f / s;
    }

    _Float16 ph[4][8];
    #pragma unroll
    for (int r = 0; r < 4; ++r)
        #pragma unroll
        for (int tj = 0; tj < 8; ++tj)
            ph[r][tj] = (_Float16)(acc[tj][r] * inv4[r]);
    __syncthreads();

    #pragma unroll
    for (int r = 0; r < 4; ++r) {
        int i = i0 + g4 * 4 + r;
        int swz = (i & 7) << 4;
        #pragma unroll
        for (int tj = 0; tj < 8; ++tj) {
            int j = tj * 16 + l15;
            _Float16 h = ph[r][tj];
            *(_Float16*)(L + L_QEA + i * 256 + ((j * 2) ^ swz)) = h;
            int cl = (j >= i) ? (127 + i - j) : j;
            *(_Float16*)(L + L_KEB + i * 256 + ((cl * 2) ^ swz)) = (j >= i) ? h : (_Float16)0.f;
        }
    }
    __syncthreads();

    h8 vf[4], vef[4];
    #pragma unroll
    for (int ks = 0; ks < 4; ++ks) {
        vf[ks]  = *(const h8*)(L + L_V   + l15 * 256 + ((ks * 64 + g4 * 16) ^ ((l15 & 7) << 4)));
        vef[ks] = *(const h8*)(L + L_RET + l15 * 512 + ((ks * 64 + g4 * 16) ^ ((l15 & 7) << 4)));
    }
    int row = i0 + l15;
    int sw = (row & 7) << 4;
    f4 cam = {0.f, 0.f, 0.f, 0.f}, cae = {0.f, 0.f, 0.f, 0.f};
    #pragma unroll
    for (int ks = 0; ks < 4; ++ks) {
        h8 pf  = *(const h8*)(L + L_QEA + row * 256 + ((ks * 64 + g4 * 16) ^ sw));
        h8 plf = *(const h8*)(L + L_KEB + row * 256 + ((ks * 64 + g4 * 16) ^ sw));
        cam = __builtin_amdgcn_mfma_f32_16x16x32_f16(vf[ks],  pf,  cam, 0, 0, 0);
        cae = __builtin_amdgcn_mfma_f32_16x16x32_f16(vef[ks], plf, cae, 0, 0, 0);
    }
    __syncthreads();

    #pragma unroll
    for (int r = 0; r < 4; ++r) {
        int i = i0 + g4 * 4 + r;
        int swz = (i & 7) << 4;
        #pragma unroll
        for (int tj = 0; tj < 8; ++tj) {
            int j = tj * 16 + l15;
            int cl = (j < i) ? (i - 1 - j) : j;
            *(_Float16*)(L + L_KEB + i * 256 + ((cl * 2) ^ swz)) = (j < i) ? ph[r][tj] : (_Float16)0.f;
        }
    }
    __syncthreads();

    h8 vef2[4];
    #pragma unroll
    for (int ks = 0; ks < 4; ++ks)
        vef2[ks] = *(const h8*)(L + L_RET + l15 * 512 + ((256 + ks * 64 + g4 * 16) ^ ((l15 & 7) << 4)));
    #pragma unroll
    for (int ks = 0; ks < 4; ++ks) {
        h8 phf = *(const h8*)(L + L_KEB + row * 256 + ((ks * 64 + g4 * 16) ^ sw));
        cae = __builtin_amdgcn_mfma_f32_16x16x32_f16(vef2[ks], phf, cae, 0, 0, 0);
    }

    // stage att tile in LDS (QEA dead), then coalesced full-line copy-out
    unsigned int* attL = (unsigned int*)(L + L_QEA);
    int i = i0 + l15;
    #pragma unroll
    for (int r = 0; r < 4; ++r) {
        union { _Float16 h[2]; unsigned int u; } pk;
        pk.h[0] = (_Float16)cam[r];
        pk.h[1] = (_Float16)cae[r];
        attL[(g4 * 4 + r) * 128 + i] = pk.u;
    }

    float* sred = (float*)(L + L_KEB);
    #pragma unroll
    for (int r = 0; r < 4; ++r) {
        float sa = cam[r], qa = cam[r] * cam[r];
        float se = cae[r], qe = cae[r] * cae[r];
        #pragma unroll
        for (int msk = 1; msk < 16; msk <<= 1) {
            sa += __shfl_xor(sa, msk, 64); qa += __shfl_xor(qa, msk, 64);
            se += __shfl_xor(se, msk, 64); qe += __shfl_xor(qe, msk, 64);
        }
        if (l15 == 0) {
            int base = w * 64 + g4 * 16 + r * 4;
            sred[base + 0] = sa; sred[base + 1] = qa;
            sred[base + 2] = se; sred[base + 3] = qe;
        }
    }
    __syncthreads();

    unsigned int* ab = att2 + n * 8192 + g * 2048;
    *(u4*)(ab + t * 4) = *(const u4*)(attL + t * 4);

    if (t < 64) {
        int lc = t & 31, stat = t >> 5;
        int c = lc >> 1, s = lc & 1;
        int gg4 = c >> 2, r = c & 3;
        float v = 0.f;
        #pragma unroll
        for (int ww = 0; ww < 8; ++ww)
            v += sred[ww * 64 + gg4 * 16 + r * 4 + 2 * s + stat];
        atomicAdd(&statout[(stat * 128 + g * 32 + lc) * SP], v);
    }
}

// axial0 finish
__global__ __launch_bounds__(256) void k_finish0(const unsigned int* __restrict__ att2,
                                                 const float* __restrict__ statout,
                                                 const float* __restrict__ og,
                                                 const float* __restrict__ ob,
                                                 float* __restrict__ t2) {
    __shared__ float tile[8][32][33];
    __shared__ float cf[256];
    int t = threadIdx.x;
    if (t < 128) {
        float mean = statout[t * SP] * (1.f / 65536.f);
        float var  = statout[(128 + t) * SP] * (1.f / 65536.f) - mean * mean;
        float A = og[t] * rsqrtf(var + EPS);
        cf[t] = A;
        cf[128 + t] = ob[t] - mean * A;
    }
    __syncthreads();
    int bid = blockIdx.x;
    int wt = bid & 3, ht = (bid >> 2) & 3, cg = (bid >> 4) & 7, b = bid >> 7;
    for (int i = t; i < 8192; i += 256) {
        int h = i & 31, w = (i >> 5) & 31, cl = i >> 10;
        int c_out = cg * 8 + cl;
        int chg = (c_out >> 4) * 32 + (c_out & 15) * 2;
        int p = chg >> 1;
        union { unsigned int u; _Float16 h2[2]; } pk;
        pk.u = att2[((b * 128 + wt * 32 + w) * 64 + p) * 128 + ht * 32 + h];
        tile[cl][w][h] = cf[chg] * (float)pk.h2[0] + cf[128 + chg]
                       + cf[chg + 1] * (float)pk.h2[1] + cf[129 + chg];
    }
    __syncthreads();
    for (int i = t; i < 8192; i += 256) {
        int w = i & 31, h = (i >> 5) & 31, cl = i >> 10;
        t2[((b * 64 + cg * 8 + cl) * 128 + ht * 32 + h) * 128 + wt * 32 + w] = tile[cl][w][h];
    }
}

// conv2 fused: att2(axial1) -> BN -> avgpool -> conv -> c2o, + fused c2o stats
__global__ __launch_bounds__(256) void k_conv2f(const unsigned int* __restrict__ att2,
                                                const float* __restrict__ statout,
                                                const float* __restrict__ og,
                                                const float* __restrict__ ob,
                                                const float* __restrict__ w,
                                                float* __restrict__ out,
                                                float* __restrict__ statc2) {
    __shared__ float ws_[4096];
    __shared__ float cf[4][64];
    __shared__ float sred[2][4][64];
    int t = threadIdx.x;
    int lane = t & 63, wv = t >> 6;
    for (int i = t; i < 4096; i += 256) ws_[i] = w[i];
    if (t < 64) {
        int chg = (t >> 4) * 32 + (t & 15) * 2;
        float m0 = statout[chg * SP] * (1.f / 65536.f);
        float v0 = statout[(128 + chg) * SP] * (1.f / 65536.f) - m0 * m0;
        float A0 = og[chg] * rsqrtf(v0 + EPS);
        cf[0][t] = A0; cf[1][t] = ob[chg] - m0 * A0;
        float m1 = statout[(chg + 1) * SP] * (1.f / 65536.f);
        float v1 = statout[(129 + chg) * SP] * (1.f / 65536.f) - m1 * m1;
        float A1 = og[chg + 1] * rsqrtf(v1 + EPS);
        cf[2][t] = A1; cf[3][t] = ob[chg + 1] - m1 * A1;
    }
    __syncthreads();
    int p = blockIdx.x * 256 + t;
    int b = p >> 12, yx = p & 4095, y = yx >> 6, x = yx & 63;
    const unsigned int* ap = att2 + (b * 128 + 2 * y) * 8192 + 2 * x;
    float xc[64];
    #pragma unroll
    for (int c = 0; c < 64; ++c) {
        int pp = (c >> 4) * 16 + (c & 15);
        const unsigned int* q = ap + pp * 128;
        union { unsigned int u; _Float16 h2[2]; } a0, a1, a2, a3;
        a0.u = q[0]; a1.u = q[1]; a2.u = q[8192]; a3.u = q[8193];
        float s0 = (float)a0.h2[0] + (float)a1.h2[0] + (float)a2.h2[0] + (float)a3.h2[0];
        float s1 = (float)a0.h2[1] + (float)a1.h2[1] + (float)a2.h2[1] + (float)a3.h2[1];
        xc[c] = 0.25f * (cf[0][c] * s0 + cf[2][c] * s1) + cf[1][c] + cf[3][c];
    }
    float* op = out + b * 262144 + yx;
    for (int o = 0; o < 64; ++o) {
        float acc = 0.f;
        #pragma unroll
        for (int c = 0; c < 64; ++c) acc += ws_[o * 64 + c] * xc[c];
        op[o * 4096] = acc;
        float s = wred(acc), ss = wred(acc * acc);
        if (lane == 0) { sred[0][wv][o] = s; sred[1][wv][o] = ss; }
    }
    __syncthreads();
    if (t < 128) {
        int o = t & 63, st = t >> 6;
        float v = sred[st][0][o] + sred[st][1][o] + sred[st][2][o] + sred[st][3][o];
        atomicAdd(&statc2[(st * 64 + o) * SP], v);
    }
}

__global__ __launch_bounds__(256) void k_final(const float* __restrict__ c2out,
                                               const float* __restrict__ input,
                                               const float* __restrict__ ws,
                                               const float* __restrict__ g2,
                                               const float* __restrict__ b2,
                                               const float* __restrict__ prelu2,
                                               float* __restrict__ out) {
    int idx = blockIdx.x * 256 + threadIdx.x;
    int x = idx & 63, y = (idx >> 6) & 63, o = (idx >> 12) & 63, b = idx >> 18;
    float mean = ws[WS_STAT_C2 + o * SP] * (1.f / 16384.f);
    float var  = ws[WS_STAT_C2 + (64 + o) * SP] * (1.f / 16384.f) - mean * mean;
    float ab = g2[o] * rsqrtf(var + EPS);
    float sc = ws[WS_SB2 + o], bi = ws[WS_SB2 + 64 + o];
    float A = sc * ab;
    float B = sc * (b2[o] - mean * ab) + bi;
    float v = A * c2out[idx] + B;
    const float* ip = input + ((b * 64 + o) * 128 + 2 * y) * 128 + 2 * x;
    v += 0.25f * (ip[0] + ip[1] + ip[128] + ip[129]);
    float s = *prelu2;
    out[idx] = v >= 0.f ? v : s * v;
}

extern "C" void kernel_launch(void* const* d_in, const int* in_sizes, int n_in,
                              void* d_out, int out_size, void* d_ws, size_t ws_size,
                              hipStream_t stream) {
    const float* input    = (const float*)d_in[0];
    const float* latent   = (const float*)d_in[1];
    const float* w_in     = (const float*)d_in[2];
    const float* cbn1_g   = (const float*)d_in[3];
    const float* cbn1_b   = (const float*)d_in[4];
    const float* cbn1_lin = (const float*)d_in[5];
    const float* prelu1   = (const float*)d_in[6];
    const float* ax_qkv_w[2] = {(const float*)d_in[7],  (const float*)d_in[15]};
    const float* ax_qkv_g[2] = {(const float*)d_in[8],  (const float*)d_in[16]};
    const float* ax_qkv_b[2] = {(const float*)d_in[9],  (const float*)d_in[17]};
    const float* ax_sim_g[2] = {(const float*)d_in[10], (const float*)d_in[18]};
    const float* ax_sim_b[2] = {(const float*)d_in[11], (const float*)d_in[19]};
    const float* ax_rel[2]   = {(const float*)d_in[12], (const float*)d_in[20]};
    const float* ax_out_g[2] = {(const float*)d_in[13], (const float*)d_in[21]};
    const float* ax_out_b[2] = {(const float*)d_in[14], (const float*)d_in[22]};
    const float* w_out    = (const float*)d_in[23];
    const float* cbn2_g   = (const float*)d_in[24];
    const float* cbn2_b   = (const float*)d_in[25];
    const float* cbn2_lin = (const float*)d_in[26];
    const float* prelu2   = (const float*)d_in[27];

    float* ws    = (float*)d_ws;
    float* out0  = ws + WS_R1;
    float* t1t   = ws + WS_R1 + 4194304;
    unsigned int* att2 = (unsigned int*)(ws + WS_R1);
    _Float16* qkvh = (_Float16*)(ws + WS_R2);
    float* t23   = ws + WS_R3;   // t2 (axial0 output)
    float* c2o   = ws + WS_R3;   // reused after qkvm-axial1 consumed t2 (att2 aliases R1!)
    float* dst   = (float*)d_out;

    k_prep0<<<1, 256, 0, stream>>>(cbn1_lin, cbn2_lin, latent, ws);
    k_conv1<<<256, 256, 0, stream>>>(input, w_in, out0);
    k_stats<<<1024, 256, 0, stream>>>(out0, 64, 14, 65536, 16, ws + WS_STAT_C1);
    k_t1t<<<4096, 256, 0, stream>>>(out0, t1t, ws, cbn1_g, cbn1_b, prelu1);

    // axial 0 (n = b*128 + w, a = h)
    k_qkvm<<<512, 256, 0, stream>>>(t1t, ax_qkv_w[0], qkvh, ws + WS_STAT_QKV0,
                                    1048576, 8192, 128);
    k_passA<<<2048, 512, 0, stream>>>(qkvh, ax_rel[0], ws + WS_STAT_QKV0,
                                      ax_qkv_g[0], ax_qkv_b[0], ws + WS_STAT_SIM0);
    k_passB<<<2048, 512, 0, stream>>>(qkvh, ax_rel[0], ws + WS_STAT_QKV0,
                                      ax_qkv_g[0], ax_qkv_b[0], ws + WS_STAT_SIM0,
                                      ax_sim_g[0], ax_sim_b[0], att2, ws + WS_STAT_OUT0);
    k_finish0<<<512, 256, 0, stream>>>(att2, ws + WS_STAT_OUT0, ax_out_g[0], ax_out_b[0], t23);

    // axial 1 (n = b*128 + h, a = w)
    k_qkvm<<<512, 256, 0, stream>>>(t23, ax_qkv_w[1], qkvh, ws + WS_STAT_QKV1,
                                    1048576, 128, 16384);
    k_passA<<<2048, 512, 0, stream>>>(qkvh, ax_rel[1], ws + WS_STAT_QKV1,
                                      ax_qkv_g[1], ax_qkv_b[1], ws + WS_STAT_SIM1);
    k_passB<<<2048, 512, 0, stream>>>(qkvh, ax_rel[1], ws + WS_STAT_QKV1,
                                      ax_qkv_g[1], ax_qkv_b[1], ws + WS_STAT_SIM1,
                                      ax_sim_g[1], ax_sim_b[1], att2, ws + WS_STAT_OUT1);

    // tail: fused finish1+pool+conv2+stats, then cbn2+residual+prelu
    k_conv2f<<<64, 256, 0, stream>>>(att2, ws + WS_STAT_OUT1, ax_out_g[1], ax_out_b[1],
                                     w_out, c2o, ws + WS_STAT_C2);
    k_final<<<4096, 256, 0, stream>>>(c2o, input, ws, cbn2_g, cbn2_b, prelu2, dst);
}

// Round 10
// 350.649 us; speedup vs baseline: 1.1730x; 1.1730x over previous
//
#include <hip/hip_runtime.h>

#define EPS 1e-5f
#define SP 16   // stat padding stride: one float per 64B line

typedef __attribute__((ext_vector_type(4))) _Float16 h4;
typedef __attribute__((ext_vector_type(8))) _Float16 h8;
typedef __attribute__((ext_vector_type(4))) float f4;
typedef __attribute__((ext_vector_type(4))) unsigned int u4;

// ---- workspace float offsets. Stat arrays are SP-strided.
#define WS_SB1        0
#define WS_SB2        128
#define WS_STAT_C1    256
#define WS_STAT_QKV0  2304
#define WS_STAT_QKV1  6400
#define WS_STAT_SIM0  10496
#define WS_STAT_SIM1  10880
#define WS_STAT_OUT0  11264
#define WS_STAT_OUT1  15360
#define WS_STAT_C2    19456
#define WS_STAT_END   21504

// ---- buffer regions (float offsets) ----
#define WS_R1  32768
#define WS_R2  (WS_R1 + 8388608)
#define WS_R3  (WS_R2 + 8388608)

// sim-stat sample count: n % 4 == 0 -> 128 n * 16384 elems
#define SIM_CNT_INV (1.f / 2097152.f)

// ---- pass-kernel LDS byte offsets (80 KiB -> 2 blocks/CU) ----
#define L_QEA 0
#define L_KEB 32768
#define L_RET 65536
#define L_AQ  73728
#define L_AK  77824
#define L_V   73728

__device__ __forceinline__ float wred(float v) {
    #pragma unroll
    for (int off = 32; off > 0; off >>= 1) v += __shfl_down(v, off, 64);
    return v;
}

__global__ void k_prep0(const float* __restrict__ lin1, const float* __restrict__ lin2,
                        const float* __restrict__ latent, float* __restrict__ ws) {
    int t = threadIdx.x;
    for (int i = 256 + t; i < WS_STAT_END; i += 256) ws[i] = 0.f;
    const float* lin = (t < 128) ? lin1 : lin2;
    int row = t & 127;
    float s = 0.f;
    for (int l = 0; l < 256; ++l) s += lin[row * 256 + l] * latent[l];
    ws[(t < 128 ? WS_SB1 : WS_SB2) + row] = s;
}

__global__ __launch_bounds__(256) void k_conv1(const float* __restrict__ in,
                                               const float* __restrict__ w,
                                               float* __restrict__ out) {
    __shared__ float ws_[4096];
    int t = threadIdx.x;
    for (int i = t; i < 4096; i += 256) ws_[i] = w[i];
    __syncthreads();
    int p  = blockIdx.x * 256 + t;
    int b  = p >> 14, hw = p & 16383;
    const float* ip = in + b * 64 * 16384 + hw;
    float x[64];
    #pragma unroll
    for (int c = 0; c < 64; ++c) x[c] = ip[c * 16384];
    float* op = out + b * 64 * 16384 + hw;
    for (int o = 0; o < 64; ++o) {
        float acc = 0.f;
        #pragma unroll
        for (int c = 0; c < 64; ++c) acc += ws_[o * 64 + c] * x[c];
        op[o * 16384] = acc;
    }
}

// f32 per-channel stats over [M][C][K]; SP-strided output (out0 only)
__global__ void k_stats(const float* __restrict__ src, int C, int logK, int MK, int split,
                        float* __restrict__ stat) {
    int c = blockIdx.x % C;
    int chunk = blockIdx.x / C;
    int per = MK / split;
    int base = chunk * per;
    int Km1 = (1 << logK) - 1;
    float s = 0.f, ss = 0.f;
    for (int i = base + threadIdx.x; i < base + per; i += blockDim.x) {
        int m = i >> logK, k = i & Km1;
        float v = src[((m * C + c) << logK) + k];
        s += v; ss += v * v;
    }
    s = wred(s); ss = wred(ss);
    if ((threadIdx.x & 63) == 0) { atomicAdd(&stat[c * SP], s); atomicAdd(&stat[(C + c) * SP], ss); }
}

// out0[b][c][h][w] -> t1t[b][w][c][h], inline cbn1 coef + prelu
__global__ __launch_bounds__(256) void k_t1t(const float* __restrict__ src, float* __restrict__ dst,
                                             const float* __restrict__ ws,
                                             const float* __restrict__ g1,
                                             const float* __restrict__ b1,
                                             const float* __restrict__ prelu1) {
    __shared__ float tile[32][33];
    int bid = blockIdx.x;
    int wt = bid & 3, ht = (bid >> 2) & 3, c = (bid >> 4) & 63, b = bid >> 10;
    float mean = ws[WS_STAT_C1 + c * SP] * (1.f / 65536.f);
    float var  = ws[WS_STAT_C1 + (64 + c) * SP] * (1.f / 65536.f) - mean * mean;
    float ab = g1[c] * rsqrtf(var + EPS);
    float sc = ws[WS_SB1 + c], bi = ws[WS_SB1 + 64 + c];
    float A = sc * ab;
    float Bb = sc * (b1[c] - mean * ab) + bi;
    float slope = *prelu1;
    int tx = threadIdx.x & 31, ty = threadIdx.x >> 5;
    const float* sp = src + ((b * 64 + c) * 128 + ht * 32) * 128 + wt * 32;
    for (int r = 0; r < 4; ++r) {
        float v = sp[(ty + r * 8) * 128 + tx];
        v = A * v + Bb;
        v = v >= 0.f ? v : slope * v;
        tile[ty + r * 8][tx] = v;
    }
    __syncthreads();
    float* dp = dst + b * 1048576 + (wt * 32) * 8192 + c * 128 + ht * 32;
    for (int r = 0; r < 4; ++r)
        dp[(ty + r * 8) * 8192 + tx] = tile[tx][ty + r * 8];
}

// MFMA qkv GEMM + fused SP-padded stats (from f32 acc); XCD-swizzled n
__global__ __launch_bounds__(256) void k_qkvm(const float* __restrict__ x, const float* __restrict__ w,
                                              _Float16* __restrict__ out, float* __restrict__ statq,
                                              int SB, int SR, int SC) {
    __shared__ __align__(16) _Float16 Wh[8192];
    __shared__ __align__(16) _Float16 Xt[8192];
    int t = threadIdx.x;
    int lane = t & 63, wv = t >> 6;
    int l15 = lane & 15, g4 = lane >> 4;
    int n = (blockIdx.x & 7) * 64 + (blockIdx.x >> 3);   // XCD swizzle (512 blocks)
    int b = n >> 7, r = n & 127;
    for (int i = t; i < 8192; i += 256) {
        int o = i >> 6, c = i & 63;
        Wh[o * 64 + (c ^ ((o & 7) << 3))] = (_Float16)w[i];
    }
    const float* xp = x + b * SB + r * SR;
    for (int i = t; i < 8192; i += 256) {
        int c = i >> 7, a = i & 127;
        Xt[a * 64 + (c ^ ((a & 7) << 3))] = (_Float16)xp[c * SC + a];
    }
    __syncthreads();
    _Float16* op = out + n * 16384;
    float sA[2][4] = {{0.f,0.f,0.f,0.f},{0.f,0.f,0.f,0.f}};
    float qA[2][4] = {{0.f,0.f,0.f,0.f},{0.f,0.f,0.f,0.f}};
    #pragma unroll
    for (int ot2 = 0; ot2 < 2; ++ot2) {
        int orow = (wv * 2 + ot2) * 16 + l15;
        h8 af[2];
        #pragma unroll
        for (int kk = 0; kk < 2; ++kk)
            af[kk] = *(const h8*)&Wh[orow * 64 + ((kk * 32 + g4 * 8) ^ ((orow & 7) << 3))];
        #pragma unroll
        for (int at = 0; at < 8; ++at) {
            int arow = at * 16 + l15;
            f4 c4 = {0.f, 0.f, 0.f, 0.f};
            #pragma unroll
            for (int kk = 0; kk < 2; ++kk) {
                h8 bf = *(const h8*)&Xt[arow * 64 + ((kk * 32 + g4 * 8) ^ ((arow & 7) << 3))];
                c4 = __builtin_amdgcn_mfma_f32_16x16x32_f16(af[kk], bf, c4, 0, 0, 0);
            }
            #pragma unroll
            for (int r4 = 0; r4 < 4; ++r4) {
                int o = (wv * 2 + ot2) * 16 + g4 * 4 + r4;
                float v = c4[r4];
                op[o * 128 + at * 16 + l15] = (_Float16)v;
                sA[ot2][r4] += v; qA[ot2][r4] += v * v;
            }
        }
    }
    #pragma unroll
    for (int ot2 = 0; ot2 < 2; ++ot2)
        #pragma unroll
        for (int r4 = 0; r4 < 4; ++r4) {
            float s = sA[ot2][r4], ss = qA[ot2][r4];
            #pragma unroll
            for (int msk = 1; msk < 16; msk <<= 1) {
                s += __shfl_xor(s, msk, 64); ss += __shfl_xor(ss, msk, 64);
            }
            if (l15 == 0) {
                int o = (wv * 2 + ot2) * 16 + g4 * 4 + r4;
                atomicAdd(&statq[o * SP], s);
                atomicAdd(&statq[(128 + o) * SP], ss);
            }
        }
}

// ---- pass helpers (512 threads) ----
__device__ __forceinline__ void stage_aqk(unsigned char* L, const _Float16* qkv,
                                          const float* statq, const float* qg, const float* qb,
                                          int n, int g, int t) {
    const _Float16* qp = qkv + n * 16384 + g * 32 * 128;
    #pragma unroll
    for (int k = 0; k < 4; ++k) {
        int i = t + k * 512;
        int a = i & 127, cc = i >> 7;
        int ch = g * 32 + cc;
        float mean = statq[ch * SP] * (1.f / 65536.f);
        float var  = statq[(128 + ch) * SP] * (1.f / 65536.f) - mean * mean;
        float A = qg[ch] * rsqrtf(var + EPS);
        float B = qb[ch] - mean * A;
        float v = A * (float)qp[cc * 128 + a] + B;
        _Float16 h = (_Float16)v;
        int off = a * 32 + ((cc * 2) ^ ((a & 4) << 2));
        *(_Float16*)(L + L_AQ + off) = (cc < 8) ? h : (_Float16)0.f;
        *(_Float16*)(L + L_AK + off) = (cc < 8) ? (_Float16)0.f : h;
    }
}

__device__ __forceinline__ void stage_ret(unsigned char* L, const float* remb, int crow0, int t) {
    #pragma unroll
    for (int k = 0; k < 8; ++k) {
        int i = t + k * 512;
        int d = i & 255, c = i >> 8;
        float v = (d < 255) ? remb[(crow0 + c) * 255 + d] : 0.f;
        *(_Float16*)(L + L_RET + d * 32 + ((c * 2) ^ ((d & 4) << 2))) = (_Float16)v;
    }
}

template <bool STATS>
__device__ __forceinline__ void build_emb(unsigned char* L, int w, int l15, int g4, float* s) {
    int at = w;
    int arow = at * 16 + l15;
    int aoff = arow * 32 + ((g4 * 8) ^ ((arow & 4) << 2));
    h4 aq = *(const h4*)(L + L_AQ + aoff);
    h4 ak = *(const h4*)(L + L_AK + aoff);
    int abase = at * 16 + g4 * 4;
    #pragma unroll
    for (int m = 0; m < 9; ++m) {
        int drow = (at + m) * 16 + l15;
        h4 bf = *(const h4*)(L + L_RET + drow * 32 + ((g4 * 8) ^ ((drow & 4) << 2)));
        f4 z = {0.f, 0.f, 0.f, 0.f};
        f4 dq = __builtin_amdgcn_mfma_f32_16x16x16f16(aq, bf, z, 0, 0, 0);
        f4 dk = __builtin_amdgcn_mfma_f32_16x16x16f16(ak, bf, z, 0, 0, 0);
        #pragma unroll
        for (int r = 0; r < 4; ++r) {
            int a = abase + r;
            int b = 127 + a - drow;
            bool ok = (m == 0 || m == 8) ? (b >= 0 && b < 128) : true;
            if (ok) {
                int off = b * 256 + ((a * 2) ^ ((b & 7) << 4));
                *(_Float16*)(L + L_QEA + off) = (_Float16)dq[r];
                *(_Float16*)(L + L_KEB + off) = (_Float16)dk[r];
                if (STATS) {
                    s[0] += dq[r]; s[1] += dq[r] * dq[r];
                    s[2] += dk[r]; s[3] += dk[r] * dk[r];
                }
            }
        }
    }
}

__device__ __forceinline__ void qk_mfma(unsigned char* L, int i0, int l15, int g4, f4 acc[8]) {
    h8 af[4];
    #pragma unroll
    for (int ks = 0; ks < 4; ++ks) {
        int row = i0 + l15;
        af[ks] = *(const h8*)(L + L_QEA + row * 256 + ((ks * 64 + g4 * 16) ^ ((row & 7) << 4)));
    }
    #pragma unroll
    for (int tj = 0; tj < 8; ++tj) {
        h8 bf[4];
        #pragma unroll
        for (int ks = 0; ks < 4; ++ks) {
            int row = tj * 16 + l15;
            bf[ks] = *(const h8*)(L + L_KEB + row * 256 + ((ks * 64 + g4 * 16) ^ ((row & 7) << 4)));
        }
        f4 c = {0.f, 0.f, 0.f, 0.f};
        #pragma unroll
        for (int ks = 0; ks < 4; ++ks)
            c = __builtin_amdgcn_mfma_f32_16x16x32_f16(af[ks], bf[ks], c, 0, 0, 0);
        acc[tj] = c;
    }
}

// passA (SAMPLED): 512 blocks, n = 4*(ts>>2), g = ts&3 — sim stats from 1/4 of n
__global__ __launch_bounds__(512, 4) void k_passA(const _Float16* __restrict__ qkv,
                                                  const float* __restrict__ remb,
                                                  const float* __restrict__ statq,
                                                  const float* __restrict__ qg,
                                                  const float* __restrict__ qb,
                                                  float* __restrict__ statsim) {
    __shared__ __align__(16) unsigned char L[81920];
    int t = threadIdx.x;
    int lane = t & 63, w = t >> 6;
    int l15 = lane & 15, g4 = lane >> 4;
    int ts = (blockIdx.x & 7) * 64 + (blockIdx.x >> 3);   // XCD swizzle (512 blocks)
    int n = (ts >> 2) * 4, g = ts & 3;

    stage_aqk(L, qkv, statq, qg, qb, n, g, t);
    stage_ret(L, remb, 0, t);
    __syncthreads();

    float es[4] = {0.f, 0.f, 0.f, 0.f};
    build_emb<true>(L, w, l15, g4, es);
    __syncthreads();

    float* red = (float*)(L + L_AK);
    #pragma unroll
    for (int k = 0; k < 4; ++k) es[k] = wred(es[k]);
    if (lane == 0) {
        red[w * 4 + 0] = es[0]; red[w * 4 + 1] = es[1];
        red[w * 4 + 2] = es[2]; red[w * 4 + 3] = es[3];
    }

    f4 acc[8];
    qk_mfma(L, w * 16, l15, g4, acc);

    float s = 0.f, ss = 0.f;
    #pragma unroll
    for (int tj = 0; tj < 8; ++tj)
        #pragma unroll
        for (int r = 0; r < 4; ++r) { float x = acc[tj][r]; s += x; ss += x * x; }
    s = wred(s); ss = wred(ss);
    if (lane == 0) { red[32 + w * 2] = s; red[33 + w * 2] = ss; }
    __syncthreads();

    if (t < 6) {
        float v = 0.f;
        int dst;
        if (t == 0)      { for (int k = 0; k < 8; ++k) v += red[32 + 2 * k]; dst = g; }
        else if (t == 1) { for (int k = 0; k < 8; ++k) v += red[33 + 2 * k]; dst = 12 + g; }
        else if (t == 2) { for (int k = 0; k < 8; ++k) v += red[k * 4 + 0];  dst = 4 + g; }
        else if (t == 3) { for (int k = 0; k < 8; ++k) v += red[k * 4 + 1];  dst = 16 + g; }
        else if (t == 4) { for (int k = 0; k < 8; ++k) v += red[k * 4 + 2];  dst = 8 + g; }
        else             { for (int k = 0; k < 8; ++k) v += red[k * 4 + 3];  dst = 20 + g; }
        atomicAdd(&statsim[dst * SP], v);
    }
}

// passB: rebuild, combine+softmax, am+ame MFMA, LDS-staged coalesced att store, fused out-stats
__global__ __launch_bounds__(512, 4) void k_passB(const _Float16* __restrict__ qkv,
                                                  const float* __restrict__ remb,
                                                  const float* __restrict__ statq,
                                                  const float* __restrict__ qg,
                                                  const float* __restrict__ qb,
                                                  const float* __restrict__ statsim,
                                                  const float* __restrict__ simg,
                                                  const float* __restrict__ simb,
                                                  unsigned int* __restrict__ att2,
                                                  float* __restrict__ statout) {
    __shared__ __align__(16) unsigned char L[81920];
    int t = threadIdx.x;
    int lane = t & 63, w = t >> 6;
    int l15 = lane & 15, g4 = lane >> 4;
    int s0 = (blockIdx.x & 7) * 256 + (blockIdx.x >> 3);   // XCD swizzle (2048 blocks)
    int n = s0 >> 2, g = s0 & 3;

    stage_aqk(L, qkv, statq, qg, qb, n, g, t);
    stage_ret(L, remb, 0, t);
    __syncthreads();

    build_emb<false>(L, w, l15, g4, nullptr);
    __syncthreads();

    #pragma unroll
    for (int k = 0; k < 4; ++k) {
        int i = t + k * 512;
        int j = i & 127, c = i >> 7;
        int ch = g * 32 + 16 + c;
        float mean = statq[ch * SP] * (1.f / 65536.f);
        float var  = statq[(128 + ch) * SP] * (1.f / 65536.f) - mean * mean;
        float A = qg[ch] * rsqrtf(var + EPS);
        float B = qb[ch] - mean * A;
        float v = A * (float)qkv[n * 16384 + ch * 128 + j] + B;
        *(_Float16*)(L + L_V + c * 256 + ((j * 2) ^ ((c & 7) << 4))) = (_Float16)v;
    }
    #pragma unroll
    for (int k = 0; k < 8; ++k) {
        int i = t + k * 512;
        int d = i & 255, c = i >> 8;
        float v = (d < 255) ? remb[(16 + c) * 255 + d] : 0.f;
        *(_Float16*)(L + L_RET + c * 512 + ((d * 2) ^ ((c & 7) << 4))) = (_Float16)v;
    }

    int i0 = w * 16;
    f4 acc[8];
    qk_mfma(L, i0, l15, g4, acc);

    float Aqk, Aqe, Ake, Cst = 0.f;
    {
        float A3[3];
        #pragma unroll
        for (int k = 0; k < 3; ++k) {
            int ch = k * 4 + g;
            float mean = statsim[ch * SP] * SIM_CNT_INV;
            float var  = statsim[(12 + ch) * SP] * SIM_CNT_INV - mean * mean;
            float A = simg[ch] * rsqrtf(var + EPS);
            A3[k] = A;
            Cst += simb[ch] - mean * A;
        }
        Aqk = A3[0]; Aqe = A3[1]; Ake = A3[2];
    }
    int ib = (i0 + g4 * 4) * 2;
    #pragma unroll
    for (int tj = 0; tj < 8; ++tj) {
        int j = tj * 16 + l15;
        h4 q4 = *(const h4*)(L + L_QEA + j * 256 + (ib ^ ((j & 7) << 4)));
        h4 k4 = *(const h4*)(L + L_KEB + j * 256 + (ib ^ ((j & 7) << 4)));
        #pragma unroll
        for (int r = 0; r < 4; ++r)
            acc[tj][r] = Aqk * acc[tj][r] + Aqe * (float)q4[r] + Ake * (float)k4[r] + Cst;
    }

    float inv4[4];
    #pragma unroll
    for (int r = 0; r < 4; ++r) {
        float m = acc[0][r];
        #pragma unroll
        for (int tj = 1; tj < 8; ++tj) m = fmaxf(m, acc[tj][r]);
        #pragma unroll
        for (int msk = 1; msk < 16; msk <<= 1) m = fmaxf(m, __shfl_xor(m, msk, 64));
        float s = 0.f;
        #pragma unroll
        for (int tj = 0; tj < 8; ++tj) {
            float e = __expf(acc[tj][r] - m);
            acc[tj][r] = e; s += e;
        }
        #pragma unroll
        for (int msk = 1; msk < 16; msk <<= 1) s += __shfl_xor(s, msk, 64);
        inv4[r] = 1.f / s;
    }

    _Float16 ph[4][8];
    #pragma unroll
    for (int r = 0; r < 4; ++r)
        #pragma unroll
        for (int tj = 0; tj < 8; ++tj)
            ph[r][tj] = (_Float16)(acc[tj][r] * inv4[r]);
    __syncthreads();

    #pragma unroll
    for (int r = 0; r < 4; ++r) {
        int i = i0 + g4 * 4 + r;
        int swz = (i & 7) << 4;
        #pragma unroll
        for (int tj = 0; tj < 8; ++tj) {
            int j = tj * 16 + l15;
            _Float16 h = ph[r][tj];
            *(_Float16*)(L + L_QEA + i * 256 + ((j * 2) ^ swz)) = h;
            int cl = (j >= i) ? (127 + i - j) : j;
            *(_Float16*)(L + L_KEB + i * 256 + ((cl * 2) ^ swz)) = (j >= i) ? h : (_Float16)0.f;
        }
    }
    __syncthreads();

    h8 vf[4], vef[4];
    #pragma unroll
    for (int ks = 0; ks < 4; ++ks) {
        vf[ks]  = *(const h8*)(L + L_V   + l15 * 256 + ((ks * 64 + g4 * 16) ^ ((l15 & 7) << 4)));
        vef[ks] = *(const h8*)(L + L_RET + l15 * 512 + ((ks * 64 + g4 * 16) ^ ((l15 & 7) << 4)));
    }
    int row = i0 + l15;
    int sw = (row & 7) << 4;
    f4 cam = {0.f, 0.f, 0.f, 0.f}, cae = {0.f, 0.f, 0.f, 0.f};
    #pragma unroll
    for (int ks = 0; ks < 4; ++ks) {
        h8 pf  = *(const h8*)(L + L_QEA + row * 256 + ((ks * 64 + g4 * 16) ^ sw));
        h8 plf = *(const h8*)(L + L_KEB + row * 256 + ((ks * 64 + g4 * 16) ^ sw));
        cam = __builtin_amdgcn_mfma_f32_16x16x32_f16(vf[ks],  pf,  cam, 0, 0, 0);
        cae = __builtin_amdgcn_mfma_f32_16x16x32_f16(vef[ks], plf, cae, 0, 0, 0);
    }
    __syncthreads();

    #pragma unroll
    for (int r = 0; r < 4; ++r) {
        int i = i0 + g4 * 4 + r;
        int swz = (i & 7) << 4;
        #pragma unroll
        for (int tj = 0; tj < 8; ++tj) {
            int j = tj * 16 + l15;
            int cl = (j < i) ? (i - 1 - j) : j;
            *(_Float16*)(L + L_KEB + i * 256 + ((cl * 2) ^ swz)) = (j < i) ? ph[r][tj] : (_Float16)0.f;
        }
    }
    __syncthreads();

    h8 vef2[4];
    #pragma unroll
    for (int ks = 0; ks < 4; ++ks)
        vef2[ks] = *(const h8*)(L + L_RET + l15 * 512 + ((256 + ks * 64 + g4 * 16) ^ ((l15 & 7) << 4)));
    #pragma unroll
    for (int ks = 0; ks < 4; ++ks) {
        h8 phf = *(const h8*)(L + L_KEB + row * 256 + ((ks * 64 + g4 * 16) ^ sw));
        cae = __builtin_amdgcn_mfma_f32_16x16x32_f16(vef2[ks], phf, cae, 0, 0, 0);
    }

    // stage att tile in LDS (QEA dead), then coalesced full-line copy-out
    unsigned int* attL = (unsigned int*)(L + L_QEA);
    int i = i0 + l15;
    #pragma unroll
    for (int r = 0; r < 4; ++r) {
        union { _Float16 h[2]; unsigned int u; } pk;
        pk.h[0] = (_Float16)cam[r];
        pk.h[1] = (_Float16)cae[r];
        attL[(g4 * 4 + r) * 128 + i] = pk.u;
    }

    float* sred = (float*)(L + L_KEB);
    #pragma unroll
    for (int r = 0; r < 4; ++r) {
        float sa = cam[r], qa = cam[r] * cam[r];
        float se = cae[r], qe = cae[r] * cae[r];
        #pragma unroll
        for (int msk = 1; msk < 16; msk <<= 1) {
            sa += __shfl_xor(sa, msk, 64); qa += __shfl_xor(qa, msk, 64);
            se += __shfl_xor(se, msk, 64); qe += __shfl_xor(qe, msk, 64);
        }
        if (l15 == 0) {
            int base = w * 64 + g4 * 16 + r * 4;
            sred[base + 0] = sa; sred[base + 1] = qa;
            sred[base + 2] = se; sred[base + 3] = qe;
        }
    }
    __syncthreads();

    unsigned int* ab = att2 + n * 8192 + g * 2048;
    *(u4*)(ab + t * 4) = *(const u4*)(attL + t * 4);

    if (t < 64) {
        int lc = t & 31, stat = t >> 5;
        int c = lc >> 1, s = lc & 1;
        int gg4 = c >> 2, r = c & 3;
        float v = 0.f;
        #pragma unroll
        for (int ww = 0; ww < 8; ++ww)
            v += sred[ww * 64 + gg4 * 16 + r * 4 + 2 * s + stat];
        atomicAdd(&statout[(stat * 128 + g * 32 + lc) * SP], v);
    }
}

// axial0 finish
__global__ __launch_bounds__(256) void k_finish0(const unsigned int* __restrict__ att2,
                                                 const float* __restrict__ statout,
                                                 const float* __restrict__ og,
                                                 const float* __restrict__ ob,
                                                 float* __restrict__ t2) {
    __shared__ float tile[8][32][33];
    __shared__ float cf[256];
    int t = threadIdx.x;
    if (t < 128) {
        float mean = statout[t * SP] * (1.f / 65536.f);
        float var  = statout[(128 + t) * SP] * (1.f / 65536.f) - mean * mean;
        float A = og[t] * rsqrtf(var + EPS);
        cf[t] = A;
        cf[128 + t] = ob[t] - mean * A;
    }
    __syncthreads();
    int bid = blockIdx.x;
    int wt = bid & 3, ht = (bid >> 2) & 3, cg = (bid >> 4) & 7, b = bid >> 7;
    for (int i = t; i < 8192; i += 256) {
        int h = i & 31, w = (i >> 5) & 31, cl = i >> 10;
        int c_out = cg * 8 + cl;
        int chg = (c_out >> 4) * 32 + (c_out & 15) * 2;
        int p = chg >> 1;
        union { unsigned int u; _Float16 h2[2]; } pk;
        pk.u = att2[((b * 128 + wt * 32 + w) * 64 + p) * 128 + ht * 32 + h];
        tile[cl][w][h] = cf[chg] * (float)pk.h2[0] + cf[128 + chg]
                       + cf[chg + 1] * (float)pk.h2[1] + cf[129 + chg];
    }
    __syncthreads();
    for (int i = t; i < 8192; i += 256) {
        int w = i & 31, h = (i >> 5) & 31, cl = i >> 10;
        t2[((b * 64 + cg * 8 + cl) * 128 + ht * 32 + h) * 128 + wt * 32 + w] = tile[cl][w][h];
    }
}

// conv2 fused: att2(axial1) -> BN -> avgpool -> conv -> c2o, + stats via LDS tile
// grid 256 x block 64 (was 64x256 — only 1/4 of the CUs busy)
__global__ __launch_bounds__(64) void k_conv2f(const unsigned int* __restrict__ att2,
                                               const float* __restrict__ statout,
                                               const float* __restrict__ og,
                                               const float* __restrict__ ob,
                                               const float* __restrict__ w,
                                               float* __restrict__ out,
                                               float* __restrict__ statc2) {
    __shared__ float ws_[4096];
    __shared__ float cf[4][64];
    __shared__ float otile[64][65];
    int t = threadIdx.x;
    for (int i = t; i < 4096; i += 64) ws_[i] = w[i];
    {
        int chg = (t >> 4) * 32 + (t & 15) * 2;
        float m0 = statout[chg * SP] * (1.f / 65536.f);
        float v0 = statout[(128 + chg) * SP] * (1.f / 65536.f) - m0 * m0;
        float A0 = og[chg] * rsqrtf(v0 + EPS);
        cf[0][t] = A0; cf[1][t] = ob[chg] - m0 * A0;
        float m1 = statout[(chg + 1) * SP] * (1.f / 65536.f);
        float v1 = statout[(129 + chg) * SP] * (1.f / 65536.f) - m1 * m1;
        float A1 = og[chg + 1] * rsqrtf(v1 + EPS);
        cf[2][t] = A1; cf[3][t] = ob[chg + 1] - m1 * A1;
    }
    __syncthreads();
    int p = blockIdx.x * 64 + t;           // < 16384
    int b = p >> 12, yx = p & 4095, y = yx >> 6, x = yx & 63;
    const unsigned int* ap = att2 + (b * 128 + 2 * y) * 8192 + 2 * x;
    float xc[64];
    #pragma unroll
    for (int c = 0; c < 64; ++c) {
        int pp = (c >> 4) * 16 + (c & 15);
        const unsigned int* q = ap + pp * 128;
        union { unsigned int u; _Float16 h2[2]; } a0, a1, a2, a3;
        a0.u = q[0]; a1.u = q[1]; a2.u = q[8192]; a3.u = q[8193];
        float s0 = (float)a0.h2[0] + (float)a1.h2[0] + (float)a2.h2[0] + (float)a3.h2[0];
        float s1 = (float)a0.h2[1] + (float)a1.h2[1] + (float)a2.h2[1] + (float)a3.h2[1];
        xc[c] = 0.25f * (cf[0][c] * s0 + cf[2][c] * s1) + cf[1][c] + cf[3][c];
    }
    float* op = out + b * 262144 + yx;
    for (int o = 0; o < 64; ++o) {
        float acc = 0.f;
        #pragma unroll
        for (int c = 0; c < 64; ++c) acc += ws_[o * 64 + c] * xc[c];
        op[o * 4096] = acc;
        otile[o][t] = acc;
    }
    __syncthreads();
    float s = 0.f, ss = 0.f;
    #pragma unroll
    for (int k = 0; k < 64; ++k) { float v = otile[t][k]; s += v; ss += v * v; }
    atomicAdd(&statc2[t * SP], s);
    atomicAdd(&statc2[(64 + t) * SP], ss);
}

// final: cbn2 + residual + prelu, 4x vectorized
__global__ __launch_bounds__(256) void k_final(const float* __restrict__ c2out,
                                               const float* __restrict__ input,
                                               const float* __restrict__ ws,
                                               const float* __restrict__ g2,
                                               const float* __restrict__ b2,
                                               const float* __restrict__ prelu2,
                                               float* __restrict__ out) {
    int q = blockIdx.x * 256 + threadIdx.x;   // < 262144
    int x4 = (q & 15) << 2, y = (q >> 4) & 63, o = (q >> 10) & 63, b = q >> 16;
    float mean = ws[WS_STAT_C2 + o * SP] * (1.f / 16384.f);
    float var  = ws[WS_STAT_C2 + (64 + o) * SP] * (1.f / 16384.f) - mean * mean;
    float ab = g2[o] * rsqrtf(var + EPS);
    float sc = ws[WS_SB2 + o], bi = ws[WS_SB2 + 64 + o];
    float A = sc * ab;
    float B = sc * (b2[o] - mean * ab) + bi;
    float slope = *prelu2;
    int base = ((b * 64 + o) * 64 + y) * 64 + x4;
    float4 c = *(const float4*)&c2out[base];
    const float* ip = input + ((b * 64 + o) * 128 + 2 * y) * 128 + 2 * x4;
    float4 r0a = *(const float4*)&ip[0];
    float4 r0b = *(const float4*)&ip[4];
    float4 r1a = *(const float4*)&ip[128];
    float4 r1b = *(const float4*)&ip[132];
    float4 r;
    float v0 = A * c.x + B + 0.25f * (r0a.x + r0a.y + r1a.x + r1a.y);
    float v1 = A * c.y + B + 0.25f * (r0a.z + r0a.w + r1a.z + r1a.w);
    float v2 = A * c.z + B + 0.25f * (r0b.x + r0b.y + r1b.x + r1b.y);
    float v3 = A * c.w + B + 0.25f * (r0b.z + r0b.w + r1b.z + r1b.w);
    r.x = v0 >= 0.f ? v0 : slope * v0;
    r.y = v1 >= 0.f ? v1 : slope * v1;
    r.z = v2 >= 0.f ? v2 : slope * v2;
    r.w = v3 >= 0.f ? v3 : slope * v3;
    *(float4*)&out[base] = r;
}

extern "C" void kernel_launch(void* const* d_in, const int* in_sizes, int n_in,
                              void* d_out, int out_size, void* d_ws, size_t ws_size,
                              hipStream_t stream) {
    const float* input    = (const float*)d_in[0];
    const float* latent   = (const float*)d_in[1];
    const float* w_in     = (const float*)d_in[2];
    const float* cbn1_g   = (const float*)d_in[3];
    const float* cbn1_b   = (const float*)d_in[4];
    const float* cbn1_lin = (const float*)d_in[5];
    const float* prelu1   = (const float*)d_in[6];
    const float* ax_qkv_w[2] = {(const float*)d_in[7],  (const float*)d_in[15]};
    const float* ax_qkv_g[2] = {(const float*)d_in[8],  (const float*)d_in[16]};
    const float* ax_qkv_b[2] = {(const float*)d_in[9],  (const float*)d_in[17]};
    const float* ax_sim_g[2] = {(const float*)d_in[10], (const float*)d_in[18]};
    const float* ax_sim_b[2] = {(const float*)d_in[11], (const float*)d_in[19]};
    const float* ax_rel[2]   = {(const float*)d_in[12], (const float*)d_in[20]};
    const float* ax_out_g[2] = {(const float*)d_in[13], (const float*)d_in[21]};
    const float* ax_out_b[2] = {(const float*)d_in[14], (const float*)d_in[22]};
    const float* w_out    = (const float*)d_in[23];
    const float* cbn2_g   = (const float*)d_in[24];
    const float* cbn2_b   = (const float*)d_in[25];
    const float* cbn2_lin = (const float*)d_in[26];
    const float* prelu2   = (const float*)d_in[27];

    float* ws    = (float*)d_ws;
    float* out0  = ws + WS_R1;
    float* t1t   = ws + WS_R1 + 4194304;
    unsigned int* att2 = (unsigned int*)(ws + WS_R1);
    _Float16* qkvh = (_Float16*)(ws + WS_R2);
    float* t23   = ws + WS_R3;   // t2 (axial0 output)
    float* c2o   = ws + WS_R3;   // reused after qkvm-axial1 consumed t2 (att2 aliases R1!)
    float* dst   = (float*)d_out;

    k_prep0<<<1, 256, 0, stream>>>(cbn1_lin, cbn2_lin, latent, ws);
    k_conv1<<<256, 256, 0, stream>>>(input, w_in, out0);
    k_stats<<<1024, 256, 0, stream>>>(out0, 64, 14, 65536, 16, ws + WS_STAT_C1);
    k_t1t<<<4096, 256, 0, stream>>>(out0, t1t, ws, cbn1_g, cbn1_b, prelu1);

    // axial 0 (n = b*128 + w, a = h)
    k_qkvm<<<512, 256, 0, stream>>>(t1t, ax_qkv_w[0], qkvh, ws + WS_STAT_QKV0,
                                    1048576, 8192, 128);
    k_passA<<<512, 512, 0, stream>>>(qkvh, ax_rel[0], ws + WS_STAT_QKV0,
                                     ax_qkv_g[0], ax_qkv_b[0], ws + WS_STAT_SIM0);
    k_passB<<<2048, 512, 0, stream>>>(qkvh, ax_rel[0], ws + WS_STAT_QKV0,
                                      ax_qkv_g[0], ax_qkv_b[0], ws + WS_STAT_SIM0,
                                      ax_sim_g[0], ax_sim_b[0], att2, ws + WS_STAT_OUT0);
    k_finish0<<<512, 256, 0, stream>>>(att2, ws + WS_STAT_OUT0, ax_out_g[0], ax_out_b[0], t23);

    // axial 1 (n = b*128 + h, a = w)
    k_qkvm<<<512, 256, 0, stream>>>(t23, ax_qkv_w[1], qkvh, ws + WS_STAT_QKV1,
                                    1048576, 128, 16384);
    k_passA<<<512, 512, 0, stream>>>(qkvh, ax_rel[1], ws + WS_STAT_QKV1,
                                     ax_qkv_g[1], ax_qkv_b[1], ws + WS_STAT_SIM1);
    k_passB<<<2048, 512, 0, stream>>>(qkvh, ax_rel[1], ws + WS_STAT_QKV1,
                                      ax_qkv_g[1], ax_qkv_b[1], ws + WS_STAT_SIM1,
                                      ax_sim_g[1], ax_sim_b[1], att2, ws + WS_STAT_OUT1);

    // tail: fused finish1+pool+conv2+stats, then cbn2+residual+prelu
    k_conv2f<<<256, 64, 0, stream>>>(att2, ws + WS_STAT_OUT1, ax_out_g[1], ax_out_b[1],
                                     w_out, c2o, ws + WS_STAT_C2);
    k_final<<<1024, 256, 0, stream>>>(c2o, input, ws, cbn2_g, cbn2_b, prelu2, dst);
}

// Round 11
// 335.607 us; speedup vs baseline: 1.2255x; 1.0448x over previous
//
#include <hip/hip_runtime.h>

#define EPS 1e-5f
#define SP 16   // stat padding stride: one float per 64B line

typedef __attribute__((ext_vector_type(4))) _Float16 h4;
typedef __attribute__((ext_vector_type(8))) _Float16 h8;
typedef __attribute__((ext_vector_type(4))) float f4;
typedef __attribute__((ext_vector_type(4))) unsigned int u4;

// ---- workspace float offsets. Stat arrays are SP-strided.
#define WS_SB1        0
#define WS_SB2        128
#define WS_STAT_C1    256
#define WS_STAT_QKV0  2304
#define WS_STAT_QKV1  6400
#define WS_STAT_SIM0  10496
#define WS_STAT_SIM1  10880
#define WS_STAT_OUT0  11264
#define WS_STAT_OUT1  15360
#define WS_STAT_C2    19456
#define WS_STAT_END   21504

// ---- buffer regions (float offsets) ----
#define WS_R1  32768
#define WS_R2  (WS_R1 + 8388608)
#define WS_R3  (WS_R2 + 8388608)

// sim-stat sample count: n % 4 == 0 -> 128 n * 16384 elems
#define SIM_CNT_INV (1.f / 2097152.f)

// ---- pass-kernel LDS byte offsets (80 KiB -> 2 blocks/CU) ----
// passB late phase: bytes 0..65536 become Pd [128 rows][512 B]; per-wave sred
// lives in the wave's own dead Pd rows; att tile in L_V region.
#define L_QEA 0
#define L_KEB 32768
#define L_RET 65536
#define L_AQ  73728
#define L_AK  77824
#define L_V   73728

__device__ __forceinline__ float wred(float v) {
    #pragma unroll
    for (int off = 32; off > 0; off >>= 1) v += __shfl_down(v, off, 64);
    return v;
}

__global__ void k_prep0(const float* __restrict__ lin1, const float* __restrict__ lin2,
                        const float* __restrict__ latent, float* __restrict__ ws) {
    int t = threadIdx.x;
    for (int i = 256 + t; i < WS_STAT_END; i += 256) ws[i] = 0.f;
    const float* lin = (t < 128) ? lin1 : lin2;
    int row = t & 127;
    float s = 0.f;
    for (int l = 0; l < 256; ++l) s += lin[row * 256 + l] * latent[l];
    ws[(t < 128 ? WS_SB1 : WS_SB2) + row] = s;
}

// conv1, o-split x2 (2 blocks/CU) + fused out0-stats (SP-padded atomics)
__global__ __launch_bounds__(256) void k_conv1(const float* __restrict__ in,
                                               const float* __restrict__ w,
                                               float* __restrict__ out,
                                               float* __restrict__ stat) {
    __shared__ float ws_[2048];
    __shared__ float sred[2][4][32];
    int t = threadIdx.x;
    int lane = t & 63, wv = t >> 6;
    int oh = blockIdx.x & 1;
    int pb = blockIdx.x >> 1;
    for (int i = t; i < 2048; i += 256) ws_[i] = w[oh * 2048 + i];
    __syncthreads();
    int p  = pb * 256 + t;
    int b  = p >> 14, hw = p & 16383;
    const float* ip = in + b * 64 * 16384 + hw;
    float x[64];
    #pragma unroll
    for (int c = 0; c < 64; ++c) x[c] = ip[c * 16384];
    float* op = out + b * 64 * 16384 + hw + oh * 32 * 16384;
    for (int o2 = 0; o2 < 32; ++o2) {
        float acc = 0.f;
        #pragma unroll
        for (int c = 0; c < 64; ++c) acc += ws_[o2 * 64 + c] * x[c];
        op[o2 * 16384] = acc;
        float s = wred(acc), ss = wred(acc * acc);
        if (lane == 0) { sred[0][wv][o2] = s; sred[1][wv][o2] = ss; }
    }
    __syncthreads();
    if (t < 64) {
        int o2 = t & 31, st = t >> 5;
        float v = sred[st][0][o2] + sred[st][1][o2] + sred[st][2][o2] + sred[st][3][o2];
        atomicAdd(&stat[(st * 64 + oh * 32 + o2) * SP], v);
    }
}

// out0[b][c][h][w] -> t1t[b][w][c][h], inline cbn1 coef + prelu
__global__ __launch_bounds__(256) void k_t1t(const float* __restrict__ src, float* __restrict__ dst,
                                             const float* __restrict__ ws,
                                             const float* __restrict__ g1,
                                             const float* __restrict__ b1,
                                             const float* __restrict__ prelu1) {
    __shared__ float tile[32][33];
    int bid = blockIdx.x;
    int wt = bid & 3, ht = (bid >> 2) & 3, c = (bid >> 4) & 63, b = bid >> 10;
    float mean = ws[WS_STAT_C1 + c * SP] * (1.f / 65536.f);
    float var  = ws[WS_STAT_C1 + (64 + c) * SP] * (1.f / 65536.f) - mean * mean;
    float ab = g1[c] * rsqrtf(var + EPS);
    float sc = ws[WS_SB1 + c], bi = ws[WS_SB1 + 64 + c];
    float A = sc * ab;
    float Bb = sc * (b1[c] - mean * ab) + bi;
    float slope = *prelu1;
    int tx = threadIdx.x & 31, ty = threadIdx.x >> 5;
    const float* sp = src + ((b * 64 + c) * 128 + ht * 32) * 128 + wt * 32;
    for (int r = 0; r < 4; ++r) {
        float v = sp[(ty + r * 8) * 128 + tx];
        v = A * v + Bb;
        v = v >= 0.f ? v : slope * v;
        tile[ty + r * 8][tx] = v;
    }
    __syncthreads();
    float* dp = dst + b * 1048576 + (wt * 32) * 8192 + c * 128 + ht * 32;
    for (int r = 0; r < 4; ++r)
        dp[(ty + r * 8) * 8192 + tx] = tile[tx][ty + r * 8];
}

// MFMA qkv GEMM + fused SP-padded stats (from f32 acc); XCD-swizzled n
__global__ __launch_bounds__(256) void k_qkvm(const float* __restrict__ x, const float* __restrict__ w,
                                              _Float16* __restrict__ out, float* __restrict__ statq,
                                              int SB, int SR, int SC) {
    __shared__ __align__(16) _Float16 Wh[8192];
    __shared__ __align__(16) _Float16 Xt[8192];
    int t = threadIdx.x;
    int lane = t & 63, wv = t >> 6;
    int l15 = lane & 15, g4 = lane >> 4;
    int n = (blockIdx.x & 7) * 64 + (blockIdx.x >> 3);   // XCD swizzle (512 blocks)
    int b = n >> 7, r = n & 127;
    for (int i = t; i < 8192; i += 256) {
        int o = i >> 6, c = i & 63;
        Wh[o * 64 + (c ^ ((o & 7) << 3))] = (_Float16)w[i];
    }
    const float* xp = x + b * SB + r * SR;
    for (int i = t; i < 8192; i += 256) {
        int c = i >> 7, a = i & 127;
        Xt[a * 64 + (c ^ ((a & 7) << 3))] = (_Float16)xp[c * SC + a];
    }
    __syncthreads();
    _Float16* op = out + n * 16384;
    float sA[2][4] = {{0.f,0.f,0.f,0.f},{0.f,0.f,0.f,0.f}};
    float qA[2][4] = {{0.f,0.f,0.f,0.f},{0.f,0.f,0.f,0.f}};
    #pragma unroll
    for (int ot2 = 0; ot2 < 2; ++ot2) {
        int orow = (wv * 2 + ot2) * 16 + l15;
        h8 af[2];
        #pragma unroll
        for (int kk = 0; kk < 2; ++kk)
            af[kk] = *(const h8*)&Wh[orow * 64 + ((kk * 32 + g4 * 8) ^ ((orow & 7) << 3))];
        #pragma unroll
        for (int at = 0; at < 8; ++at) {
            int arow = at * 16 + l15;
            f4 c4 = {0.f, 0.f, 0.f, 0.f};
            #pragma unroll
            for (int kk = 0; kk < 2; ++kk) {
                h8 bf = *(const h8*)&Xt[arow * 64 + ((kk * 32 + g4 * 8) ^ ((arow & 7) << 3))];
                c4 = __builtin_amdgcn_mfma_f32_16x16x32_f16(af[kk], bf, c4, 0, 0, 0);
            }
            #pragma unroll
            for (int r4 = 0; r4 < 4; ++r4) {
                int o = (wv * 2 + ot2) * 16 + g4 * 4 + r4;
                float v = c4[r4];
                op[o * 128 + at * 16 + l15] = (_Float16)v;
                sA[ot2][r4] += v; qA[ot2][r4] += v * v;
            }
        }
    }
    #pragma unroll
    for (int ot2 = 0; ot2 < 2; ++ot2)
        #pragma unroll
        for (int r4 = 0; r4 < 4; ++r4) {
            float s = sA[ot2][r4], ss = qA[ot2][r4];
            #pragma unroll
            for (int msk = 1; msk < 16; msk <<= 1) {
                s += __shfl_xor(s, msk, 64); ss += __shfl_xor(ss, msk, 64);
            }
            if (l15 == 0) {
                int o = (wv * 2 + ot2) * 16 + g4 * 4 + r4;
                atomicAdd(&statq[o * SP], s);
                atomicAdd(&statq[(128 + o) * SP], ss);
            }
        }
}

// ---- pass helpers (512 threads) ----
__device__ __forceinline__ void stage_aqk(unsigned char* L, const _Float16* qkv,
                                          const float* statq, const float* qg, const float* qb,
                                          int n, int g, int t) {
    const _Float16* qp = qkv + n * 16384 + g * 32 * 128;
    #pragma unroll
    for (int k = 0; k < 4; ++k) {
        int i = t + k * 512;
        int a = i & 127, cc = i >> 7;
        int ch = g * 32 + cc;
        float mean = statq[ch * SP] * (1.f / 65536.f);
        float var  = statq[(128 + ch) * SP] * (1.f / 65536.f) - mean * mean;
        float A = qg[ch] * rsqrtf(var + EPS);
        float B = qb[ch] - mean * A;
        float v = A * (float)qp[cc * 128 + a] + B;
        _Float16 h = (_Float16)v;
        int off = a * 32 + ((cc * 2) ^ ((a & 4) << 2));
        *(_Float16*)(L + L_AQ + off) = (cc < 8) ? h : (_Float16)0.f;
        *(_Float16*)(L + L_AK + off) = (cc < 8) ? (_Float16)0.f : h;
    }
}

__device__ __forceinline__ void stage_ret(unsigned char* L, const float* remb, int crow0, int t) {
    #pragma unroll
    for (int k = 0; k < 8; ++k) {
        int i = t + k * 512;
        int d = i & 255, c = i >> 8;
        float v = (d < 255) ? remb[(crow0 + c) * 255 + d] : 0.f;
        *(_Float16*)(L + L_RET + d * 32 + ((c * 2) ^ ((d & 4) << 2))) = (_Float16)v;
    }
}

template <bool STATS>
__device__ __forceinline__ void build_emb(unsigned char* L, int w, int l15, int g4, float* s) {
    int at = w;
    int arow = at * 16 + l15;
    int aoff = arow * 32 + ((g4 * 8) ^ ((arow & 4) << 2));
    h4 aq = *(const h4*)(L + L_AQ + aoff);
    h4 ak = *(const h4*)(L + L_AK + aoff);
    int abase = at * 16 + g4 * 4;
    #pragma unroll
    for (int m = 0; m < 9; ++m) {
        int drow = (at + m) * 16 + l15;
        h4 bf = *(const h4*)(L + L_RET + drow * 32 + ((g4 * 8) ^ ((drow & 4) << 2)));
        f4 z = {0.f, 0.f, 0.f, 0.f};
        f4 dq = __builtin_amdgcn_mfma_f32_16x16x16f16(aq, bf, z, 0, 0, 0);
        f4 dk = __builtin_amdgcn_mfma_f32_16x16x16f16(ak, bf, z, 0, 0, 0);
        #pragma unroll
        for (int r = 0; r < 4; ++r) {
            int a = abase + r;
            int b = 127 + a - drow;
            bool ok = (m == 0 || m == 8) ? (b >= 0 && b < 128) : true;
            if (ok) {
                int off = b * 256 + ((a * 2) ^ ((b & 7) << 4));
                *(_Float16*)(L + L_QEA + off) = (_Float16)dq[r];
                *(_Float16*)(L + L_KEB + off) = (_Float16)dk[r];
                if (STATS) {
                    s[0] += dq[r]; s[1] += dq[r] * dq[r];
                    s[2] += dk[r]; s[3] += dk[r] * dk[r];
                }
            }
        }
    }
}

__device__ __forceinline__ void qk_mfma(unsigned char* L, int i0, int l15, int g4, f4 acc[8]) {
    h8 af[4];
    #pragma unroll
    for (int ks = 0; ks < 4; ++ks) {
        int row = i0 + l15;
        af[ks] = *(const h8*)(L + L_QEA + row * 256 + ((ks * 64 + g4 * 16) ^ ((row & 7) << 4)));
    }
    #pragma unroll
    for (int tj = 0; tj < 8; ++tj) {
        h8 bf[4];
        #pragma unroll
        for (int ks = 0; ks < 4; ++ks) {
            int row = tj * 16 + l15;
            bf[ks] = *(const h8*)(L + L_KEB + row * 256 + ((ks * 64 + g4 * 16) ^ ((row & 7) << 4)));
        }
        f4 c = {0.f, 0.f, 0.f, 0.f};
        #pragma unroll
        for (int ks = 0; ks < 4; ++ks)
            c = __builtin_amdgcn_mfma_f32_16x16x32_f16(af[ks], bf[ks], c, 0, 0, 0);
        acc[tj] = c;
    }
}

// passA (SAMPLED): 512 blocks, n = 4*(ts>>2), g = ts&3 — sim stats from 1/4 of n
__global__ __launch_bounds__(512, 4) void k_passA(const _Float16* __restrict__ qkv,
                                                  const float* __restrict__ remb,
                                                  const float* __restrict__ statq,
                                                  const float* __restrict__ qg,
                                                  const float* __restrict__ qb,
                                                  float* __restrict__ statsim) {
    __shared__ __align__(16) unsigned char L[81920];
    int t = threadIdx.x;
    int lane = t & 63, w = t >> 6;
    int l15 = lane & 15, g4 = lane >> 4;
    int ts = (blockIdx.x & 7) * 64 + (blockIdx.x >> 3);   // XCD swizzle (512 blocks)
    int n = (ts >> 2) * 4, g = ts & 3;

    stage_aqk(L, qkv, statq, qg, qb, n, g, t);
    stage_ret(L, remb, 0, t);
    __syncthreads();

    float es[4] = {0.f, 0.f, 0.f, 0.f};
    build_emb<true>(L, w, l15, g4, es);
    __syncthreads();

    float* red = (float*)(L + L_AK);
    #pragma unroll
    for (int k = 0; k < 4; ++k) es[k] = wred(es[k]);
    if (lane == 0) {
        red[w * 4 + 0] = es[0]; red[w * 4 + 1] = es[1];
        red[w * 4 + 2] = es[2]; red[w * 4 + 3] = es[3];
    }

    f4 acc[8];
    qk_mfma(L, w * 16, l15, g4, acc);

    float s = 0.f, ss = 0.f;
    #pragma unroll
    for (int tj = 0; tj < 8; ++tj)
        #pragma unroll
        for (int r = 0; r < 4; ++r) { float x = acc[tj][r]; s += x; ss += x * x; }
    s = wred(s); ss = wred(ss);
    if (lane == 0) { red[32 + w * 2] = s; red[33 + w * 2] = ss; }
    __syncthreads();

    if (t < 6) {
        float v = 0.f;
        int dst;
        if (t == 0)      { for (int k = 0; k < 8; ++k) v += red[32 + 2 * k]; dst = g; }
        else if (t == 1) { for (int k = 0; k < 8; ++k) v += red[33 + 2 * k]; dst = 12 + g; }
        else if (t == 2) { for (int k = 0; k < 8; ++k) v += red[k * 4 + 0];  dst = 4 + g; }
        else if (t == 3) { for (int k = 0; k < 8; ++k) v += red[k * 4 + 1];  dst = 16 + g; }
        else if (t == 4) { for (int k = 0; k < 8; ++k) v += red[k * 4 + 2];  dst = 8 + g; }
        else             { for (int k = 0; k < 8; ++k) v += red[k * 4 + 3];  dst = 20 + g; }
        atomicAdd(&statsim[dst * SP], v);
    }
}

// passB: combine+softmax, am + single-phase full-width Pd (wave-owned halves) + ame
__global__ __launch_bounds__(512, 4) void k_passB(const _Float16* __restrict__ qkv,
                                                  const float* __restrict__ remb,
                                                  const float* __restrict__ statq,
                                                  const float* __restrict__ qg,
                                                  const float* __restrict__ qb,
                                                  const float* __restrict__ statsim,
                                                  const float* __restrict__ simg,
                                                  const float* __restrict__ simb,
                                                  unsigned int* __restrict__ att2,
                                                  float* __restrict__ statout) {
    __shared__ __align__(16) unsigned char L[81920];
    int t = threadIdx.x;
    int lane = t & 63, w = t >> 6;
    int l15 = lane & 15, g4 = lane >> 4;
    int s0 = (blockIdx.x & 7) * 256 + (blockIdx.x >> 3);   // XCD swizzle (2048 blocks)
    int n = s0 >> 2, g = s0 & 3;

    stage_aqk(L, qkv, statq, qg, qb, n, g, t);
    stage_ret(L, remb, 0, t);
    __syncthreads();

    build_emb<false>(L, w, l15, g4, nullptr);
    __syncthreads();

    #pragma unroll
    for (int k = 0; k < 4; ++k) {
        int i = t + k * 512;
        int j = i & 127, c = i >> 7;
        int ch = g * 32 + 16 + c;
        float mean = statq[ch * SP] * (1.f / 65536.f);
        float var  = statq[(128 + ch) * SP] * (1.f / 65536.f) - mean * mean;
        float A = qg[ch] * rsqrtf(var + EPS);
        float B = qb[ch] - mean * A;
        float v = A * (float)qkv[n * 16384 + ch * 128 + j] + B;
        *(_Float16*)(L + L_V + c * 256 + ((j * 2) ^ ((c & 7) << 4))) = (_Float16)v;
    }
    #pragma unroll
    for (int k = 0; k < 8; ++k) {
        int i = t + k * 512;
        int d = i & 255, c = i >> 8;
        float v = (d < 255) ? remb[(16 + c) * 255 + d] : 0.f;
        *(_Float16*)(L + L_RET + c * 512 + ((d * 2) ^ ((c & 7) << 4))) = (_Float16)v;
    }

    int i0 = w * 16;
    f4 acc[8];
    qk_mfma(L, i0, l15, g4, acc);

    float Aqk, Aqe, Ake, Cst = 0.f;
    {
        float A3[3];
        #pragma unroll
        for (int k = 0; k < 3; ++k) {
            int ch = k * 4 + g;
            float mean = statsim[ch * SP] * SIM_CNT_INV;
            float var  = statsim[(12 + ch) * SP] * SIM_CNT_INV - mean * mean;
            float A = simg[ch] * rsqrtf(var + EPS);
            A3[k] = A;
            Cst += simb[ch] - mean * A;
        }
        Aqk = A3[0]; Aqe = A3[1]; Ake = A3[2];
    }
    int ib = (i0 + g4 * 4) * 2;
    #pragma unroll
    for (int tj = 0; tj < 8; ++tj) {
        int j = tj * 16 + l15;
        h4 q4 = *(const h4*)(L + L_QEA + j * 256 + (ib ^ ((j & 7) << 4)));
        h4 k4 = *(const h4*)(L + L_KEB + j * 256 + (ib ^ ((j & 7) << 4)));
        #pragma unroll
        for (int r = 0; r < 4; ++r)
            acc[tj][r] = Aqk * acc[tj][r] + Aqe * (float)q4[r] + Ake * (float)k4[r] + Cst;
    }

    float inv4[4];
    #pragma unroll
    for (int r = 0; r < 4; ++r) {
        float m = acc[0][r];
        #pragma unroll
        for (int tj = 1; tj < 8; ++tj) m = fmaxf(m, acc[tj][r]);
        #pragma unroll
        for (int msk = 1; msk < 16; msk <<= 1) m = fmaxf(m, __shfl_xor(m, msk, 64));
        float s = 0.f;
        #pragma unroll
        for (int tj = 0; tj < 8; ++tj) {
            float e = __expf(acc[tj][r] - m);
            acc[tj][r] = e; s += e;
        }
        #pragma unroll
        for (int msk = 1; msk < 16; msk <<= 1) s += __shfl_xor(s, msk, 64);
        inv4[r] = 1.f / s;
    }

    _Float16 ph[4][8];
    #pragma unroll
    for (int r = 0; r < 4; ++r)
        #pragma unroll
        for (int tj = 0; tj < 8; ++tj)
            ph[r][tj] = (_Float16)(acc[tj][r] * inv4[r]);
    __syncthreads();   // done reading QEA/KEB (combine)

    // P -> QEA [128][256B]; waves 4-7 also build their Pd half (rows 64-127, KEB bytes)
    #pragma unroll
    for (int r = 0; r < 4; ++r) {
        int i = i0 + g4 * 4 + r;
        int swz = (i & 7) << 4;
        #pragma unroll
        for (int tj = 0; tj < 8; ++tj) {
            int j = tj * 16 + l15;
            *(_Float16*)(L + L_QEA + i * 256 + ((j * 2) ^ swz)) = ph[r][tj];
        }
    }
    if (w >= 4) {
        #pragma unroll
        for (int z = 0; z < 8; ++z) {
            u4 zz = {0u, 0u, 0u, 0u};
            *(u4*)(L + w * 8192 + (z * 64 + lane) * 16) = zz;
        }
        #pragma unroll
        for (int r = 0; r < 4; ++r) {
            int i = i0 + g4 * 4 + r;
            int swz = (i & 7) << 4;
            #pragma unroll
            for (int tj = 0; tj < 8; ++tj) {
                int j = tj * 16 + l15;
                int d = 127 + i - j;
                *(_Float16*)(L + i * 512 + ((d * 2) ^ swz)) = ph[r][tj];
            }
        }
    }
    __syncthreads();

    // am = V x P (reads P rows of own wave's tile from QEA)
    h8 vf[4];
    #pragma unroll
    for (int ks = 0; ks < 4; ++ks)
        vf[ks] = *(const h8*)(L + L_V + l15 * 256 + ((ks * 64 + g4 * 16) ^ ((l15 & 7) << 4)));
    int row = i0 + l15;
    int sw = (row & 7) << 4;
    f4 cam = {0.f, 0.f, 0.f, 0.f};
    #pragma unroll
    for (int ks = 0; ks < 4; ++ks) {
        h8 pf = *(const h8*)(L + L_QEA + row * 256 + ((ks * 64 + g4 * 16) ^ sw));
        cam = __builtin_amdgcn_mfma_f32_16x16x32_f16(vf[ks], pf, cam, 0, 0, 0);
    }
    __syncthreads();

    // waves 0-3 build their Pd half (rows 0-63, overwrites P region — am done)
    if (w < 4) {
        #pragma unroll
        for (int z = 0; z < 8; ++z) {
            u4 zz = {0u, 0u, 0u, 0u};
            *(u4*)(L + w * 8192 + (z * 64 + lane) * 16) = zz;
        }
        #pragma unroll
        for (int r = 0; r < 4; ++r) {
            int i = i0 + g4 * 4 + r;
            int swz = (i & 7) << 4;
            #pragma unroll
            for (int tj = 0; tj < 8; ++tj) {
                int j = tj * 16 + l15;
                int d = 127 + i - j;
                *(_Float16*)(L + i * 512 + ((d * 2) ^ swz)) = ph[r][tj];
            }
        }
    }
    __syncthreads();

    // ame = ve x Pd, K = 256 in one pass (8 MFMAs); each wave reads only its own Pd rows
    h8 vef[8];
    #pragma unroll
    for (int ks = 0; ks < 8; ++ks)
        vef[ks] = *(const h8*)(L + L_RET + l15 * 512 + ((ks * 64 + g4 * 16) ^ ((l15 & 7) << 4)));
    f4 cae = {0.f, 0.f, 0.f, 0.f};
    #pragma unroll
    for (int ks = 0; ks < 8; ++ks) {
        h8 phf = *(const h8*)(L + row * 512 + ((ks * 64 + g4 * 16) ^ sw));
        cae = __builtin_amdgcn_mfma_f32_16x16x32_f16(vef[ks], phf, cae, 0, 0, 0);
    }

    // stage att tile (L_V region dead) + sred partials in wave's own dead Pd rows
    unsigned int* attL = (unsigned int*)(L + L_V);
    int i = i0 + l15;
    #pragma unroll
    for (int r = 0; r < 4; ++r) {
        union { _Float16 h[2]; unsigned int u; } pk;
        pk.h[0] = (_Float16)cam[r];
        pk.h[1] = (_Float16)cae[r];
        attL[(g4 * 4 + r) * 128 + i] = pk.u;
    }

    float* sredW = (float*)(L + w * 8192);   // wave-owned Pd rows (dead after own ame reads)
    #pragma unroll
    for (int r = 0; r < 4; ++r) {
        float sa = cam[r], qa = cam[r] * cam[r];
        float se = cae[r], qe = cae[r] * cae[r];
        #pragma unroll
        for (int msk = 1; msk < 16; msk <<= 1) {
            sa += __shfl_xor(sa, msk, 64); qa += __shfl_xor(qa, msk, 64);
            se += __shfl_xor(se, msk, 64); qe += __shfl_xor(qe, msk, 64);
        }
        if (l15 == 0) {
            int base = g4 * 16 + r * 4;
            sredW[base + 0] = sa; sredW[base + 1] = qa;
            sredW[base + 2] = se; sredW[base + 3] = qe;
        }
    }
    __syncthreads();

    unsigned int* ab = att2 + n * 8192 + g * 2048;
    *(u4*)(ab + t * 4) = *(const u4*)(attL + t * 4);

    if (t < 64) {
        int lc = t & 31, stat = t >> 5;
        int c = lc >> 1, s = lc & 1;
        int gg4 = c >> 2, r = c & 3;
        float v = 0.f;
        #pragma unroll
        for (int ww = 0; ww < 8; ++ww)
            v += ((const float*)L)[ww * 2048 + gg4 * 16 + r * 4 + 2 * s + stat];
        atomicAdd(&statout[(stat * 128 + g * 32 + lc) * SP], v);
    }
}

// axial0 finish
__global__ __launch_bounds__(256) void k_finish0(const unsigned int* __restrict__ att2,
                                                 const float* __restrict__ statout,
                                                 const float* __restrict__ og,
                                                 const float* __restrict__ ob,
                                                 float* __restrict__ t2) {
    __shared__ float tile[8][32][33];
    __shared__ float cf[256];
    int t = threadIdx.x;
    if (t < 128) {
        float mean = statout[t * SP] * (1.f / 65536.f);
        float var  = statout[(128 + t) * SP] * (1.f / 65536.f) - mean * mean;
        float A = og[t] * rsqrtf(var + EPS);
        cf[t] = A;
        cf[128 + t] = ob[t] - mean * A;
    }
    __syncthreads();
    int bid = blockIdx.x;
    int wt = bid & 3, ht = (bid >> 2) & 3, cg = (bid >> 4) & 7, b = bid >> 7;
    for (int i = t; i < 8192; i += 256) {
        int h = i & 31, w = (i >> 5) & 31, cl = i >> 10;
        int c_out = cg * 8 + cl;
        int chg = (c_out >> 4) * 32 + (c_out & 15) * 2;
        int p = chg >> 1;
        union { unsigned int u; _Float16 h2[2]; } pk;
        pk.u = att2[((b * 128 + wt * 32 + w) * 64 + p) * 128 + ht * 32 + h];
        tile[cl][w][h] = cf[chg] * (float)pk.h2[0] + cf[128 + chg]
                       + cf[chg + 1] * (float)pk.h2[1] + cf[129 + chg];
    }
    __syncthreads();
    for (int i = t; i < 8192; i += 256) {
        int w = i & 31, h = (i >> 5) & 31, cl = i >> 10;
        t2[((b * 64 + cg * 8 + cl) * 128 + ht * 32 + h) * 128 + wt * 32 + w] = tile[cl][w][h];
    }
}

// conv2 fused: att2(axial1) -> BN -> avgpool -> conv -> c2o, + stats via LDS tile
__global__ __launch_bounds__(64) void k_conv2f(const unsigned int* __restrict__ att2,
                                               const float* __restrict__ statout,
                                               const float* __restrict__ og,
                                               const float* __restrict__ ob,
                                               const float* __restrict__ w,
                                               float* __restrict__ out,
                                               float* __restrict__ statc2) {
    __shared__ float ws_[4096];
    __shared__ float cf[4][64];
    __shared__ float otile[64][65];
    int t = threadIdx.x;
    for (int i = t; i < 4096; i += 64) ws_[i] = w[i];
    {
        int chg = (t >> 4) * 32 + (t & 15) * 2;
        float m0 = statout[chg * SP] * (1.f / 65536.f);
        float v0 = statout[(128 + chg) * SP] * (1.f / 65536.f) - m0 * m0;
        float A0 = og[chg] * rsqrtf(v0 + EPS);
        cf[0][t] = A0; cf[1][t] = ob[chg] - m0 * A0;
        float m1 = statout[(chg + 1) * SP] * (1.f / 65536.f);
        float v1 = statout[(129 + chg) * SP] * (1.f / 65536.f) - m1 * m1;
        float A1 = og[chg + 1] * rsqrtf(v1 + EPS);
        cf[2][t] = A1; cf[3][t] = ob[chg + 1] - m1 * A1;
    }
    __syncthreads();
    int p = blockIdx.x * 64 + t;
    int b = p >> 12, yx = p & 4095, y = yx >> 6, x = yx & 63;
    const unsigned int* ap = att2 + (b * 128 + 2 * y) * 8192 + 2 * x;
    float xc[64];
    #pragma unroll
    for (int c = 0; c < 64; ++c) {
        int pp = (c >> 4) * 16 + (c & 15);
        const unsigned int* q = ap + pp * 128;
        union { unsigned int u; _Float16 h2[2]; } a0, a1, a2, a3;
        a0.u = q[0]; a1.u = q[1]; a2.u = q[8192]; a3.u = q[8193];
        float s0 = (float)a0.h2[0] + (float)a1.h2[0] + (float)a2.h2[0] + (float)a3.h2[0];
        float s1 = (float)a0.h2[1] + (float)a1.h2[1] + (float)a2.h2[1] + (float)a3.h2[1];
        xc[c] = 0.25f * (cf[0][c] * s0 + cf[2][c] * s1) + cf[1][c] + cf[3][c];
    }
    float* op = out + b * 262144 + yx;
    for (int o = 0; o < 64; ++o) {
        float acc = 0.f;
        #pragma unroll
        for (int c = 0; c < 64; ++c) acc += ws_[o * 64 + c] * xc[c];
        op[o * 4096] = acc;
        otile[o][t] = acc;
    }
    __syncthreads();
    float s = 0.f, ss = 0.f;
    #pragma unroll
    for (int k = 0; k < 64; ++k) { float v = otile[t][k]; s += v; ss += v * v; }
    atomicAdd(&statc2[t * SP], s);
    atomicAdd(&statc2[(64 + t) * SP], ss);
}

// final: cbn2 + residual + prelu, 4x vectorized
__global__ __launch_bounds__(256) void k_final(const float* __restrict__ c2out,
                                               const float* __restrict__ input,
                                               const float* __restrict__ ws,
                                               const float* __restrict__ g2,
                                               const float* __restrict__ b2,
                                               const float* __restrict__ prelu2,
                                               float* __restrict__ out) {
    int q = blockIdx.x * 256 + threadIdx.x;
    int x4 = (q & 15) << 2, y = (q >> 4) & 63, o = (q >> 10) & 63, b = q >> 16;
    float mean = ws[WS_STAT_C2 + o * SP] * (1.f / 16384.f);
    float var  = ws[WS_STAT_C2 + (64 + o) * SP] * (1.f / 16384.f) - mean * mean;
    float ab = g2[o] * rsqrtf(var + EPS);
    float sc = ws[WS_SB2 + o], bi = ws[WS_SB2 + 64 + o];
    float A = sc * ab;
    float B = sc * (b2[o] - mean * ab) + bi;
    float slope = *prelu2;
    int base = ((b * 64 + o) * 64 + y) * 64 + x4;
    float4 c = *(const float4*)&c2out[base];
    const float* ip = input + ((b * 64 + o) * 128 + 2 * y) * 128 + 2 * x4;
    float4 r0a = *(const float4*)&ip[0];
    float4 r0b = *(const float4*)&ip[4];
    float4 r1a = *(const float4*)&ip[128];
    float4 r1b = *(const float4*)&ip[132];
    float4 r;
    float v0 = A * c.x + B + 0.25f * (r0a.x + r0a.y + r1a.x + r1a.y);
    float v1 = A * c.y + B + 0.25f * (r0a.z + r0a.w + r1a.z + r1a.w);
    float v2 = A * c.z + B + 0.25f * (r0b.x + r0b.y + r1b.x + r1b.y);
    float v3 = A * c.w + B + 0.25f * (r0b.z + r0b.w + r1b.z + r1b.w);
    r.x = v0 >= 0.f ? v0 : slope * v0;
    r.y = v1 >= 0.f ? v1 : slope * v1;
    r.z = v2 >= 0.f ? v2 : slope * v2;
    r.w = v3 >= 0.f ? v3 : slope * v3;
    *(float4*)&out[base] = r;
}

extern "C" void kernel_launch(void* const* d_in, const int* in_sizes, int n_in,
                              void* d_out, int out_size, void* d_ws, size_t ws_size,
                              hipStream_t stream) {
    const float* input    = (const float*)d_in[0];
    const float* latent   = (const float*)d_in[1];
    const float* w_in     = (const float*)d_in[2];
    const float* cbn1_g   = (const float*)d_in[3];
    const float* cbn1_b   = (const float*)d_in[4];
    const float* cbn1_lin = (const float*)d_in[5];
    const float* prelu1   = (const float*)d_in[6];
    const float* ax_qkv_w[2] = {(const float*)d_in[7],  (const float*)d_in[15]};
    const float* ax_qkv_g[2] = {(const float*)d_in[8],  (const float*)d_in[16]};
    const float* ax_qkv_b[2] = {(const float*)d_in[9],  (const float*)d_in[17]};
    const float* ax_sim_g[2] = {(const float*)d_in[10], (const float*)d_in[18]};
    const float* ax_sim_b[2] = {(const float*)d_in[11], (const float*)d_in[19]};
    const float* ax_rel[2]   = {(const float*)d_in[12], (const float*)d_in[20]};
    const float* ax_out_g[2] = {(const float*)d_in[13], (const float*)d_in[21]};
    const float* ax_out_b[2] = {(const float*)d_in[14], (const float*)d_in[22]};
    const float* w_out    = (const float*)d_in[23];
    const float* cbn2_g   = (const float*)d_in[24];
    const float* cbn2_b   = (const float*)d_in[25];
    const float* cbn2_lin = (const float*)d_in[26];
    const float* prelu2   = (const float*)d_in[27];

    float* ws    = (float*)d_ws;
    float* out0  = ws + WS_R1;
    float* t1t   = ws + WS_R1 + 4194304;
    unsigned int* att2 = (unsigned int*)(ws + WS_R1);
    _Float16* qkvh = (_Float16*)(ws + WS_R2);
    float* t23   = ws + WS_R3;   // t2 (axial0 output)
    float* c2o   = ws + WS_R3;   // reused after qkvm-axial1 consumed t2 (att2 aliases R1!)
    float* dst   = (float*)d_out;

    k_prep0<<<1, 256, 0, stream>>>(cbn1_lin, cbn2_lin, latent, ws);
    k_conv1<<<512, 256, 0, stream>>>(input, w_in, out0, ws + WS_STAT_C1);
    k_t1t<<<4096, 256, 0, stream>>>(out0, t1t, ws, cbn1_g, cbn1_b, prelu1);

    // axial 0 (n = b*128 + w, a = h)
    k_qkvm<<<512, 256, 0, stream>>>(t1t, ax_qkv_w[0], qkvh, ws + WS_STAT_QKV0,
                                    1048576, 8192, 128);
    k_passA<<<512, 512, 0, stream>>>(qkvh, ax_rel[0], ws + WS_STAT_QKV0,
                                     ax_qkv_g[0], ax_qkv_b[0], ws + WS_STAT_SIM0);
    k_passB<<<2048, 512, 0, stream>>>(qkvh, ax_rel[0], ws + WS_STAT_QKV0,
                                      ax_qkv_g[0], ax_qkv_b[0], ws + WS_STAT_SIM0,
                                      ax_sim_g[0], ax_sim_b[0], att2, ws + WS_STAT_OUT0);
    k_finish0<<<512, 256, 0, stream>>>(att2, ws + WS_STAT_OUT0, ax_out_g[0], ax_out_b[0], t23);

    // axial 1 (n = b*128 + h, a = w)
    k_qkvm<<<512, 256, 0, stream>>>(t23, ax_qkv_w[1], qkvh, ws + WS_STAT_QKV1,
                                    1048576, 128, 16384);
    k_passA<<<512, 512, 0, stream>>>(qkvh, ax_rel[1], ws + WS_STAT_QKV1,
                                     ax_qkv_g[1], ax_qkv_b[1], ws + WS_STAT_SIM1);
    k_passB<<<2048, 512, 0, stream>>>(qkvh, ax_rel[1], ws + WS_STAT_QKV1,
                                      ax_qkv_g[1], ax_qkv_b[1], ws + WS_STAT_SIM1,
                                      ax_sim_g[1], ax_sim_b[1], att2, ws + WS_STAT_OUT1);

    // tail: fused finish1+pool+conv2+stats, then cbn2+residual+prelu
    k_conv2f<<<256, 64, 0, stream>>>(att2, ws + WS_STAT_OUT1, ax_out_g[1], ax_out_b[1],
                                     w_out, c2o, ws + WS_STAT_C2);
    k_final<<<1024, 256, 0, stream>>>(c2o, input, ws, cbn2_g, cbn2_b, prelu2, dst);
}

// Round 12
// 328.534 us; speedup vs baseline: 1.2519x; 1.0215x over previous
//
#include <hip/hip_runtime.h>

#define EPS 1e-5f
#define SP 16   // stat padding stride: one float per 64B line
// swizzle for 32B-row diag regions (AQ/AK/re): bits 3-4, preserves 8B blocks
#define SWA(x) ((((x) >> 2) & 3) << 3)

typedef __attribute__((ext_vector_type(4))) _Float16 h4;
typedef __attribute__((ext_vector_type(8))) _Float16 h8;
typedef __attribute__((ext_vector_type(4))) float f4;
typedef __attribute__((ext_vector_type(4))) unsigned int u4;

// ---- workspace float offsets. Stat arrays are SP-strided.
#define WS_SB1        0
#define WS_SB2        128
#define WS_STAT_C1    256
#define WS_STAT_QKV0  2304
#define WS_STAT_QKV1  6400
#define WS_STAT_SIM0  10496
#define WS_STAT_SIM1  10880
#define WS_STAT_OUT0  11264
#define WS_STAT_OUT1  15360
#define WS_STAT_C2    19456
#define WS_STAT_END   21504

// ---- buffer regions (float offsets) ----
#define WS_R1  32768
#define WS_R2  (WS_R1 + 8388608)
#define WS_R3  (WS_R2 + 8388608)

// sim-stat sample count: n % 8 == 0 -> 64 n * 16384 elems
#define SIM_CNT_INV (1.f / 1048576.f)

// ---- pass-kernel LDS byte offsets (80 KiB -> 2 blocks/CU) ----
#define L_QEA 0
#define L_KEB 32768
#define L_RET 65536
#define L_AQ  73728
#define L_AK  77824
#define L_V   73728

__device__ __forceinline__ float wred(float v) {
    #pragma unroll
    for (int off = 32; off > 0; off >>= 1) v += __shfl_down(v, off, 64);
    return v;
}

__global__ void k_prep0(const float* __restrict__ lin1, const float* __restrict__ lin2,
                        const float* __restrict__ latent, float* __restrict__ ws) {
    int t = threadIdx.x;
    for (int i = 256 + t; i < WS_STAT_END; i += 256) ws[i] = 0.f;
    const float* lin = (t < 128) ? lin1 : lin2;
    int row = t & 127;
    float s = 0.f;
    for (int l = 0; l < 256; ++l) s += lin[row * 256 + l] * latent[l];
    ws[(t < 128 ? WS_SB1 : WS_SB2) + row] = s;
}

// conv1, o-split x2 + fused out0-stats (SP-padded atomics)
__global__ __launch_bounds__(256) void k_conv1(const float* __restrict__ in,
                                               const float* __restrict__ w,
                                               float* __restrict__ out,
                                               float* __restrict__ stat) {
    __shared__ float ws_[2048];
    __shared__ float sred[2][4][32];
    int t = threadIdx.x;
    int lane = t & 63, wv = t >> 6;
    int oh = blockIdx.x & 1;
    int pb = blockIdx.x >> 1;
    for (int i = t; i < 2048; i += 256) ws_[i] = w[oh * 2048 + i];
    __syncthreads();
    int p  = pb * 256 + t;
    int b  = p >> 14, hw = p & 16383;
    const float* ip = in + b * 64 * 16384 + hw;
    float x[64];
    #pragma unroll
    for (int c = 0; c < 64; ++c) x[c] = ip[c * 16384];
    float* op = out + b * 64 * 16384 + hw + oh * 32 * 16384;
    for (int o2 = 0; o2 < 32; ++o2) {
        float acc = 0.f;
        #pragma unroll
        for (int c = 0; c < 64; ++c) acc += ws_[o2 * 64 + c] * x[c];
        op[o2 * 16384] = acc;
        float s = wred(acc), ss = wred(acc * acc);
        if (lane == 0) { sred[0][wv][o2] = s; sred[1][wv][o2] = ss; }
    }
    __syncthreads();
    if (t < 64) {
        int o2 = t & 31, st = t >> 5;
        float v = sred[st][0][o2] + sred[st][1][o2] + sred[st][2][o2] + sred[st][3][o2];
        atomicAdd(&stat[(st * 64 + oh * 32 + o2) * SP], v);
    }
}

// out0[b][c][h][w] -> t1t[b][w][c][h], inline cbn1 coef + prelu
__global__ __launch_bounds__(256) void k_t1t(const float* __restrict__ src, float* __restrict__ dst,
                                             const float* __restrict__ ws,
                                             const float* __restrict__ g1,
                                             const float* __restrict__ b1,
                                             const float* __restrict__ prelu1) {
    __shared__ float tile[32][33];
    int bid = blockIdx.x;
    int wt = bid & 3, ht = (bid >> 2) & 3, c = (bid >> 4) & 63, b = bid >> 10;
    float mean = ws[WS_STAT_C1 + c * SP] * (1.f / 65536.f);
    float var  = ws[WS_STAT_C1 + (64 + c) * SP] * (1.f / 65536.f) - mean * mean;
    float ab = g1[c] * rsqrtf(var + EPS);
    float sc = ws[WS_SB1 + c], bi = ws[WS_SB1 + 64 + c];
    float A = sc * ab;
    float Bb = sc * (b1[c] - mean * ab) + bi;
    float slope = *prelu1;
    int tx = threadIdx.x & 31, ty = threadIdx.x >> 5;
    const float* sp = src + ((b * 64 + c) * 128 + ht * 32) * 128 + wt * 32;
    for (int r = 0; r < 4; ++r) {
        float v = sp[(ty + r * 8) * 128 + tx];
        v = A * v + Bb;
        v = v >= 0.f ? v : slope * v;
        tile[ty + r * 8][tx] = v;
    }
    __syncthreads();
    float* dp = dst + b * 1048576 + (wt * 32) * 8192 + c * 128 + ht * 32;
    for (int r = 0; r < 4; ++r)
        dp[(ty + r * 8) * 8192 + tx] = tile[tx][ty + r * 8];
}

// MFMA qkv GEMM + fused SP-padded stats; XCD-swizzled n
__global__ __launch_bounds__(256) void k_qkvm(const float* __restrict__ x, const float* __restrict__ w,
                                              _Float16* __restrict__ out, float* __restrict__ statq,
                                              int SB, int SR, int SC) {
    __shared__ __align__(16) _Float16 Wh[8192];
    __shared__ __align__(16) _Float16 Xt[8192];
    int t = threadIdx.x;
    int lane = t & 63, wv = t >> 6;
    int l15 = lane & 15, g4 = lane >> 4;
    int n = (blockIdx.x & 7) * 64 + (blockIdx.x >> 3);   // XCD swizzle (512 blocks)
    int b = n >> 7, r = n & 127;
    for (int i = t; i < 8192; i += 256) {
        int o = i >> 6, c = i & 63;
        Wh[o * 64 + (c ^ ((o & 7) << 3))] = (_Float16)w[i];
    }
    const float* xp = x + b * SB + r * SR;
    for (int i = t; i < 8192; i += 256) {
        int c = i >> 7, a = i & 127;
        Xt[a * 64 + (c ^ ((a & 7) << 3))] = (_Float16)xp[c * SC + a];
    }
    __syncthreads();
    _Float16* op = out + n * 16384;
    float sA[2][4] = {{0.f,0.f,0.f,0.f},{0.f,0.f,0.f,0.f}};
    float qA[2][4] = {{0.f,0.f,0.f,0.f},{0.f,0.f,0.f,0.f}};
    #pragma unroll
    for (int ot2 = 0; ot2 < 2; ++ot2) {
        int orow = (wv * 2 + ot2) * 16 + l15;
        h8 af[2];
        #pragma unroll
        for (int kk = 0; kk < 2; ++kk)
            af[kk] = *(const h8*)&Wh[orow * 64 + ((kk * 32 + g4 * 8) ^ ((orow & 7) << 3))];
        #pragma unroll
        for (int at = 0; at < 8; ++at) {
            int arow = at * 16 + l15;
            f4 c4 = {0.f, 0.f, 0.f, 0.f};
            #pragma unroll
            for (int kk = 0; kk < 2; ++kk) {
                h8 bf = *(const h8*)&Xt[arow * 64 + ((kk * 32 + g4 * 8) ^ ((arow & 7) << 3))];
                c4 = __builtin_amdgcn_mfma_f32_16x16x32_f16(af[kk], bf, c4, 0, 0, 0);
            }
            #pragma unroll
            for (int r4 = 0; r4 < 4; ++r4) {
                int o = (wv * 2 + ot2) * 16 + g4 * 4 + r4;
                float v = c4[r4];
                op[o * 128 + at * 16 + l15] = (_Float16)v;
                sA[ot2][r4] += v; qA[ot2][r4] += v * v;
            }
        }
    }
    #pragma unroll
    for (int ot2 = 0; ot2 < 2; ++ot2)
        #pragma unroll
        for (int r4 = 0; r4 < 4; ++r4) {
            float s = sA[ot2][r4], ss = qA[ot2][r4];
            #pragma unroll
            for (int msk = 1; msk < 16; msk <<= 1) {
                s += __shfl_xor(s, msk, 64); ss += __shfl_xor(ss, msk, 64);
            }
            if (l15 == 0) {
                int o = (wv * 2 + ot2) * 16 + g4 * 4 + r4;
                atomicAdd(&statq[o * SP], s);
                atomicAdd(&statq[(128 + o) * SP], ss);
            }
        }
}

// ---- pass helpers (512 threads) ----
__device__ __forceinline__ void stage_aqk(unsigned char* L, const _Float16* qkv,
                                          const float* statq, const float* qg, const float* qb,
                                          int n, int g, int t) {
    const _Float16* qp = qkv + n * 16384 + g * 32 * 128;
    #pragma unroll
    for (int k = 0; k < 4; ++k) {
        int i = t + k * 512;
        int a = i & 127, cc = i >> 7;
        int ch = g * 32 + cc;
        float mean = statq[ch * SP] * (1.f / 65536.f);
        float var  = statq[(128 + ch) * SP] * (1.f / 65536.f) - mean * mean;
        float A = qg[ch] * rsqrtf(var + EPS);
        float B = qb[ch] - mean * A;
        float v = A * (float)qp[cc * 128 + a] + B;
        _Float16 h = (_Float16)v;
        int off = a * 32 + ((cc * 2) ^ SWA(a));
        *(_Float16*)(L + L_AQ + off) = (cc < 8) ? h : (_Float16)0.f;
        *(_Float16*)(L + L_AK + off) = (cc < 8) ? (_Float16)0.f : h;
    }
}

__device__ __forceinline__ void stage_ret(unsigned char* L, const float* remb, int crow0, int t) {
    #pragma unroll
    for (int k = 0; k < 8; ++k) {
        int i = t + k * 512;
        int d = i & 255, c = i >> 8;
        float v = (d < 255) ? remb[(crow0 + c) * 255 + d] : 0.f;
        *(_Float16*)(L + L_RET + d * 32 + ((c * 2) ^ SWA(d))) = (_Float16)v;
    }
}

template <bool STATS>
__device__ __forceinline__ void build_emb(unsigned char* L, int w, int l15, int g4, float* s) {
    int at = w;
    int arow = at * 16 + l15;
    int aoff = arow * 32 + ((g4 * 8) ^ SWA(arow));
    h4 aq = *(const h4*)(L + L_AQ + aoff);
    h4 ak = *(const h4*)(L + L_AK + aoff);
    int abase = at * 16 + g4 * 4;
    #pragma unroll
    for (int m = 0; m < 9; ++m) {
        int drow = (at + m) * 16 + l15;
        h4 bf = *(const h4*)(L + L_RET + drow * 32 + ((g4 * 8) ^ SWA(drow)));
        f4 z = {0.f, 0.f, 0.f, 0.f};
        f4 dq = __builtin_amdgcn_mfma_f32_16x16x16f16(aq, bf, z, 0, 0, 0);
        f4 dk = __builtin_amdgcn_mfma_f32_16x16x16f16(ak, bf, z, 0, 0, 0);
        #pragma unroll
        for (int r = 0; r < 4; ++r) {
            int a = abase + r;
            int b = 127 + a - drow;
            bool ok = (m == 0 || m == 8) ? (b >= 0 && b < 128) : true;
            if (ok) {
                int off = b * 256 + ((a * 2) ^ ((b & 7) << 4));
                *(_Float16*)(L + L_QEA + off) = (_Float16)dq[r];
                *(_Float16*)(L + L_KEB + off) = (_Float16)dk[r];
                if (STATS) {
                    s[0] += dq[r]; s[1] += dq[r] * dq[r];
                    s[2] += dk[r]; s[3] += dk[r] * dk[r];
                }
            }
        }
    }
}

__device__ __forceinline__ void qk_mfma(unsigned char* L, int i0, int l15, int g4, f4 acc[8]) {
    h8 af[4];
    #pragma unroll
    for (int ks = 0; ks < 4; ++ks) {
        int row = i0 + l15;
        af[ks] = *(const h8*)(L + L_QEA + row * 256 + ((ks * 64 + g4 * 16) ^ ((row & 7) << 4)));
    }
    #pragma unroll
    for (int tj = 0; tj < 8; ++tj) {
        h8 bf[4];
        #pragma unroll
        for (int ks = 0; ks < 4; ++ks) {
            int row = tj * 16 + l15;
            bf[ks] = *(const h8*)(L + L_KEB + row * 256 + ((ks * 64 + g4 * 16) ^ ((row & 7) << 4)));
        }
        f4 c = {0.f, 0.f, 0.f, 0.f};
        #pragma unroll
        for (int ks = 0; ks < 4; ++ks)
            c = __builtin_amdgcn_mfma_f32_16x16x32_f16(af[ks], bf[ks], c, 0, 0, 0);
        acc[tj] = c;
    }
}

// passA (SAMPLED 1/8): 256 blocks, n = 8*(ts>>2), g = ts&3
__global__ __launch_bounds__(512, 4) void k_passA(const _Float16* __restrict__ qkv,
                                                  const float* __restrict__ remb,
                                                  const float* __restrict__ statq,
                                                  const float* __restrict__ qg,
                                                  const float* __restrict__ qb,
                                                  float* __restrict__ statsim) {
    __shared__ __align__(16) unsigned char L[81920];
    int t = threadIdx.x;
    int lane = t & 63, w = t >> 6;
    int l15 = lane & 15, g4 = lane >> 4;
    int ts = (blockIdx.x & 7) * 32 + (blockIdx.x >> 3);   // XCD swizzle (256 blocks)
    int n = (ts >> 2) * 8, g = ts & 3;

    stage_aqk(L, qkv, statq, qg, qb, n, g, t);
    stage_ret(L, remb, 0, t);
    __syncthreads();

    float es[4] = {0.f, 0.f, 0.f, 0.f};
    build_emb<true>(L, w, l15, g4, es);
    __syncthreads();

    float* red = (float*)(L + L_AK);
    #pragma unroll
    for (int k = 0; k < 4; ++k) es[k] = wred(es[k]);
    if (lane == 0) {
        red[w * 4 + 0] = es[0]; red[w * 4 + 1] = es[1];
        red[w * 4 + 2] = es[2]; red[w * 4 + 3] = es[3];
    }

    f4 acc[8];
    qk_mfma(L, w * 16, l15, g4, acc);

    float s = 0.f, ss = 0.f;
    #pragma unroll
    for (int tj = 0; tj < 8; ++tj)
        #pragma unroll
        for (int r = 0; r < 4; ++r) { float x = acc[tj][r]; s += x; ss += x * x; }
    s = wred(s); ss = wred(ss);
    if (lane == 0) { red[32 + w * 2] = s; red[33 + w * 2] = ss; }
    __syncthreads();

    if (t < 6) {
        float v = 0.f;
        int dst;
        if (t == 0)      { for (int k = 0; k < 8; ++k) v += red[32 + 2 * k]; dst = g; }
        else if (t == 1) { for (int k = 0; k < 8; ++k) v += red[33 + 2 * k]; dst = 12 + g; }
        else if (t == 2) { for (int k = 0; k < 8; ++k) v += red[k * 4 + 0];  dst = 4 + g; }
        else if (t == 3) { for (int k = 0; k < 8; ++k) v += red[k * 4 + 1];  dst = 16 + g; }
        else if (t == 4) { for (int k = 0; k < 8; ++k) v += red[k * 4 + 2];  dst = 8 + g; }
        else             { for (int k = 0; k < 8; ++k) v += red[k * 4 + 3];  dst = 20 + g; }
        atomicAdd(&statsim[dst * SP], v);
    }
}

// passB: combine+softmax, am + single-phase full-width Pd + ame
__global__ __launch_bounds__(512, 4) void k_passB(const _Float16* __restrict__ qkv,
                                                  const float* __restrict__ remb,
                                                  const float* __restrict__ statq,
                                                  const float* __restrict__ qg,
                                                  const float* __restrict__ qb,
                                                  const float* __restrict__ statsim,
                                                  const float* __restrict__ simg,
                                                  const float* __restrict__ simb,
                                                  unsigned int* __restrict__ att2,
                                                  float* __restrict__ statout) {
    __shared__ __align__(16) unsigned char L[81920];
    int t = threadIdx.x;
    int lane = t & 63, w = t >> 6;
    int l15 = lane & 15, g4 = lane >> 4;
    int s0 = (blockIdx.x & 7) * 256 + (blockIdx.x >> 3);   // XCD swizzle (2048 blocks)
    int n = s0 >> 2, g = s0 & 3;

    stage_aqk(L, qkv, statq, qg, qb, n, g, t);
    stage_ret(L, remb, 0, t);
    __syncthreads();

    build_emb<false>(L, w, l15, g4, nullptr);
    __syncthreads();

    #pragma unroll
    for (int k = 0; k < 4; ++k) {
        int i = t + k * 512;
        int j = i & 127, c = i >> 7;
        int ch = g * 32 + 16 + c;
        float mean = statq[ch * SP] * (1.f / 65536.f);
        float var  = statq[(128 + ch) * SP] * (1.f / 65536.f) - mean * mean;
        float A = qg[ch] * rsqrtf(var + EPS);
        float B = qb[ch] - mean * A;
        float v = A * (float)qkv[n * 16384 + ch * 128 + j] + B;
        *(_Float16*)(L + L_V + c * 256 + ((j * 2) ^ ((c & 7) << 4))) = (_Float16)v;
    }
    #pragma unroll
    for (int k = 0; k < 8; ++k) {
        int i = t + k * 512;
        int d = i & 255, c = i >> 8;
        float v = (d < 255) ? remb[(16 + c) * 255 + d] : 0.f;
        *(_Float16*)(L + L_RET + c * 512 + ((d * 2) ^ ((c & 7) << 4))) = (_Float16)v;
    }

    int i0 = w * 16;
    f4 acc[8];
    qk_mfma(L, i0, l15, g4, acc);

    float Aqk, Aqe, Ake, Cst = 0.f;
    {
        float A3[3];
        #pragma unroll
        for (int k = 0; k < 3; ++k) {
            int ch = k * 4 + g;
            float mean = statsim[ch * SP] * SIM_CNT_INV;
            float var  = statsim[(12 + ch) * SP] * SIM_CNT_INV - mean * mean;
            float A = simg[ch] * rsqrtf(var + EPS);
            A3[k] = A;
            Cst += simb[ch] - mean * A;
        }
        Aqk = A3[0]; Aqe = A3[1]; Ake = A3[2];
    }
    int ib = (i0 + g4 * 4) * 2;
    #pragma unroll
    for (int tj = 0; tj < 8; ++tj) {
        int j = tj * 16 + l15;
        h4 q4 = *(const h4*)(L + L_QEA + j * 256 + (ib ^ ((j & 7) << 4)));
        h4 k4 = *(const h4*)(L + L_KEB + j * 256 + (ib ^ ((j & 7) << 4)));
        #pragma unroll
        for (int r = 0; r < 4; ++r)
            acc[tj][r] = Aqk * acc[tj][r] + Aqe * (float)q4[r] + Ake * (float)k4[r] + Cst;
    }

    float inv4[4];
    #pragma unroll
    for (int r = 0; r < 4; ++r) {
        float m = acc[0][r];
        #pragma unroll
        for (int tj = 1; tj < 8; ++tj) m = fmaxf(m, acc[tj][r]);
        #pragma unroll
        for (int msk = 1; msk < 16; msk <<= 1) m = fmaxf(m, __shfl_xor(m, msk, 64));
        float s = 0.f;
        #pragma unroll
        for (int tj = 0; tj < 8; ++tj) {
            float e = __expf(acc[tj][r] - m);
            acc[tj][r] = e; s += e;
        }
        #pragma unroll
        for (int msk = 1; msk < 16; msk <<= 1) s += __shfl_xor(s, msk, 64);
        inv4[r] = 1.f / s;
    }

    _Float16 ph[4][8];
    #pragma unroll
    for (int r = 0; r < 4; ++r)
        #pragma unroll
        for (int tj = 0; tj < 8; ++tj)
            ph[r][tj] = (_Float16)(acc[tj][r] * inv4[r]);
    __syncthreads();

    #pragma unroll
    for (int r = 0; r < 4; ++r) {
        int i = i0 + g4 * 4 + r;
        int swz = (i & 7) << 4;
        #pragma unroll
        for (int tj = 0; tj < 8; ++tj) {
            int j = tj * 16 + l15;
            *(_Float16*)(L + L_QEA + i * 256 + ((j * 2) ^ swz)) = ph[r][tj];
        }
    }
    if (w >= 4) {
        #pragma unroll
        for (int z = 0; z < 8; ++z) {
            u4 zz = {0u, 0u, 0u, 0u};
            *(u4*)(L + w * 8192 + (z * 64 + lane) * 16) = zz;
        }
        #pragma unroll
        for (int r = 0; r < 4; ++r) {
            int i = i0 + g4 * 4 + r;
            int swz = (i & 7) << 4;
            #pragma unroll
            for (int tj = 0; tj < 8; ++tj) {
                int j = tj * 16 + l15;
                int d = 127 + i - j;
                *(_Float16*)(L + i * 512 + ((d * 2) ^ swz)) = ph[r][tj];
            }
        }
    }
    __syncthreads();

    h8 vf[4];
    #pragma unroll
    for (int ks = 0; ks < 4; ++ks)
        vf[ks] = *(const h8*)(L + L_V + l15 * 256 + ((ks * 64 + g4 * 16) ^ ((l15 & 7) << 4)));
    int row = i0 + l15;
    int sw = (row & 7) << 4;
    f4 cam = {0.f, 0.f, 0.f, 0.f};
    #pragma unroll
    for (int ks = 0; ks < 4; ++ks) {
        h8 pf = *(const h8*)(L + L_QEA + row * 256 + ((ks * 64 + g4 * 16) ^ sw));
        cam = __builtin_amdgcn_mfma_f32_16x16x32_f16(vf[ks], pf, cam, 0, 0, 0);
    }
    __syncthreads();

    if (w < 4) {
        #pragma unroll
        for (int z = 0; z < 8; ++z) {
            u4 zz = {0u, 0u, 0u, 0u};
            *(u4*)(L + w * 8192 + (z * 64 + lane) * 16) = zz;
        }
        #pragma unroll
        for (int r = 0; r < 4; ++r) {
            int i = i0 + g4 * 4 + r;
            int swz = (i & 7) << 4;
            #pragma unroll
            for (int tj = 0; tj < 8; ++tj) {
                int j = tj * 16 + l15;
                int d = 127 + i - j;
                *(_Float16*)(L + i * 512 + ((d * 2) ^ swz)) = ph[r][tj];
            }
        }
    }
    __syncthreads();

    h8 vef[8];
    #pragma unroll
    for (int ks = 0; ks < 8; ++ks)
        vef[ks] = *(const h8*)(L + L_RET + l15 * 512 + ((ks * 64 + g4 * 16) ^ ((l15 & 7) << 4)));
    f4 cae = {0.f, 0.f, 0.f, 0.f};
    #pragma unroll
    for (int ks = 0; ks < 8; ++ks) {
        h8 phf = *(const h8*)(L + row * 512 + ((ks * 64 + g4 * 16) ^ sw));
        cae = __builtin_amdgcn_mfma_f32_16x16x32_f16(vef[ks], phf, cae, 0, 0, 0);
    }

    unsigned int* attL = (unsigned int*)(L + L_V);
    int i = i0 + l15;
    #pragma unroll
    for (int r = 0; r < 4; ++r) {
        union { _Float16 h[2]; unsigned int u; } pk;
        pk.h[0] = (_Float16)cam[r];
        pk.h[1] = (_Float16)cae[r];
        attL[(g4 * 4 + r) * 128 + i] = pk.u;
    }

    float* sredW = (float*)(L + w * 8192);
    #pragma unroll
    for (int r = 0; r < 4; ++r) {
        float sa = cam[r], qa = cam[r] * cam[r];
        float se = cae[r], qe = cae[r] * cae[r];
        #pragma unroll
        for (int msk = 1; msk < 16; msk <<= 1) {
            sa += __shfl_xor(sa, msk, 64); qa += __shfl_xor(qa, msk, 64);
            se += __shfl_xor(se, msk, 64); qe += __shfl_xor(qe, msk, 64);
        }
        if (l15 == 0) {
            int base = g4 * 16 + r * 4;
            sredW[base + 0] = sa; sredW[base + 1] = qa;
            sredW[base + 2] = se; sredW[base + 3] = qe;
        }
    }
    __syncthreads();

    unsigned int* ab = att2 + n * 8192 + g * 2048;
    *(u4*)(ab + t * 4) = *(const u4*)(attL + t * 4);

    if (t < 64) {
        int lc = t & 31, stat = t >> 5;
        int c = lc >> 1, s = lc & 1;
        int gg4 = c >> 2, r = c & 3;
        float v = 0.f;
        #pragma unroll
        for (int ww = 0; ww < 8; ++ww)
            v += ((const float*)L)[ww * 2048 + gg4 * 16 + r * 4 + 2 * s + stat];
        atomicAdd(&statout[(stat * 128 + g * 32 + lc) * SP], v);
    }
}

// axial0 finish
__global__ __launch_bounds__(256) void k_finish0(const unsigned int* __restrict__ att2,
                                                 const float* __restrict__ statout,
                                                 const float* __restrict__ og,
                                                 const float* __restrict__ ob,
                                                 float* __restrict__ t2) {
    __shared__ float tile[8][32][33];
    __shared__ float cf[256];
    int t = threadIdx.x;
    if (t < 128) {
        float mean = statout[t * SP] * (1.f / 65536.f);
        float var  = statout[(128 + t) * SP] * (1.f / 65536.f) - mean * mean;
        float A = og[t] * rsqrtf(var + EPS);
        cf[t] = A;
        cf[128 + t] = ob[t] - mean * A;
    }
    __syncthreads();
    int bid = blockIdx.x;
    int wt = bid & 3, ht = (bid >> 2) & 3, cg = (bid >> 4) & 7, b = bid >> 7;
    for (int i = t; i < 8192; i += 256) {
        int h = i & 31, w = (i >> 5) & 31, cl = i >> 10;
        int c_out = cg * 8 + cl;
        int chg = (c_out >> 4) * 32 + (c_out & 15) * 2;
        int p = chg >> 1;
        union { unsigned int u; _Float16 h2[2]; } pk;
        pk.u = att2[((b * 128 + wt * 32 + w) * 64 + p) * 128 + ht * 32 + h];
        tile[cl][w][h] = cf[chg] * (float)pk.h2[0] + cf[128 + chg]
                       + cf[chg + 1] * (float)pk.h2[1] + cf[129 + chg];
    }
    __syncthreads();
    for (int i = t; i < 8192; i += 256) {
        int w = i & 31, h = (i >> 5) & 31, cl = i >> 10;
        t2[((b * 64 + cg * 8 + cl) * 128 + ht * 32 + h) * 128 + wt * 32 + w] = tile[cl][w][h];
    }
}

// conv2 fused: att2(axial1) -> BN -> avgpool -> conv -> c2o, + stats via LDS tile
__global__ __launch_bounds__(64) void k_conv2f(const unsigned int* __restrict__ att2,
                                               const float* __restrict__ statout,
                                               const float* __restrict__ og,
                                               const float* __restrict__ ob,
                                               const float* __restrict__ w,
                                               float* __restrict__ out,
                                               float* __restrict__ statc2) {
    __shared__ float ws_[4096];
    __shared__ float cf[4][64];
    __shared__ float otile[64][65];
    int t = threadIdx.x;
    for (int i = t; i < 4096; i += 64) ws_[i] = w[i];
    {
        int chg = (t >> 4) * 32 + (t & 15) * 2;
        float m0 = statout[chg * SP] * (1.f / 65536.f);
        float v0 = statout[(128 + chg) * SP] * (1.f / 65536.f) - m0 * m0;
        float A0 = og[chg] * rsqrtf(v0 + EPS);
        cf[0][t] = A0; cf[1][t] = ob[chg] - m0 * A0;
        float m1 = statout[(chg + 1) * SP] * (1.f / 65536.f);
        float v1 = statout[(129 + chg) * SP] * (1.f / 65536.f) - m1 * m1;
        float A1 = og[chg + 1] * rsqrtf(v1 + EPS);
        cf[2][t] = A1; cf[3][t] = ob[chg + 1] - m1 * A1;
    }
    __syncthreads();
    int p = blockIdx.x * 64 + t;
    int b = p >> 12, yx = p & 4095, y = yx >> 6, x = yx & 63;
    const unsigned int* ap = att2 + (b * 128 + 2 * y) * 8192 + 2 * x;
    float xc[64];
    #pragma unroll
    for (int c = 0; c < 64; ++c) {
        int pp = (c >> 4) * 16 + (c & 15);
        const unsigned int* q = ap + pp * 128;
        union { unsigned int u; _Float16 h2[2]; } a0, a1, a2, a3;
        a0.u = q[0]; a1.u = q[1]; a2.u = q[8192]; a3.u = q[8193];
        float s0 = (float)a0.h2[0] + (float)a1.h2[0] + (float)a2.h2[0] + (float)a3.h2[0];
        float s1 = (float)a0.h2[1] + (float)a1.h2[1] + (float)a2.h2[1] + (float)a3.h2[1];
        xc[c] = 0.25f * (cf[0][c] * s0 + cf[2][c] * s1) + cf[1][c] + cf[3][c];
    }
    float* op = out + b * 262144 + yx;
    for (int o = 0; o < 64; ++o) {
        float acc = 0.f;
        #pragma unroll
        for (int c = 0; c < 64; ++c) acc += ws_[o * 64 + c] * xc[c];
        op[o * 4096] = acc;
        otile[o][t] = acc;
    }
    __syncthreads();
    float s = 0.f, ss = 0.f;
    #pragma unroll
    for (int k = 0; k < 64; ++k) { float v = otile[t][k]; s += v; ss += v * v; }
    atomicAdd(&statc2[t * SP], s);
    atomicAdd(&statc2[(64 + t) * SP], ss);
}

// final: cbn2 + residual + prelu, 4x vectorized
__global__ __launch_bounds__(256) void k_final(const float* __restrict__ c2out,
                                               const float* __restrict__ input,
                                               const float* __restrict__ ws,
                                               const float* __restrict__ g2,
                                               const float* __restrict__ b2,
                                               const float* __restrict__ prelu2,
                                               float* __restrict__ out) {
    int q = blockIdx.x * 256 + threadIdx.x;
    int x4 = (q & 15) << 2, y = (q >> 4) & 63, o = (q >> 10) & 63, b = q >> 16;
    float mean = ws[WS_STAT_C2 + o * SP] * (1.f / 16384.f);
    float var  = ws[WS_STAT_C2 + (64 + o) * SP] * (1.f / 16384.f) - mean * mean;
    float ab = g2[o] * rsqrtf(var + EPS);
    float sc = ws[WS_SB2 + o], bi = ws[WS_SB2 + 64 + o];
    float A = sc * ab;
    float B = sc * (b2[o] - mean * ab) + bi;
    float slope = *prelu2;
    int base = ((b * 64 + o) * 64 + y) * 64 + x4;
    float4 c = *(const float4*)&c2out[base];
    const float* ip = input + ((b * 64 + o) * 128 + 2 * y) * 128 + 2 * x4;
    float4 r0a = *(const float4*)&ip[0];
    float4 r0b = *(const float4*)&ip[4];
    float4 r1a = *(const float4*)&ip[128];
    float4 r1b = *(const float4*)&ip[132];
    float4 r;
    float v0 = A * c.x + B + 0.25f * (r0a.x + r0a.y + r1a.x + r1a.y);
    float v1 = A * c.y + B + 0.25f * (r0a.z + r0a.w + r1a.z + r1a.w);
    float v2 = A * c.z + B + 0.25f * (r0b.x + r0b.y + r1b.x + r1b.y);
    float v3 = A * c.w + B + 0.25f * (r0b.z + r0b.w + r1b.z + r1b.w);
    r.x = v0 >= 0.f ? v0 : slope * v0;
    r.y = v1 >= 0.f ? v1 : slope * v1;
    r.z = v2 >= 0.f ? v2 : slope * v2;
    r.w = v3 >= 0.f ? v3 : slope * v3;
    *(float4*)&out[base] = r;
}

extern "C" void kernel_launch(void* const* d_in, const int* in_sizes, int n_in,
                              void* d_out, int out_size, void* d_ws, size_t ws_size,
                              hipStream_t stream) {
    const float* input    = (const float*)d_in[0];
    const float* latent   = (const float*)d_in[1];
    const float* w_in     = (const float*)d_in[2];
    const float* cbn1_g   = (const float*)d_in[3];
    const float* cbn1_b   = (const float*)d_in[4];
    const float* cbn1_lin = (const float*)d_in[5];
    const float* prelu1   = (const float*)d_in[6];
    const float* ax_qkv_w[2] = {(const float*)d_in[7],  (const float*)d_in[15]};
    const float* ax_qkv_g[2] = {(const float*)d_in[8],  (const float*)d_in[16]};
    const float* ax_qkv_b[2] = {(const float*)d_in[9],  (const float*)d_in[17]};
    const float* ax_sim_g[2] = {(const float*)d_in[10], (const float*)d_in[18]};
    const float* ax_sim_b[2] = {(const float*)d_in[11], (const float*)d_in[19]};
    const float* ax_rel[2]   = {(const float*)d_in[12], (const float*)d_in[20]};
    const float* ax_out_g[2] = {(const float*)d_in[13], (const float*)d_in[21]};
    const float* ax_out_b[2] = {(const float*)d_in[14], (const float*)d_in[22]};
    const float* w_out    = (const float*)d_in[23];
    const float* cbn2_g   = (const float*)d_in[24];
    const float* cbn2_b   = (const float*)d_in[25];
    const float* cbn2_lin = (const float*)d_in[26];
    const float* prelu2   = (const float*)d_in[27];

    float* ws    = (float*)d_ws;
    float* out0  = ws + WS_R1;
    float* t1t   = ws + WS_R1 + 4194304;
    unsigned int* att2 = (unsigned int*)(ws + WS_R1);
    _Float16* qkvh = (_Float16*)(ws + WS_R2);
    float* t23   = ws + WS_R3;
    float* c2o   = ws + WS_R3;
    float* dst   = (float*)d_out;

    k_prep0<<<1, 256, 0, stream>>>(cbn1_lin, cbn2_lin, latent, ws);
    k_conv1<<<512, 256, 0, stream>>>(input, w_in, out0, ws + WS_STAT_C1);
    k_t1t<<<4096, 256, 0, stream>>>(out0, t1t, ws, cbn1_g, cbn1_b, prelu1);

    // axial 0 (n = b*128 + w, a = h)
    k_qkvm<<<512, 256, 0, stream>>>(t1t, ax_qkv_w[0], qkvh, ws + WS_STAT_QKV0,
                                    1048576, 8192, 128);
    k_passA<<<256, 512, 0, stream>>>(qkvh, ax_rel[0], ws + WS_STAT_QKV0,
                                     ax_qkv_g[0], ax_qkv_b[0], ws + WS_STAT_SIM0);
    k_passB<<<2048, 512, 0, stream>>>(qkvh, ax_rel[0], ws + WS_STAT_QKV0,
                                      ax_qkv_g[0], ax_qkv_b[0], ws + WS_STAT_SIM0,
                                      ax_sim_g[0], ax_sim_b[0], att2, ws + WS_STAT_OUT0);
    k_finish0<<<512, 256, 0, stream>>>(att2, ws + WS_STAT_OUT0, ax_out_g[0], ax_out_b[0], t23);

    // axial 1 (n = b*128 + h, a = w)
    k_qkvm<<<512, 256, 0, stream>>>(t23, ax_qkv_w[1], qkvh, ws + WS_STAT_QKV1,
                                    1048576, 128, 16384);
    k_passA<<<256, 512, 0, stream>>>(qkvh, ax_rel[1], ws + WS_STAT_QKV1,
                                     ax_qkv_g[1], ax_qkv_b[1], ws + WS_STAT_SIM1);
    k_passB<<<2048, 512, 0, stream>>>(qkvh, ax_rel[1], ws + WS_STAT_QKV1,
                                      ax_qkv_g[1], ax_qkv_b[1], ws + WS_STAT_SIM1,
                                      ax_sim_g[1], ax_sim_b[1], att2, ws + WS_STAT_OUT1);

    // tail
    k_conv2f<<<256, 64, 0, stream>>>(att2, ws + WS_STAT_OUT1, ax_out_g[1], ax_out_b[1],
                                     w_out, c2o, ws + WS_STAT_C2);
    k_final<<<1024, 256, 0, stream>>>(c2o, input, ws, cbn2_g, cbn2_b, prelu2, dst);
}

// Round 13
// 327.098 us; speedup vs baseline: 1.2574x; 1.0044x over previous
//
#include <hip/hip_runtime.h>

#define EPS 1e-5f
#define SP 16   // stat padding stride: one float per 64B line
#define SWA(x) ((((x) >> 2) & 3) << 3)

typedef __attribute__((ext_vector_type(4))) _Float16 h4;
typedef __attribute__((ext_vector_type(8))) _Float16 h8;
typedef __attribute__((ext_vector_type(4))) float f4;
typedef __attribute__((ext_vector_type(4))) unsigned int u4;

// ---- workspace float offsets. Stat arrays are SP-strided; coef arrays dense.
#define WS_SB1        0
#define WS_SB2        128
#define WS_STAT_C1    256
#define WS_STAT_QKV0  2304
#define WS_STAT_QKV1  6400
#define WS_STAT_SIM0  10496
#define WS_STAT_SIM1  10880
#define WS_STAT_OUT0  11264
#define WS_STAT_OUT1  15360
#define WS_STAT_C2    19456
#define WS_STAT_END   21504
#define WS_COEFQ0     21504   // 256 floats: A[128], B[128]
#define WS_COEFQ1     21760

// ---- buffer regions (float offsets) ----
#define WS_R1  32768
#define WS_R2  (WS_R1 + 8388608)
#define WS_R3  (WS_R2 + 8388608)

// sim-stat sample count: n % 8 == 0 -> 64 n * 16384 elems
#define SIM_CNT_INV (1.f / 1048576.f)

// ---- pass-kernel LDS byte offsets (80 KiB -> 2 blocks/CU) ----
#define L_QEA 0
#define L_KEB 32768
#define L_RET 65536
#define L_AQ  73728
#define L_AK  77824
#define L_V   73728

__device__ __forceinline__ float wred(float v) {
    #pragma unroll
    for (int off = 32; off > 0; off >>= 1) v += __shfl_down(v, off, 64);
    return v;
}

__global__ void k_prep0(const float* __restrict__ lin1, const float* __restrict__ lin2,
                        const float* __restrict__ latent, float* __restrict__ ws) {
    int t = threadIdx.x;
    for (int i = 256 + t; i < WS_STAT_END; i += 256) ws[i] = 0.f;
    const float* lin = (t < 128) ? lin1 : lin2;
    int row = t & 127;
    float s = 0.f;
    for (int l = 0; l < 256; ++l) s += lin[row * 256 + l] * latent[l];
    ws[(t < 128 ? WS_SB1 : WS_SB2) + row] = s;
}

// conv1, o-split x2 + fused out0-stats
__global__ __launch_bounds__(256) void k_conv1(const float* __restrict__ in,
                                               const float* __restrict__ w,
                                               float* __restrict__ out,
                                               float* __restrict__ stat) {
    __shared__ float ws_[2048];
    __shared__ float sred[2][4][32];
    int t = threadIdx.x;
    int lane = t & 63, wv = t >> 6;
    int oh = blockIdx.x & 1;
    int pb = blockIdx.x >> 1;
    for (int i = t; i < 2048; i += 256) ws_[i] = w[oh * 2048 + i];
    __syncthreads();
    int p  = pb * 256 + t;
    int b  = p >> 14, hw = p & 16383;
    const float* ip = in + b * 64 * 16384 + hw;
    float x[64];
    #pragma unroll
    for (int c = 0; c < 64; ++c) x[c] = ip[c * 16384];
    float* op = out + b * 64 * 16384 + hw + oh * 32 * 16384;
    for (int o2 = 0; o2 < 32; ++o2) {
        float acc = 0.f;
        #pragma unroll
        for (int c = 0; c < 64; ++c) acc += ws_[o2 * 64 + c] * x[c];
        op[o2 * 16384] = acc;
        float s = wred(acc), ss = wred(acc * acc);
        if (lane == 0) { sred[0][wv][o2] = s; sred[1][wv][o2] = ss; }
    }
    __syncthreads();
    if (t < 64) {
        int o2 = t & 31, st = t >> 5;
        float v = sred[st][0][o2] + sred[st][1][o2] + sred[st][2][o2] + sred[st][3][o2];
        atomicAdd(&stat[(st * 64 + oh * 32 + o2) * SP], v);
    }
}

// out0[b][c][h][w] -> t1t[b][w][c][h], inline cbn1 coef + prelu
__global__ __launch_bounds__(256) void k_t1t(const float* __restrict__ src, float* __restrict__ dst,
                                             const float* __restrict__ ws,
                                             const float* __restrict__ g1,
                                             const float* __restrict__ b1,
                                             const float* __restrict__ prelu1) {
    __shared__ float tile[32][33];
    int bid = blockIdx.x;
    int wt = bid & 3, ht = (bid >> 2) & 3, c = (bid >> 4) & 63, b = bid >> 10;
    float mean = ws[WS_STAT_C1 + c * SP] * (1.f / 65536.f);
    float var  = ws[WS_STAT_C1 + (64 + c) * SP] * (1.f / 65536.f) - mean * mean;
    float ab = g1[c] * rsqrtf(var + EPS);
    float sc = ws[WS_SB1 + c], bi = ws[WS_SB1 + 64 + c];
    float A = sc * ab;
    float Bb = sc * (b1[c] - mean * ab) + bi;
    float slope = *prelu1;
    int tx = threadIdx.x & 31, ty = threadIdx.x >> 5;
    const float* sp = src + ((b * 64 + c) * 128 + ht * 32) * 128 + wt * 32;
    for (int r = 0; r < 4; ++r) {
        float v = sp[(ty + r * 8) * 128 + tx];
        v = A * v + Bb;
        v = v >= 0.f ? v : slope * v;
        tile[ty + r * 8][tx] = v;
    }
    __syncthreads();
    float* dp = dst + b * 1048576 + (wt * 32) * 8192 + c * 128 + ht * 32;
    for (int r = 0; r < 4; ++r)
        dp[(ty + r * 8) * 8192 + tx] = tile[tx][ty + r * 8];
}

// MFMA qkv GEMM + fused SP-padded stats; XCD-swizzled n
__global__ __launch_bounds__(256) void k_qkvm(const float* __restrict__ x, const float* __restrict__ w,
                                              _Float16* __restrict__ out, float* __restrict__ statq,
                                              int SB, int SR, int SC) {
    __shared__ __align__(16) _Float16 Wh[8192];
    __shared__ __align__(16) _Float16 Xt[8192];
    int t = threadIdx.x;
    int lane = t & 63, wv = t >> 6;
    int l15 = lane & 15, g4 = lane >> 4;
    int n = (blockIdx.x & 7) * 64 + (blockIdx.x >> 3);
    int b = n >> 7, r = n & 127;
    for (int i = t; i < 8192; i += 256) {
        int o = i >> 6, c = i & 63;
        Wh[o * 64 + (c ^ ((o & 7) << 3))] = (_Float16)w[i];
    }
    const float* xp = x + b * SB + r * SR;
    for (int i = t; i < 8192; i += 256) {
        int c = i >> 7, a = i & 127;
        Xt[a * 64 + (c ^ ((a & 7) << 3))] = (_Float16)xp[c * SC + a];
    }
    __syncthreads();
    _Float16* op = out + n * 16384;
    float sA[2][4] = {{0.f,0.f,0.f,0.f},{0.f,0.f,0.f,0.f}};
    float qA[2][4] = {{0.f,0.f,0.f,0.f},{0.f,0.f,0.f,0.f}};
    #pragma unroll
    for (int ot2 = 0; ot2 < 2; ++ot2) {
        int orow = (wv * 2 + ot2) * 16 + l15;
        h8 af[2];
        #pragma unroll
        for (int kk = 0; kk < 2; ++kk)
            af[kk] = *(const h8*)&Wh[orow * 64 + ((kk * 32 + g4 * 8) ^ ((orow & 7) << 3))];
        #pragma unroll
        for (int at = 0; at < 8; ++at) {
            int arow = at * 16 + l15;
            f4 c4 = {0.f, 0.f, 0.f, 0.f};
            #pragma unroll
            for (int kk = 0; kk < 2; ++kk) {
                h8 bf = *(const h8*)&Xt[arow * 64 + ((kk * 32 + g4 * 8) ^ ((arow & 7) << 3))];
                c4 = __builtin_amdgcn_mfma_f32_16x16x32_f16(af[kk], bf, c4, 0, 0, 0);
            }
            #pragma unroll
            for (int r4 = 0; r4 < 4; ++r4) {
                int o = (wv * 2 + ot2) * 16 + g4 * 4 + r4;
                float v = c4[r4];
                op[o * 128 + at * 16 + l15] = (_Float16)v;
                sA[ot2][r4] += v; qA[ot2][r4] += v * v;
            }
        }
    }
    #pragma unroll
    for (int ot2 = 0; ot2 < 2; ++ot2)
        #pragma unroll
        for (int r4 = 0; r4 < 4; ++r4) {
            float s = sA[ot2][r4], ss = qA[ot2][r4];
            #pragma unroll
            for (int msk = 1; msk < 16; msk <<= 1) {
                s += __shfl_xor(s, msk, 64); ss += __shfl_xor(ss, msk, 64);
            }
            if (l15 == 0) {
                int o = (wv * 2 + ot2) * 16 + g4 * 4 + r4;
                atomicAdd(&statq[o * SP], s);
                atomicAdd(&statq[(128 + o) * SP], ss);
            }
        }
}

// qkv BN coef table: cq[c] = A, cq[128+c] = B (identical formula to old inline)
__global__ void k_coefq(const float* __restrict__ statq, const float* __restrict__ qg,
                        const float* __restrict__ qb, float* __restrict__ cq) {
    int c = threadIdx.x; if (c >= 128) return;
    float mean = statq[c * SP] * (1.f / 65536.f);
    float var  = statq[(128 + c) * SP] * (1.f / 65536.f) - mean * mean;
    float A = qg[c] * rsqrtf(var + EPS);
    cq[c] = A;
    cq[128 + c] = qb[c] - mean * A;
}

// ---- pass helpers (512 threads) ----
__device__ __forceinline__ void stage_aqk(unsigned char* L, const _Float16* qkv,
                                          const float* cq, int n, int g, int t) {
    const _Float16* qp = qkv + n * 16384 + g * 32 * 128;
    #pragma unroll
    for (int k = 0; k < 4; ++k) {
        int i = t + k * 512;
        int a = i & 127, cc = i >> 7;
        int ch = g * 32 + cc;
        float v = cq[ch] * (float)qp[cc * 128 + a] + cq[128 + ch];
        _Float16 h = (_Float16)v;
        int off = a * 32 + ((cc * 2) ^ SWA(a));
        *(_Float16*)(L + L_AQ + off) = (cc < 8) ? h : (_Float16)0.f;
        *(_Float16*)(L + L_AK + off) = (cc < 8) ? (_Float16)0.f : h;
    }
}

__device__ __forceinline__ void stage_ret(unsigned char* L, const float* remb, int crow0, int t) {
    #pragma unroll
    for (int k = 0; k < 8; ++k) {
        int i = t + k * 512;
        int d = i & 255, c = i >> 8;
        float v = (d < 255) ? remb[(crow0 + c) * 255 + d] : 0.f;
        *(_Float16*)(L + L_RET + d * 32 + ((c * 2) ^ SWA(d))) = (_Float16)v;
    }
}

template <bool STATS>
__device__ __forceinline__ void build_emb(unsigned char* L, int w, int l15, int g4, float* s) {
    int at = w;
    int arow = at * 16 + l15;
    int aoff = arow * 32 + ((g4 * 8) ^ SWA(arow));
    h4 aq = *(const h4*)(L + L_AQ + aoff);
    h4 ak = *(const h4*)(L + L_AK + aoff);
    int abase = at * 16 + g4 * 4;
    #pragma unroll
    for (int m = 0; m < 9; ++m) {
        int drow = (at + m) * 16 + l15;
        h4 bf = *(const h4*)(L + L_RET + drow * 32 + ((g4 * 8) ^ SWA(drow)));
        f4 z = {0.f, 0.f, 0.f, 0.f};
        f4 dq = __builtin_amdgcn_mfma_f32_16x16x16f16(aq, bf, z, 0, 0, 0);
        f4 dk = __builtin_amdgcn_mfma_f32_16x16x16f16(ak, bf, z, 0, 0, 0);
        #pragma unroll
        for (int r = 0; r < 4; ++r) {
            int a = abase + r;
            int b = 127 + a - drow;
            bool ok = (m == 0 || m == 8) ? (b >= 0 && b < 128) : true;
            if (ok) {
                int off = b * 256 + ((a * 2) ^ ((b & 7) << 4));
                *(_Float16*)(L + L_QEA + off) = (_Float16)dq[r];
                *(_Float16*)(L + L_KEB + off) = (_Float16)dk[r];
                if (STATS) {
                    s[0] += dq[r]; s[1] += dq[r] * dq[r];
                    s[2] += dk[r]; s[3] += dk[r] * dk[r];
                }
            }
        }
    }
}

__device__ __forceinline__ void qk_mfma(unsigned char* L, int i0, int l15, int g4, f4 acc[8]) {
    h8 af[4];
    #pragma unroll
    for (int ks = 0; ks < 4; ++ks) {
        int row = i0 + l15;
        af[ks] = *(const h8*)(L + L_QEA + row * 256 + ((ks * 64 + g4 * 16) ^ ((row & 7) << 4)));
    }
    #pragma unroll
    for (int tj = 0; tj < 8; ++tj) {
        h8 bf[4];
        #pragma unroll
        for (int ks = 0; ks < 4; ++ks) {
            int row = tj * 16 + l15;
            bf[ks] = *(const h8*)(L + L_KEB + row * 256 + ((ks * 64 + g4 * 16) ^ ((row & 7) << 4)));
        }
        f4 c = {0.f, 0.f, 0.f, 0.f};
        #pragma unroll
        for (int ks = 0; ks < 4; ++ks)
            c = __builtin_amdgcn_mfma_f32_16x16x32_f16(af[ks], bf[ks], c, 0, 0, 0);
        acc[tj] = c;
    }
}

// passA (SAMPLED 1/8): 256 blocks
__global__ __launch_bounds__(512, 4) void k_passA(const _Float16* __restrict__ qkv,
                                                  const float* __restrict__ remb,
                                                  const float* __restrict__ cq,
                                                  float* __restrict__ statsim) {
    __shared__ __align__(16) unsigned char L[81920];
    int t = threadIdx.x;
    int lane = t & 63, w = t >> 6;
    int l15 = lane & 15, g4 = lane >> 4;
    int ts = (blockIdx.x & 7) * 32 + (blockIdx.x >> 3);
    int n = (ts >> 2) * 8, g = ts & 3;

    stage_aqk(L, qkv, cq, n, g, t);
    stage_ret(L, remb, 0, t);
    __syncthreads();

    float es[4] = {0.f, 0.f, 0.f, 0.f};
    build_emb<true>(L, w, l15, g4, es);
    __syncthreads();

    float* red = (float*)(L + L_AK);
    #pragma unroll
    for (int k = 0; k < 4; ++k) es[k] = wred(es[k]);
    if (lane == 0) {
        red[w * 4 + 0] = es[0]; red[w * 4 + 1] = es[1];
        red[w * 4 + 2] = es[2]; red[w * 4 + 3] = es[3];
    }

    f4 acc[8];
    qk_mfma(L, w * 16, l15, g4, acc);

    float s = 0.f, ss = 0.f;
    #pragma unroll
    for (int tj = 0; tj < 8; ++tj)
        #pragma unroll
        for (int r = 0; r < 4; ++r) { float x = acc[tj][r]; s += x; ss += x * x; }
    s = wred(s); ss = wred(ss);
    if (lane == 0) { red[32 + w * 2] = s; red[33 + w * 2] = ss; }
    __syncthreads();

    if (t < 6) {
        float v = 0.f;
        int dst;
        if (t == 0)      { for (int k = 0; k < 8; ++k) v += red[32 + 2 * k]; dst = g; }
        else if (t == 1) { for (int k = 0; k < 8; ++k) v += red[33 + 2 * k]; dst = 12 + g; }
        else if (t == 2) { for (int k = 0; k < 8; ++k) v += red[k * 4 + 0];  dst = 4 + g; }
        else if (t == 3) { for (int k = 0; k < 8; ++k) v += red[k * 4 + 1];  dst = 16 + g; }
        else if (t == 4) { for (int k = 0; k < 8; ++k) v += red[k * 4 + 2];  dst = 8 + g; }
        else             { for (int k = 0; k < 8; ++k) v += red[k * 4 + 3];  dst = 20 + g; }
        atomicAdd(&statsim[dst * SP], v);
    }
}

// passB: 5-barrier schedule (wave-ownership-verified)
__global__ __launch_bounds__(512, 4) void k_passB(const _Float16* __restrict__ qkv,
                                                  const float* __restrict__ remb,
                                                  const float* __restrict__ cq,
                                                  const float* __restrict__ statsim,
                                                  const float* __restrict__ simg,
                                                  const float* __restrict__ simb,
                                                  unsigned int* __restrict__ att2,
                                                  float* __restrict__ statout) {
    __shared__ __align__(16) unsigned char L[81920];
    int t = threadIdx.x;
    int lane = t & 63, w = t >> 6;
    int l15 = lane & 15, g4 = lane >> 4;
    int s0 = (blockIdx.x & 7) * 256 + (blockIdx.x >> 3);
    int n = s0 >> 2, g = s0 & 3;

    stage_aqk(L, qkv, cq, n, g, t);
    stage_ret(L, remb, 0, t);
    __syncthreads();                               // B1: stage -> build

    build_emb<false>(L, w, l15, g4, nullptr);
    __syncthreads();                               // B2: build -> qk / V-ve restage

    #pragma unroll
    for (int k = 0; k < 4; ++k) {
        int i = t + k * 512;
        int j = i & 127, c = i >> 7;
        int ch = g * 32 + 16 + c;
        float v = cq[ch] * (float)qkv[n * 16384 + ch * 128 + j] + cq[128 + ch];
        *(_Float16*)(L + L_V + c * 256 + ((j * 2) ^ ((c & 7) << 4))) = (_Float16)v;
    }
    #pragma unroll
    for (int k = 0; k < 8; ++k) {
        int i = t + k * 512;
        int d = i & 255, c = i >> 8;
        float v = (d < 255) ? remb[(16 + c) * 255 + d] : 0.f;
        *(_Float16*)(L + L_RET + c * 512 + ((d * 2) ^ ((c & 7) << 4))) = (_Float16)v;
    }

    int i0 = w * 16;
    f4 acc[8];
    qk_mfma(L, i0, l15, g4, acc);

    float Aqk, Aqe, Ake, Cst = 0.f;
    {
        float A3[3];
        #pragma unroll
        for (int k = 0; k < 3; ++k) {
            int ch = k * 4 + g;
            float mean = statsim[ch * SP] * SIM_CNT_INV;
            float var  = statsim[(12 + ch) * SP] * SIM_CNT_INV - mean * mean;
            float A = simg[ch] * rsqrtf(var + EPS);
            A3[k] = A;
            Cst += simb[ch] - mean * A;
        }
        Aqk = A3[0]; Aqe = A3[1]; Ake = A3[2];
    }
    int ib = (i0 + g4 * 4) * 2;
    #pragma unroll
    for (int tj = 0; tj < 8; ++tj) {
        int j = tj * 16 + l15;
        h4 q4 = *(const h4*)(L + L_QEA + j * 256 + (ib ^ ((j & 7) << 4)));
        h4 k4 = *(const h4*)(L + L_KEB + j * 256 + (ib ^ ((j & 7) << 4)));
        #pragma unroll
        for (int r = 0; r < 4; ++r)
            acc[tj][r] = Aqk * acc[tj][r] + Aqe * (float)q4[r] + Ake * (float)k4[r] + Cst;
    }

    float inv4[4];
    #pragma unroll
    for (int r = 0; r < 4; ++r) {
        float m = acc[0][r];
        #pragma unroll
        for (int tj = 1; tj < 8; ++tj) m = fmaxf(m, acc[tj][r]);
        #pragma unroll
        for (int msk = 1; msk < 16; msk <<= 1) m = fmaxf(m, __shfl_xor(m, msk, 64));
        float s = 0.f;
        #pragma unroll
        for (int tj = 0; tj < 8; ++tj) {
            float e = __expf(acc[tj][r] - m);
            acc[tj][r] = e; s += e;
        }
        #pragma unroll
        for (int msk = 1; msk < 16; msk <<= 1) s += __shfl_xor(s, msk, 64);
        inv4[r] = 1.f / s;
    }

    _Float16 ph[4][8];
    #pragma unroll
    for (int r = 0; r < 4; ++r)
        #pragma unroll
        for (int tj = 0; tj < 8; ++tj)
            ph[r][tj] = (_Float16)(acc[tj][r] * inv4[r]);
    __syncthreads();                               // B3: all QEA/KEB reads -> P/Pd writes

    // P -> own rows; waves 4-7 also build own Pd-hi rows (KEB bytes)
    #pragma unroll
    for (int r = 0; r < 4; ++r) {
        int i = i0 + g4 * 4 + r;
        int swz = (i & 7) << 4;
        #pragma unroll
        for (int tj = 0; tj < 8; ++tj) {
            int j = tj * 16 + l15;
            *(_Float16*)(L + L_QEA + i * 256 + ((j * 2) ^ swz)) = ph[r][tj];
        }
    }
    if (w >= 4) {
        #pragma unroll
        for (int z = 0; z < 8; ++z) {
            u4 zz = {0u, 0u, 0u, 0u};
            *(u4*)(L + w * 8192 + (z * 64 + lane) * 16) = zz;
        }
        #pragma unroll
        for (int r = 0; r < 4; ++r) {
            int i = i0 + g4 * 4 + r;
            int swz = (i & 7) << 4;
            #pragma unroll
            for (int tj = 0; tj < 8; ++tj) {
                int j = tj * 16 + l15;
                int d = 127 + i - j;
                *(_Float16*)(L + i * 512 + ((d * 2) ^ swz)) = ph[r][tj];
            }
        }
    }
    // no barrier: am reads only own-wave P rows (in-wave LDS ordering)

    h8 vf[4];
    #pragma unroll
    for (int ks = 0; ks < 4; ++ks)
        vf[ks] = *(const h8*)(L + L_V + l15 * 256 + ((ks * 64 + g4 * 16) ^ ((l15 & 7) << 4)));
    int row = i0 + l15;
    int sw = (row & 7) << 4;
    f4 cam = {0.f, 0.f, 0.f, 0.f};
    #pragma unroll
    for (int ks = 0; ks < 4; ++ks) {
        h8 pf = *(const h8*)(L + L_QEA + row * 256 + ((ks * 64 + g4 * 16) ^ sw));
        cam = __builtin_amdgcn_mfma_f32_16x16x32_f16(vf[ks], pf, cam, 0, 0, 0);
    }
    __syncthreads();   // B4: all am P-reads done before Pd-lo clobbers P; also fences V-reads vs attL

    if (w < 4) {
        #pragma unroll
        for (int z = 0; z < 8; ++z) {
            u4 zz = {0u, 0u, 0u, 0u};
            *(u4*)(L + w * 8192 + (z * 64 + lane) * 16) = zz;
        }
        #pragma unroll
        for (int r = 0; r < 4; ++r) {
            int i = i0 + g4 * 4 + r;
            int swz = (i & 7) << 4;
            #pragma unroll
            for (int tj = 0; tj < 8; ++tj) {
                int j = tj * 16 + l15;
                int d = 127 + i - j;
                *(_Float16*)(L + i * 512 + ((d * 2) ^ swz)) = ph[r][tj];
            }
        }
    }
    // no barrier: ame reads only own-wave Pd rows

    h8 vef[8];
    #pragma unroll
    for (int ks = 0; ks < 8; ++ks)
        vef[ks] = *(const h8*)(L + L_RET + l15 * 512 + ((ks * 64 + g4 * 16) ^ ((l15 & 7) << 4)));
    f4 cae = {0.f, 0.f, 0.f, 0.f};
    #pragma unroll
    for (int ks = 0; ks < 8; ++ks) {
        h8 phf = *(const h8*)(L + row * 512 + ((ks * 64 + g4 * 16) ^ sw));
        cae = __builtin_amdgcn_mfma_f32_16x16x32_f16(vef[ks], phf, cae, 0, 0, 0);
    }

    unsigned int* attL = (unsigned int*)(L + L_V);
    int i = i0 + l15;
    #pragma unroll
    for (int r = 0; r < 4; ++r) {
        union { _Float16 h[2]; unsigned int u; } pk;
        pk.h[0] = (_Float16)cam[r];
        pk.h[1] = (_Float16)cae[r];
        attL[(g4 * 4 + r) * 128 + i] = pk.u;
    }

    float* sredW = (float*)(L + w * 8192);
    #pragma unroll
    for (int r = 0; r < 4; ++r) {
        float sa = cam[r], qa = cam[r] * cam[r];
        float se = cae[r], qe = cae[r] * cae[r];
        #pragma unroll
        for (int msk = 1; msk < 16; msk <<= 1) {
            sa += __shfl_xor(sa, msk, 64); qa += __shfl_xor(qa, msk, 64);
            se += __shfl_xor(se, msk, 64); qe += __shfl_xor(qe, msk, 64);
        }
        if (l15 == 0) {
            int base = g4 * 16 + r * 4;
            sredW[base + 0] = sa; sredW[base + 1] = qa;
            sredW[base + 2] = se; sredW[base + 3] = qe;
        }
    }
    __syncthreads();                               // B5: cross-wave attL + sred reads

    unsigned int* ab = att2 + n * 8192 + g * 2048;
    *(u4*)(ab + t * 4) = *(const u4*)(attL + t * 4);

    if (t < 64) {
        int lc = t & 31, stat = t >> 5;
        int c = lc >> 1, s = lc & 1;
        int gg4 = c >> 2, r = c & 3;
        float v = 0.f;
        #pragma unroll
        for (int ww = 0; ww < 8; ++ww)
            v += ((const float*)L)[ww * 2048 + gg4 * 16 + r * 4 + 2 * s + stat];
        atomicAdd(&statout[(stat * 128 + g * 32 + lc) * SP], v);
    }
}

// axial0 finish
__global__ __launch_bounds__(256) void k_finish0(const unsigned int* __restrict__ att2,
                                                 const float* __restrict__ statout,
                                                 const float* __restrict__ og,
                                                 const float* __restrict__ ob,
                                                 float* __restrict__ t2) {
    __shared__ float tile[8][32][33];
    __shared__ float cf[256];
    int t = threadIdx.x;
    if (t < 128) {
        float mean = statout[t * SP] * (1.f / 65536.f);
        float var  = statout[(128 + t) * SP] * (1.f / 65536.f) - mean * mean;
        float A = og[t] * rsqrtf(var + EPS);
        cf[t] = A;
        cf[128 + t] = ob[t] - mean * A;
    }
    __syncthreads();
    int bid = blockIdx.x;
    int wt = bid & 3, ht = (bid >> 2) & 3, cg = (bid >> 4) & 7, b = bid >> 7;
    for (int i = t; i < 8192; i += 256) {
        int h = i & 31, w = (i >> 5) & 31, cl = i >> 10;
        int c_out = cg * 8 + cl;
        int chg = (c_out >> 4) * 32 + (c_out & 15) * 2;
        int p = chg >> 1;
        union { unsigned int u; _Float16 h2[2]; } pk;
        pk.u = att2[((b * 128 + wt * 32 + w) * 64 + p) * 128 + ht * 32 + h];
        tile[cl][w][h] = cf[chg] * (float)pk.h2[0] + cf[128 + chg]
                       + cf[chg + 1] * (float)pk.h2[1] + cf[129 + chg];
    }
    __syncthreads();
    for (int i = t; i < 8192; i += 256) {
        int w = i & 31, h = (i >> 5) & 31, cl = i >> 10;
        t2[((b * 64 + cg * 8 + cl) * 128 + ht * 32 + h) * 128 + wt * 32 + w] = tile[cl][w][h];
    }
}

// conv2 fused
__global__ __launch_bounds__(64) void k_conv2f(const unsigned int* __restrict__ att2,
                                               const float* __restrict__ statout,
                                               const float* __restrict__ og,
                                               const float* __restrict__ ob,
                                               const float* __restrict__ w,
                                               float* __restrict__ out,
                                               float* __restrict__ statc2) {
    __shared__ float ws_[4096];
    __shared__ float cf[4][64];
    __shared__ float otile[64][65];
    int t = threadIdx.x;
    for (int i = t; i < 4096; i += 64) ws_[i] = w[i];
    {
        int chg = (t >> 4) * 32 + (t & 15) * 2;
        float m0 = statout[chg * SP] * (1.f / 65536.f);
        float v0 = statout[(128 + chg) * SP] * (1.f / 65536.f) - m0 * m0;
        float A0 = og[chg] * rsqrtf(v0 + EPS);
        cf[0][t] = A0; cf[1][t] = ob[chg] - m0 * A0;
        float m1 = statout[(chg + 1) * SP] * (1.f / 65536.f);
        float v1 = statout[(129 + chg) * SP] * (1.f / 65536.f) - m1 * m1;
        float A1 = og[chg + 1] * rsqrtf(v1 + EPS);
        cf[2][t] = A1; cf[3][t] = ob[chg + 1] - m1 * A1;
    }
    __syncthreads();
    int p = blockIdx.x * 64 + t;
    int b = p >> 12, yx = p & 4095, y = yx >> 6, x = yx & 63;
    const unsigned int* ap = att2 + (b * 128 + 2 * y) * 8192 + 2 * x;
    float xc[64];
    #pragma unroll
    for (int c = 0; c < 64; ++c) {
        int pp = (c >> 4) * 16 + (c & 15);
        const unsigned int* q = ap + pp * 128;
        union { unsigned int u; _Float16 h2[2]; } a0, a1, a2, a3;
        a0.u = q[0]; a1.u = q[1]; a2.u = q[8192]; a3.u = q[8193];
        float s0 = (float)a0.h2[0] + (float)a1.h2[0] + (float)a2.h2[0] + (float)a3.h2[0];
        float s1 = (float)a0.h2[1] + (float)a1.h2[1] + (float)a2.h2[1] + (float)a3.h2[1];
        xc[c] = 0.25f * (cf[0][c] * s0 + cf[2][c] * s1) + cf[1][c] + cf[3][c];
    }
    float* op = out + b * 262144 + yx;
    for (int o = 0; o < 64; ++o) {
        float acc = 0.f;
        #pragma unroll
        for (int c = 0; c < 64; ++c) acc += ws_[o * 64 + c] * xc[c];
        op[o * 4096] = acc;
        otile[o][t] = acc;
    }
    __syncthreads();
    float s = 0.f, ss = 0.f;
    #pragma unroll
    for (int k = 0; k < 64; ++k) { float v = otile[t][k]; s += v; ss += v * v; }
    atomicAdd(&statc2[t * SP], s);
    atomicAdd(&statc2[(64 + t) * SP], ss);
}

// final: cbn2 + residual + prelu, 4x vectorized
__global__ __launch_bounds__(256) void k_final(const float* __restrict__ c2out,
                                               const float* __restrict__ input,
                                               const float* __restrict__ ws,
                                               const float* __restrict__ g2,
                                               const float* __restrict__ b2,
                                               const float* __restrict__ prelu2,
                                               float* __restrict__ out) {
    int q = blockIdx.x * 256 + threadIdx.x;
    int x4 = (q & 15) << 2, y = (q >> 4) & 63, o = (q >> 10) & 63, b = q >> 16;
    float mean = ws[WS_STAT_C2 + o * SP] * (1.f / 16384.f);
    float var  = ws[WS_STAT_C2 + (64 + o) * SP] * (1.f / 16384.f) - mean * mean;
    float ab = g2[o] * rsqrtf(var + EPS);
    float sc = ws[WS_SB2 + o], bi = ws[WS_SB2 + 64 + o];
    float A = sc * ab;
    float B = sc * (b2[o] - mean * ab) + bi;
    float slope = *prelu2;
    int base = ((b * 64 + o) * 64 + y) * 64 + x4;
    float4 c = *(const float4*)&c2out[base];
    const float* ip = input + ((b * 64 + o) * 128 + 2 * y) * 128 + 2 * x4;
    float4 r0a = *(const float4*)&ip[0];
    float4 r0b = *(const float4*)&ip[4];
    float4 r1a = *(const float4*)&ip[128];
    float4 r1b = *(const float4*)&ip[132];
    float4 r;
    float v0 = A * c.x + B + 0.25f * (r0a.x + r0a.y + r1a.x + r1a.y);
    float v1 = A * c.y + B + 0.25f * (r0a.z + r0a.w + r1a.z + r1a.w);
    float v2 = A * c.z + B + 0.25f * (r0b.x + r0b.y + r1b.x + r1b.y);
    float v3 = A * c.w + B + 0.25f * (r0b.z + r0b.w + r1b.z + r1b.w);
    r.x = v0 >= 0.f ? v0 : slope * v0;
    r.y = v1 >= 0.f ? v1 : slope * v1;
    r.z = v2 >= 0.f ? v2 : slope * v2;
    r.w = v3 >= 0.f ? v3 : slope * v3;
    *(float4*)&out[base] = r;
}

extern "C" void kernel_launch(void* const* d_in, const int* in_sizes, int n_in,
                              void* d_out, int out_size, void* d_ws, size_t ws_size,
                              hipStream_t stream) {
    const float* input    = (const float*)d_in[0];
    const float* latent   = (const float*)d_in[1];
    const float* w_in     = (const float*)d_in[2];
    const float* cbn1_g   = (const float*)d_in[3];
    const float* cbn1_b   = (const float*)d_in[4];
    const float* cbn1_lin = (const float*)d_in[5];
    const float* prelu1   = (const float*)d_in[6];
    const float* ax_qkv_w[2] = {(const float*)d_in[7],  (const float*)d_in[15]};
    const float* ax_qkv_g[2] = {(const float*)d_in[8],  (const float*)d_in[16]};
    const float* ax_qkv_b[2] = {(const float*)d_in[9],  (const float*)d_in[17]};
    const float* ax_sim_g[2] = {(const float*)d_in[10], (const float*)d_in[18]};
    const float* ax_sim_b[2] = {(const float*)d_in[11], (const float*)d_in[19]};
    const float* ax_rel[2]   = {(const float*)d_in[12], (const float*)d_in[20]};
    const float* ax_out_g[2] = {(const float*)d_in[13], (const float*)d_in[21]};
    const float* ax_out_b[2] = {(const float*)d_in[14], (const float*)d_in[22]};
    const float* w_out    = (const float*)d_in[23];
    const float* cbn2_g   = (const float*)d_in[24];
    const float* cbn2_b   = (const float*)d_in[25];
    const float* cbn2_lin = (const float*)d_in[26];
    const float* prelu2   = (const float*)d_in[27];

    float* ws    = (float*)d_ws;
    float* out0  = ws + WS_R1;
    float* t1t   = ws + WS_R1 + 4194304;
    unsigned int* att2 = (unsigned int*)(ws + WS_R1);
    _Float16* qkvh = (_Float16*)(ws + WS_R2);
    float* t23   = ws + WS_R3;
    float* c2o   = ws + WS_R3;
    float* dst   = (float*)d_out;

    k_prep0<<<1, 256, 0, stream>>>(cbn1_lin, cbn2_lin, latent, ws);
    k_conv1<<<512, 256, 0, stream>>>(input, w_in, out0, ws + WS_STAT_C1);
    k_t1t<<<4096, 256, 0, stream>>>(out0, t1t, ws, cbn1_g, cbn1_b, prelu1);

    // axial 0 (n = b*128 + w, a = h)
    k_qkvm<<<512, 256, 0, stream>>>(t1t, ax_qkv_w[0], qkvh, ws + WS_STAT_QKV0,
                                    1048576, 8192, 128);
    k_coefq<<<1, 128, 0, stream>>>(ws + WS_STAT_QKV0, ax_qkv_g[0], ax_qkv_b[0], ws + WS_COEFQ0);
    k_passA<<<256, 512, 0, stream>>>(qkvh, ax_rel[0], ws + WS_COEFQ0, ws + WS_STAT_SIM0);
    k_passB<<<2048, 512, 0, stream>>>(qkvh, ax_rel[0], ws + WS_COEFQ0, ws + WS_STAT_SIM0,
                                      ax_sim_g[0], ax_sim_b[0], att2, ws + WS_STAT_OUT0);
    k_finish0<<<512, 256, 0, stream>>>(att2, ws + WS_STAT_OUT0, ax_out_g[0], ax_out_b[0], t23);

    // axial 1 (n = b*128 + h, a = w)
    k_qkvm<<<512, 256, 0, stream>>>(t23, ax_qkv_w[1], qkvh, ws + WS_STAT_QKV1,
                                    1048576, 128, 16384);
    k_coefq<<<1, 128, 0, stream>>>(ws + WS_STAT_QKV1, ax_qkv_g[1], ax_qkv_b[1], ws + WS_COEFQ1);
    k_passA<<<256, 512, 0, stream>>>(qkvh, ax_rel[1], ws + WS_COEFQ1, ws + WS_STAT_SIM1);
    k_passB<<<2048, 512, 0, stream>>>(qkvh, ax_rel[1], ws + WS_COEFQ1, ws + WS_STAT_SIM1,
                                      ax_sim_g[1], ax_sim_b[1], att2, ws + WS_STAT_OUT1);

    // tail
    k_conv2f<<<256, 64, 0, stream>>>(att2, ws + WS_STAT_OUT1, ax_out_g[1], ax_out_b[1],
                                     w_out, c2o, ws + WS_STAT_C2);
    k_final<<<1024, 256, 0, stream>>>(c2o, input, ws, cbn2_g, cbn2_b, prelu2, dst);
}

// Round 14
// 324.467 us; speedup vs baseline: 1.2676x; 1.0081x over previous
//
#include <hip/hip_runtime.h>

#define EPS 1e-5f
#define SP 16   // stat padding stride: one float per 64B line
#define SWA(x) ((((x) >> 2) & 3) << 3)

typedef __attribute__((ext_vector_type(4))) _Float16 h4;
typedef __attribute__((ext_vector_type(8))) _Float16 h8;
typedef __attribute__((ext_vector_type(4))) float f4;
typedef __attribute__((ext_vector_type(4))) unsigned int u4;

// ---- workspace float offsets. Stat arrays are SP-strided; coef arrays dense.
#define WS_SB1        0
#define WS_SB2        128
#define WS_STAT_C1    256
#define WS_STAT_QKV0  2304
#define WS_STAT_QKV1  6400
#define WS_STAT_SIM0  10496
#define WS_STAT_SIM1  10880
#define WS_STAT_OUT0  11264
#define WS_STAT_OUT1  15360
#define WS_STAT_C2    19456
#define WS_STAT_END   21504
#define WS_COEFQ0     21504   // 256 floats: A[128], B[128]
#define WS_COEFQ1     21760

// ---- buffer regions (float offsets) ----
#define WS_R1  32768
#define WS_R2  (WS_R1 + 8388608)
#define WS_R3  (WS_R2 + 8388608)

// sim-stat sample count: n % 8 == 0 -> 64 n * 16384 elems
#define SIM_CNT_INV (1.f / 1048576.f)

// ---- pass-kernel LDS byte offsets (80 KiB -> 2 blocks/CU) ----
#define L_QEA 0
#define L_KEB 32768
#define L_RET 65536
#define L_AQ  73728
#define L_AK  77824
#define L_V   73728

__device__ __forceinline__ float wred(float v) {
    #pragma unroll
    for (int off = 32; off > 0; off >>= 1) v += __shfl_down(v, off, 64);
    return v;
}

__global__ void k_prep0(const float* __restrict__ lin1, const float* __restrict__ lin2,
                        const float* __restrict__ latent, float* __restrict__ ws) {
    int t = threadIdx.x;
    for (int i = 256 + t; i < WS_STAT_END; i += 256) ws[i] = 0.f;
    const float* lin = (t < 128) ? lin1 : lin2;
    int row = t & 127;
    float s = 0.f;
    for (int l = 0; l < 256; ++l) s += lin[row * 256 + l] * latent[l];
    ws[(t < 128 ? WS_SB1 : WS_SB2) + row] = s;
}

// conv1, o-split x2 + fused out0-stats
__global__ __launch_bounds__(256) void k_conv1(const float* __restrict__ in,
                                               const float* __restrict__ w,
                                               float* __restrict__ out,
                                               float* __restrict__ stat) {
    __shared__ float ws_[2048];
    __shared__ float sred[2][4][32];
    int t = threadIdx.x;
    int lane = t & 63, wv = t >> 6;
    int oh = blockIdx.x & 1;
    int pb = blockIdx.x >> 1;
    for (int i = t; i < 2048; i += 256) ws_[i] = w[oh * 2048 + i];
    __syncthreads();
    int p  = pb * 256 + t;
    int b  = p >> 14, hw = p & 16383;
    const float* ip = in + b * 64 * 16384 + hw;
    float x[64];
    #pragma unroll
    for (int c = 0; c < 64; ++c) x[c] = ip[c * 16384];
    float* op = out + b * 64 * 16384 + hw + oh * 32 * 16384;
    for (int o2 = 0; o2 < 32; ++o2) {
        float acc = 0.f;
        #pragma unroll
        for (int c = 0; c < 64; ++c) acc += ws_[o2 * 64 + c] * x[c];
        op[o2 * 16384] = acc;
        float s = wred(acc), ss = wred(acc * acc);
        if (lane == 0) { sred[0][wv][o2] = s; sred[1][wv][o2] = ss; }
    }
    __syncthreads();
    if (t < 64) {
        int o2 = t & 31, st = t >> 5;
        float v = sred[st][0][o2] + sred[st][1][o2] + sred[st][2][o2] + sred[st][3][o2];
        atomicAdd(&stat[(st * 64 + oh * 32 + o2) * SP], v);
    }
}

// out0[b][c][h][w] -> t1t[b][w][c][h], inline cbn1 coef + prelu
__global__ __launch_bounds__(256) void k_t1t(const float* __restrict__ src, float* __restrict__ dst,
                                             const float* __restrict__ ws,
                                             const float* __restrict__ g1,
                                             const float* __restrict__ b1,
                                             const float* __restrict__ prelu1) {
    __shared__ float tile[32][33];
    int bid = blockIdx.x;
    int wt = bid & 3, ht = (bid >> 2) & 3, c = (bid >> 4) & 63, b = bid >> 10;
    float mean = ws[WS_STAT_C1 + c * SP] * (1.f / 65536.f);
    float var  = ws[WS_STAT_C1 + (64 + c) * SP] * (1.f / 65536.f) - mean * mean;
    float ab = g1[c] * rsqrtf(var + EPS);
    float sc = ws[WS_SB1 + c], bi = ws[WS_SB1 + 64 + c];
    float A = sc * ab;
    float Bb = sc * (b1[c] - mean * ab) + bi;
    float slope = *prelu1;
    int tx = threadIdx.x & 31, ty = threadIdx.x >> 5;
    const float* sp = src + ((b * 64 + c) * 128 + ht * 32) * 128 + wt * 32;
    for (int r = 0; r < 4; ++r) {
        float v = sp[(ty + r * 8) * 128 + tx];
        v = A * v + Bb;
        v = v >= 0.f ? v : slope * v;
        tile[ty + r * 8][tx] = v;
    }
    __syncthreads();
    float* dp = dst + b * 1048576 + (wt * 32) * 8192 + c * 128 + ht * 32;
    for (int r = 0; r < 4; ++r)
        dp[(ty + r * 8) * 8192 + tx] = tile[tx][ty + r * 8];
}

// MFMA qkv GEMM + fused SP-padded stats; XCD-swizzled n
__global__ __launch_bounds__(256) void k_qkvm(const float* __restrict__ x, const float* __restrict__ w,
                                              _Float16* __restrict__ out, float* __restrict__ statq,
                                              int SB, int SR, int SC) {
    __shared__ __align__(16) _Float16 Wh[8192];
    __shared__ __align__(16) _Float16 Xt[8192];
    int t = threadIdx.x;
    int lane = t & 63, wv = t >> 6;
    int l15 = lane & 15, g4 = lane >> 4;
    int n = (blockIdx.x & 7) * 64 + (blockIdx.x >> 3);
    int b = n >> 7, r = n & 127;
    for (int i = t; i < 8192; i += 256) {
        int o = i >> 6, c = i & 63;
        Wh[o * 64 + (c ^ ((o & 7) << 3))] = (_Float16)w[i];
    }
    const float* xp = x + b * SB + r * SR;
    for (int i = t; i < 8192; i += 256) {
        int c = i >> 7, a = i & 127;
        Xt[a * 64 + (c ^ ((a & 7) << 3))] = (_Float16)xp[c * SC + a];
    }
    __syncthreads();
    _Float16* op = out + n * 16384;
    float sA[2][4] = {{0.f,0.f,0.f,0.f},{0.f,0.f,0.f,0.f}};
    float qA[2][4] = {{0.f,0.f,0.f,0.f},{0.f,0.f,0.f,0.f}};
    #pragma unroll
    for (int ot2 = 0; ot2 < 2; ++ot2) {
        int orow = (wv * 2 + ot2) * 16 + l15;
        h8 af[2];
        #pragma unroll
        for (int kk = 0; kk < 2; ++kk)
            af[kk] = *(const h8*)&Wh[orow * 64 + ((kk * 32 + g4 * 8) ^ ((orow & 7) << 3))];
        #pragma unroll
        for (int at = 0; at < 8; ++at) {
            int arow = at * 16 + l15;
            f4 c4 = {0.f, 0.f, 0.f, 0.f};
            #pragma unroll
            for (int kk = 0; kk < 2; ++kk) {
                h8 bf = *(const h8*)&Xt[arow * 64 + ((kk * 32 + g4 * 8) ^ ((arow & 7) << 3))];
                c4 = __builtin_amdgcn_mfma_f32_16x16x32_f16(af[kk], bf, c4, 0, 0, 0);
            }
            #pragma unroll
            for (int r4 = 0; r4 < 4; ++r4) {
                int o = (wv * 2 + ot2) * 16 + g4 * 4 + r4;
                float v = c4[r4];
                op[o * 128 + at * 16 + l15] = (_Float16)v;
                sA[ot2][r4] += v; qA[ot2][r4] += v * v;
            }
        }
    }
    #pragma unroll
    for (int ot2 = 0; ot2 < 2; ++ot2)
        #pragma unroll
        for (int r4 = 0; r4 < 4; ++r4) {
            float s = sA[ot2][r4], ss = qA[ot2][r4];
            #pragma unroll
            for (int msk = 1; msk < 16; msk <<= 1) {
                s += __shfl_xor(s, msk, 64); ss += __shfl_xor(ss, msk, 64);
            }
            if (l15 == 0) {
                int o = (wv * 2 + ot2) * 16 + g4 * 4 + r4;
                atomicAdd(&statq[o * SP], s);
                atomicAdd(&statq[(128 + o) * SP], ss);
            }
        }
}

// qkv BN coef table
__global__ void k_coefq(const float* __restrict__ statq, const float* __restrict__ qg,
                        const float* __restrict__ qb, float* __restrict__ cq) {
    int c = threadIdx.x; if (c >= 128) return;
    float mean = statq[c * SP] * (1.f / 65536.f);
    float var  = statq[(128 + c) * SP] * (1.f / 65536.f) - mean * mean;
    float A = qg[c] * rsqrtf(var + EPS);
    cq[c] = A;
    cq[128 + c] = qb[c] - mean * A;
}

// ---- pass helpers (512 threads) ----
__device__ __forceinline__ void stage_aqk(unsigned char* L, const _Float16* qkv,
                                          const float* cq, int n, int g, int t) {
    const _Float16* qp = qkv + n * 16384 + g * 32 * 128;
    #pragma unroll
    for (int k = 0; k < 4; ++k) {
        int i = t + k * 512;
        int a = i & 127, cc = i >> 7;
        int ch = g * 32 + cc;
        float v = cq[ch] * (float)qp[cc * 128 + a] + cq[128 + ch];
        _Float16 h = (_Float16)v;
        int off = a * 32 + ((cc * 2) ^ SWA(a));
        *(_Float16*)(L + L_AQ + off) = (cc < 8) ? h : (_Float16)0.f;
        *(_Float16*)(L + L_AK + off) = (cc < 8) ? (_Float16)0.f : h;
    }
}

__device__ __forceinline__ void stage_ret(unsigned char* L, const float* remb, int crow0, int t) {
    #pragma unroll
    for (int k = 0; k < 8; ++k) {
        int i = t + k * 512;
        int d = i & 255, c = i >> 8;
        float v = (d < 255) ? remb[(crow0 + c) * 255 + d] : 0.f;
        *(_Float16*)(L + L_RET + d * 32 + ((c * 2) ^ SWA(d))) = (_Float16)v;
    }
}

template <bool STATS>
__device__ __forceinline__ void build_emb(unsigned char* L, int w, int l15, int g4, float* s) {
    int at = w;
    int arow = at * 16 + l15;
    int aoff = arow * 32 + ((g4 * 8) ^ SWA(arow));
    h4 aq = *(const h4*)(L + L_AQ + aoff);
    h4 ak = *(const h4*)(L + L_AK + aoff);
    int abase = at * 16 + g4 * 4;
    #pragma unroll
    for (int m = 0; m < 9; ++m) {
        int drow = (at + m) * 16 + l15;
        h4 bf = *(const h4*)(L + L_RET + drow * 32 + ((g4 * 8) ^ SWA(drow)));
        f4 z = {0.f, 0.f, 0.f, 0.f};
        f4 dq = __builtin_amdgcn_mfma_f32_16x16x16f16(aq, bf, z, 0, 0, 0);
        f4 dk = __builtin_amdgcn_mfma_f32_16x16x16f16(ak, bf, z, 0, 0, 0);
        #pragma unroll
        for (int r = 0; r < 4; ++r) {
            int a = abase + r;
            int b = 127 + a - drow;
            bool ok = (m == 0 || m == 8) ? (b >= 0 && b < 128) : true;
            if (ok) {
                int off = b * 256 + ((a * 2) ^ ((b & 7) << 4));
                *(_Float16*)(L + L_QEA + off) = (_Float16)dq[r];
                *(_Float16*)(L + L_KEB + off) = (_Float16)dk[r];
                if (STATS) {
                    s[0] += dq[r]; s[1] += dq[r] * dq[r];
                    s[2] += dk[r]; s[3] += dk[r] * dk[r];
                }
            }
        }
    }
}

__device__ __forceinline__ void qk_mfma(unsigned char* L, int i0, int l15, int g4, f4 acc[8]) {
    h8 af[4];
    #pragma unroll
    for (int ks = 0; ks < 4; ++ks) {
        int row = i0 + l15;
        af[ks] = *(const h8*)(L + L_QEA + row * 256 + ((ks * 64 + g4 * 16) ^ ((row & 7) << 4)));
    }
    #pragma unroll
    for (int tj = 0; tj < 8; ++tj) {
        h8 bf[4];
        #pragma unroll
        for (int ks = 0; ks < 4; ++ks) {
            int row = tj * 16 + l15;
            bf[ks] = *(const h8*)(L + L_KEB + row * 256 + ((ks * 64 + g4 * 16) ^ ((row & 7) << 4)));
        }
        f4 c = {0.f, 0.f, 0.f, 0.f};
        #pragma unroll
        for (int ks = 0; ks < 4; ++ks)
            c = __builtin_amdgcn_mfma_f32_16x16x32_f16(af[ks], bf[ks], c, 0, 0, 0);
        acc[tj] = c;
    }
}

// passA (SAMPLED 1/8): 256 blocks
__global__ __launch_bounds__(512, 4) void k_passA(const _Float16* __restrict__ qkv,
                                                  const float* __restrict__ remb,
                                                  const float* __restrict__ cq,
                                                  float* __restrict__ statsim) {
    __shared__ __align__(16) unsigned char L[81920];
    int t = threadIdx.x;
    int lane = t & 63, w = t >> 6;
    int l15 = lane & 15, g4 = lane >> 4;
    int ts = (blockIdx.x & 7) * 32 + (blockIdx.x >> 3);
    int n = (ts >> 2) * 8, g = ts & 3;

    stage_aqk(L, qkv, cq, n, g, t);
    stage_ret(L, remb, 0, t);
    __syncthreads();

    float es[4] = {0.f, 0.f, 0.f, 0.f};
    build_emb<true>(L, w, l15, g4, es);
    __syncthreads();

    float* red = (float*)(L + L_AK);
    #pragma unroll
    for (int k = 0; k < 4; ++k) es[k] = wred(es[k]);
    if (lane == 0) {
        red[w * 4 + 0] = es[0]; red[w * 4 + 1] = es[1];
        red[w * 4 + 2] = es[2]; red[w * 4 + 3] = es[3];
    }

    f4 acc[8];
    qk_mfma(L, w * 16, l15, g4, acc);

    float s = 0.f, ss = 0.f;
    #pragma unroll
    for (int tj = 0; tj < 8; ++tj)
        #pragma unroll
        for (int r = 0; r < 4; ++r) { float x = acc[tj][r]; s += x; ss += x * x; }
    s = wred(s); ss = wred(ss);
    if (lane == 0) { red[32 + w * 2] = s; red[33 + w * 2] = ss; }
    __syncthreads();

    if (t < 6) {
        float v = 0.f;
        int dst;
        if (t == 0)      { for (int k = 0; k < 8; ++k) v += red[32 + 2 * k]; dst = g; }
        else if (t == 1) { for (int k = 0; k < 8; ++k) v += red[33 + 2 * k]; dst = 12 + g; }
        else if (t == 2) { for (int k = 0; k < 8; ++k) v += red[k * 4 + 0];  dst = 4 + g; }
        else if (t == 3) { for (int k = 0; k < 8; ++k) v += red[k * 4 + 1];  dst = 16 + g; }
        else if (t == 4) { for (int k = 0; k < 8; ++k) v += red[k * 4 + 2];  dst = 8 + g; }
        else             { for (int k = 0; k < 8; ++k) v += red[k * 4 + 3];  dst = 20 + g; }
        atomicAdd(&statsim[dst * SP], v);
    }
}

// passB: 5-barrier schedule + slot-trimmed ame (5 of 8 k-slots valid per wave)
__global__ __launch_bounds__(512, 4) void k_passB(const _Float16* __restrict__ qkv,
                                                  const float* __restrict__ remb,
                                                  const float* __restrict__ cq,
                                                  const float* __restrict__ statsim,
                                                  const float* __restrict__ simg,
                                                  const float* __restrict__ simb,
                                                  unsigned int* __restrict__ att2,
                                                  float* __restrict__ statout) {
    __shared__ __align__(16) unsigned char L[81920];
    int t = threadIdx.x;
    int lane = t & 63, w = t >> 6;
    int l15 = lane & 15, g4 = lane >> 4;
    int s0 = (blockIdx.x & 7) * 256 + (blockIdx.x >> 3);
    int n = s0 >> 2, g = s0 & 3;

    stage_aqk(L, qkv, cq, n, g, t);
    stage_ret(L, remb, 0, t);
    __syncthreads();                               // B1

    build_emb<false>(L, w, l15, g4, nullptr);
    __syncthreads();                               // B2

    #pragma unroll
    for (int k = 0; k < 4; ++k) {
        int i = t + k * 512;
        int j = i & 127, c = i >> 7;
        int ch = g * 32 + 16 + c;
        float v = cq[ch] * (float)qkv[n * 16384 + ch * 128 + j] + cq[128 + ch];
        *(_Float16*)(L + L_V + c * 256 + ((j * 2) ^ ((c & 7) << 4))) = (_Float16)v;
    }
    #pragma unroll
    for (int k = 0; k < 8; ++k) {
        int i = t + k * 512;
        int d = i & 255, c = i >> 8;
        float v = (d < 255) ? remb[(16 + c) * 255 + d] : 0.f;
        *(_Float16*)(L + L_RET + c * 512 + ((d * 2) ^ ((c & 7) << 4))) = (_Float16)v;
    }

    int i0 = w * 16;
    f4 acc[8];
    qk_mfma(L, i0, l15, g4, acc);

    float Aqk, Aqe, Ake, Cst = 0.f;
    {
        float A3[3];
        #pragma unroll
        for (int k = 0; k < 3; ++k) {
            int ch = k * 4 + g;
            float mean = statsim[ch * SP] * SIM_CNT_INV;
            float var  = statsim[(12 + ch) * SP] * SIM_CNT_INV - mean * mean;
            float A = simg[ch] * rsqrtf(var + EPS);
            A3[k] = A;
            Cst += simb[ch] - mean * A;
        }
        Aqk = A3[0]; Aqe = A3[1]; Ake = A3[2];
    }
    int ib = (i0 + g4 * 4) * 2;
    #pragma unroll
    for (int tj = 0; tj < 8; ++tj) {
        int j = tj * 16 + l15;
        h4 q4 = *(const h4*)(L + L_QEA + j * 256 + (ib ^ ((j & 7) << 4)));
        h4 k4 = *(const h4*)(L + L_KEB + j * 256 + (ib ^ ((j & 7) << 4)));
        #pragma unroll
        for (int r = 0; r < 4; ++r)
            acc[tj][r] = Aqk * acc[tj][r] + Aqe * (float)q4[r] + Ake * (float)k4[r] + Cst;
    }

    float inv4[4];
    #pragma unroll
    for (int r = 0; r < 4; ++r) {
        float m = acc[0][r];
        #pragma unroll
        for (int tj = 1; tj < 8; ++tj) m = fmaxf(m, acc[tj][r]);
        #pragma unroll
        for (int msk = 1; msk < 16; msk <<= 1) m = fmaxf(m, __shfl_xor(m, msk, 64));
        float s = 0.f;
        #pragma unroll
        for (int tj = 0; tj < 8; ++tj) {
            float e = __expf(acc[tj][r] - m);
            acc[tj][r] = e; s += e;
        }
        #pragma unroll
        for (int msk = 1; msk < 16; msk <<= 1) s += __shfl_xor(s, msk, 64);
        inv4[r] = 1.f / s;
    }

    _Float16 ph[4][8];
    #pragma unroll
    for (int r = 0; r < 4; ++r)
        #pragma unroll
        for (int tj = 0; tj < 8; ++tj)
            ph[r][tj] = (_Float16)(acc[tj][r] * inv4[r]);
    __syncthreads();                               // B3

    int lo = w >> 1;               // first valid ame k-slot for this wave
    int lo2 = (w >> 2) << 1;       // pair-aligned zero-fill base slot

    // P -> own rows; waves 4-7 also build own Pd-hi rows
    #pragma unroll
    for (int r = 0; r < 4; ++r) {
        int i = i0 + g4 * 4 + r;
        int swz = (i & 7) << 4;
        #pragma unroll
        for (int tj = 0; tj < 8; ++tj) {
            int j = tj * 16 + l15;
            *(_Float16*)(L + L_QEA + i * 256 + ((j * 2) ^ swz)) = ph[r][tj];
        }
    }
    if (w >= 4) {
        #pragma unroll
        for (int u = 0; u < 6; ++u) {
            u4 zz = {0u, 0u, 0u, 0u};
            *(u4*)(L + w * 8192 + (lane >> 2) * 512 + lo2 * 64 + ((u * 4 + (lane & 3)) << 4)) = zz;
        }
        #pragma unroll
        for (int r = 0; r < 4; ++r) {
            int i = i0 + g4 * 4 + r;
            int swz = (i & 7) << 4;
            #pragma unroll
            for (int tj = 0; tj < 8; ++tj) {
                int j = tj * 16 + l15;
                int d = 127 + i - j;
                *(_Float16*)(L + i * 512 + ((d * 2) ^ swz)) = ph[r][tj];
            }
        }
    }
    // no barrier: am reads only own-wave P rows

    h8 vf[4];
    #pragma unroll
    for (int ks = 0; ks < 4; ++ks)
        vf[ks] = *(const h8*)(L + L_V + l15 * 256 + ((ks * 64 + g4 * 16) ^ ((l15 & 7) << 4)));
    int row = i0 + l15;
    int sw = (row & 7) << 4;
    f4 cam = {0.f, 0.f, 0.f, 0.f};
    #pragma unroll
    for (int ks = 0; ks < 4; ++ks) {
        h8 pf = *(const h8*)(L + L_QEA + row * 256 + ((ks * 64 + g4 * 16) ^ sw));
        cam = __builtin_amdgcn_mfma_f32_16x16x32_f16(vf[ks], pf, cam, 0, 0, 0);
    }
    __syncthreads();   // B4

    if (w < 4) {
        #pragma unroll
        for (int u = 0; u < 6; ++u) {
            u4 zz = {0u, 0u, 0u, 0u};
            *(u4*)(L + w * 8192 + (lane >> 2) * 512 + lo2 * 64 + ((u * 4 + (lane & 3)) << 4)) = zz;
        }
        #pragma unroll
        for (int r = 0; r < 4; ++r) {
            int i = i0 + g4 * 4 + r;
            int swz = (i & 7) << 4;
            #pragma unroll
            for (int tj = 0; tj < 8; ++tj) {
                int j = tj * 16 + l15;
                int d = 127 + i - j;
                *(_Float16*)(L + i * 512 + ((d * 2) ^ swz)) = ph[r][tj];
            }
        }
    }
    // no barrier: ame reads only own-wave Pd rows

    // ame over 5 valid k-slots {lo..lo+4}
    h8 vef[5];
    #pragma unroll
    for (int u = 0; u < 5; ++u) {
        int ks = lo + u;
        vef[u] = *(const h8*)(L + L_RET + l15 * 512 + ((ks * 64 + g4 * 16) ^ ((l15 & 7) << 4)));
    }
    f4 cae = {0.f, 0.f, 0.f, 0.f};
    #pragma unroll
    for (int u = 0; u < 5; ++u) {
        int ks = lo + u;
        h8 phf = *(const h8*)(L + row * 512 + ((ks * 64 + g4 * 16) ^ sw));
        cae = __builtin_amdgcn_mfma_f32_16x16x32_f16(vef[u], phf, cae, 0, 0, 0);
    }

    unsigned int* attL = (unsigned int*)(L + L_V);
    int i = i0 + l15;
    #pragma unroll
    for (int r = 0; r < 4; ++r) {
        union { _Float16 h[2]; unsigned int u; } pk;
        pk.h[0] = (_Float16)cam[r];
        pk.h[1] = (_Float16)cae[r];
        attL[(g4 * 4 + r) * 128 + i] = pk.u;
    }

    float* sredW = (float*)(L + w * 8192);
    #pragma unroll
    for (int r = 0; r < 4; ++r) {
        float sa = cam[r], qa = cam[r] * cam[r];
        float se = cae[r], qe = cae[r] * cae[r];
        #pragma unroll
        for (int msk = 1; msk < 16; msk <<= 1) {
            sa += __shfl_xor(sa, msk, 64); qa += __shfl_xor(qa, msk, 64);
            se += __shfl_xor(se, msk, 64); qe += __shfl_xor(qe, msk, 64);
        }
        if (l15 == 0) {
            int base = g4 * 16 + r * 4;
            sredW[base + 0] = sa; sredW[base + 1] = qa;
            sredW[base + 2] = se; sredW[base + 3] = qe;
        }
    }
    __syncthreads();                               // B5

    unsigned int* ab = att2 + n * 8192 + g * 2048;
    *(u4*)(ab + t * 4) = *(const u4*)(attL + t * 4);

    if (t < 64) {
        int lc = t & 31, stat = t >> 5;
        int c = lc >> 1, s = lc & 1;
        int gg4 = c >> 2, r = c & 3;
        float v = 0.f;
        #pragma unroll
        for (int ww = 0; ww < 8; ++ww)
            v += ((const float*)L)[ww * 2048 + gg4 * 16 + r * 4 + 2 * s + stat];
        atomicAdd(&statout[(stat * 128 + g * 32 + lc) * SP], v);
    }
}

// axial0 finish
__global__ __launch_bounds__(256) void k_finish0(const unsigned int* __restrict__ att2,
                                                 const float* __restrict__ statout,
                                                 const float* __restrict__ og,
                                                 const float* __restrict__ ob,
                                                 float* __restrict__ t2) {
    __shared__ float tile[8][32][33];
    __shared__ float cf[256];
    int t = threadIdx.x;
    if (t < 128) {
        float mean = statout[t * SP] * (1.f / 65536.f);
        float var  = statout[(128 + t) * SP] * (1.f / 65536.f) - mean * mean;
        float A = og[t] * rsqrtf(var + EPS);
        cf[t] = A;
        cf[128 + t] = ob[t] - mean * A;
    }
    __syncthreads();
    int bid = blockIdx.x;
    int wt = bid & 3, ht = (bid >> 2) & 3, cg = (bid >> 4) & 7, b = bid >> 7;
    for (int i = t; i < 8192; i += 256) {
        int h = i & 31, w = (i >> 5) & 31, cl = i >> 10;
        int c_out = cg * 8 + cl;
        int chg = (c_out >> 4) * 32 + (c_out & 15) * 2;
        int p = chg >> 1;
        union { unsigned int u; _Float16 h2[2]; } pk;
        pk.u = att2[((b * 128 + wt * 32 + w) * 64 + p) * 128 + ht * 32 + h];
        tile[cl][w][h] = cf[chg] * (float)pk.h2[0] + cf[128 + chg]
                       + cf[chg + 1] * (float)pk.h2[1] + cf[129 + chg];
    }
    __syncthreads();
    for (int i = t; i < 8192; i += 256) {
        int w = i & 31, h = (i >> 5) & 31, cl = i >> 10;
        t2[((b * 64 + cg * 8 + cl) * 128 + ht * 32 + h) * 128 + wt * 32 + w] = tile[cl][w][h];
    }
}

// conv2 fused
__global__ __launch_bounds__(64) void k_conv2f(const unsigned int* __restrict__ att2,
                                               const float* __restrict__ statout,
                                               const float* __restrict__ og,
                                               const float* __restrict__ ob,
                                               const float* __restrict__ w,
                                               float* __restrict__ out,
                                               float* __restrict__ statc2) {
    __shared__ float ws_[4096];
    __shared__ float cf[4][64];
    __shared__ float otile[64][65];
    int t = threadIdx.x;
    for (int i = t; i < 4096; i += 64) ws_[i] = w[i];
    {
        int chg = (t >> 4) * 32 + (t & 15) * 2;
        float m0 = statout[chg * SP] * (1.f / 65536.f);
        float v0 = statout[(128 + chg) * SP] * (1.f / 65536.f) - m0 * m0;
        float A0 = og[chg] * rsqrtf(v0 + EPS);
        cf[0][t] = A0; cf[1][t] = ob[chg] - m0 * A0;
        float m1 = statout[(chg + 1) * SP] * (1.f / 65536.f);
        float v1 = statout[(129 + chg) * SP] * (1.f / 65536.f) - m1 * m1;
        float A1 = og[chg + 1] * rsqrtf(v1 + EPS);
        cf[2][t] = A1; cf[3][t] = ob[chg + 1] - m1 * A1;
    }
    __syncthreads();
    int p = blockIdx.x * 64 + t;
    int b = p >> 12, yx = p & 4095, y = yx >> 6, x = yx & 63;
    const unsigned int* ap = att2 + (b * 128 + 2 * y) * 8192 + 2 * x;
    float xc[64];
    #pragma unroll
    for (int c = 0; c < 64; ++c) {
        int pp = (c >> 4) * 16 + (c & 15);
        const unsigned int* q = ap + pp * 128;
        union { unsigned int u; _Float16 h2[2]; } a0, a1, a2, a3;
        a0.u = q[0]; a1.u = q[1]; a2.u = q[8192]; a3.u = q[8193];
        float s0 = (float)a0.h2[0] + (float)a1.h2[0] + (float)a2.h2[0] + (float)a3.h2[0];
        float s1 = (float)a0.h2[1] + (float)a1.h2[1] + (float)a2.h2[1] + (float)a3.h2[1];
        xc[c] = 0.25f * (cf[0][c] * s0 + cf[2][c] * s1) + cf[1][c] + cf[3][c];
    }
    float* op = out + b * 262144 + yx;
    for (int o = 0; o < 64; ++o) {
        float acc = 0.f;
        #pragma unroll
        for (int c = 0; c < 64; ++c) acc += ws_[o * 64 + c] * xc[c];
        op[o * 4096] = acc;
        otile[o][t] = acc;
    }
    __syncthreads();
    float s = 0.f, ss = 0.f;
    #pragma unroll
    for (int k = 0; k < 64; ++k) { float v = otile[t][k]; s += v; ss += v * v; }
    atomicAdd(&statc2[t * SP], s);
    atomicAdd(&statc2[(64 + t) * SP], ss);
}

// final: cbn2 + residual + prelu, 4x vectorized
__global__ __launch_bounds__(256) void k_final(const float* __restrict__ c2out,
                                               const float* __restrict__ input,
                                               const float* __restrict__ ws,
                                               const float* __restrict__ g2,
                                               const float* __restrict__ b2,
                                               const float* __restrict__ prelu2,
                                               float* __restrict__ out) {
    int q = blockIdx.x * 256 + threadIdx.x;
    int x4 = (q & 15) << 2, y = (q >> 4) & 63, o = (q >> 10) & 63, b = q >> 16;
    float mean = ws[WS_STAT_C2 + o * SP] * (1.f / 16384.f);
    float var  = ws[WS_STAT_C2 + (64 + o) * SP] * (1.f / 16384.f) - mean * mean;
    float ab = g2[o] * rsqrtf(var + EPS);
    float sc = ws[WS_SB2 + o], bi = ws[WS_SB2 + 64 + o];
    float A = sc * ab;
    float B = sc * (b2[o] - mean * ab) + bi;
    float slope = *prelu2;
    int base = ((b * 64 + o) * 64 + y) * 64 + x4;
    float4 c = *(const float4*)&c2out[base];
    const float* ip = input + ((b * 64 + o) * 128 + 2 * y) * 128 + 2 * x4;
    float4 r0a = *(const float4*)&ip[0];
    float4 r0b = *(const float4*)&ip[4];
    float4 r1a = *(const float4*)&ip[128];
    float4 r1b = *(const float4*)&ip[132];
    float4 r;
    float v0 = A * c.x + B + 0.25f * (r0a.x + r0a.y + r1a.x + r1a.y);
    float v1 = A * c.y + B + 0.25f * (r0a.z + r0a.w + r1a.z + r1a.w);
    float v2 = A * c.z + B + 0.25f * (r0b.x + r0b.y + r1b.x + r1b.y);
    float v3 = A * c.w + B + 0.25f * (r0b.z + r0b.w + r1b.z + r1b.w);
    r.x = v0 >= 0.f ? v0 : slope * v0;
    r.y = v1 >= 0.f ? v1 : slope * v1;
    r.z = v2 >= 0.f ? v2 : slope * v2;
    r.w = v3 >= 0.f ? v3 : slope * v3;
    *(float4*)&out[base] = r;
}

extern "C" void kernel_launch(void* const* d_in, const int* in_sizes, int n_in,
                              void* d_out, int out_size, void* d_ws, size_t ws_size,
                              hipStream_t stream) {
    const float* input    = (const float*)d_in[0];
    const float* latent   = (const float*)d_in[1];
    const float* w_in     = (const float*)d_in[2];
    const float* cbn1_g   = (const float*)d_in[3];
    const float* cbn1_b   = (const float*)d_in[4];
    const float* cbn1_lin = (const float*)d_in[5];
    const float* prelu1   = (const float*)d_in[6];
    const float* ax_qkv_w[2] = {(const float*)d_in[7],  (const float*)d_in[15]};
    const float* ax_qkv_g[2] = {(const float*)d_in[8],  (const float*)d_in[16]};
    const float* ax_qkv_b[2] = {(const float*)d_in[9],  (const float*)d_in[17]};
    const float* ax_sim_g[2] = {(const float*)d_in[10], (const float*)d_in[18]};
    const float* ax_sim_b[2] = {(const float*)d_in[11], (const float*)d_in[19]};
    const float* ax_rel[2]   = {(const float*)d_in[12], (const float*)d_in[20]};
    const float* ax_out_g[2] = {(const float*)d_in[13], (const float*)d_in[21]};
    const float* ax_out_b[2] = {(const float*)d_in[14], (const float*)d_in[22]};
    const float* w_out    = (const float*)d_in[23];
    const float* cbn2_g   = (const float*)d_in[24];
    const float* cbn2_b   = (const float*)d_in[25];
    const float* cbn2_lin = (const float*)d_in[26];
    const float* prelu2   = (const float*)d_in[27];

    float* ws    = (float*)d_ws;
    float* out0  = ws + WS_R1;
    float* t1t   = ws + WS_R1 + 4194304;
    unsigned int* att2 = (unsigned int*)(ws + WS_R1);
    _Float16* qkvh = (_Float16*)(ws + WS_R2);
    float* t23   = ws + WS_R3;
    float* c2o   = ws + WS_R3;
    float* dst   = (float*)d_out;

    k_prep0<<<1, 256, 0, stream>>>(cbn1_lin, cbn2_lin, latent, ws);
    k_conv1<<<512, 256, 0, stream>>>(input, w_in, out0, ws + WS_STAT_C1);
    k_t1t<<<4096, 256, 0, stream>>>(out0, t1t, ws, cbn1_g, cbn1_b, prelu1);

    // axial 0 (n = b*128 + w, a = h)
    k_qkvm<<<512, 256, 0, stream>>>(t1t, ax_qkv_w[0], qkvh, ws + WS_STAT_QKV0,
                                    1048576, 8192, 128);
    k_coefq<<<1, 128, 0, stream>>>(ws + WS_STAT_QKV0, ax_qkv_g[0], ax_qkv_b[0], ws + WS_COEFQ0);
    k_passA<<<256, 512, 0, stream>>>(qkvh, ax_rel[0], ws + WS_COEFQ0, ws + WS_STAT_SIM0);
    k_passB<<<2048, 512, 0, stream>>>(qkvh, ax_rel[0], ws + WS_COEFQ0, ws + WS_STAT_SIM0,
                                      ax_sim_g[0], ax_sim_b[0], att2, ws + WS_STAT_OUT0);
    k_finish0<<<512, 256, 0, stream>>>(att2, ws + WS_STAT_OUT0, ax_out_g[0], ax_out_b[0], t23);

    // axial 1 (n = b*128 + h, a = w)
    k_qkvm<<<512, 256, 0, stream>>>(t23, ax_qkv_w[1], qkvh, ws + WS_STAT_QKV1,
                                    1048576, 128, 16384);
    k_coefq<<<1, 128, 0, stream>>>(ws + WS_STAT_QKV1, ax_qkv_g[1], ax_qkv_b[1], ws + WS_COEFQ1);
    k_passA<<<256, 512, 0, stream>>>(qkvh, ax_rel[1], ws + WS_COEFQ1, ws + WS_STAT_SIM1);
    k_passB<<<2048, 512, 0, stream>>>(qkvh, ax_rel[1], ws + WS_COEFQ1, ws + WS_STAT_SIM1,
                                      ax_sim_g[1], ax_sim_b[1], att2, ws + WS_STAT_OUT1);

    // tail
    k_conv2f<<<256, 64, 0, stream>>>(att2, ws + WS_STAT_OUT1, ax_out_g[1], ax_out_b[1],
                                     w_out, c2o, ws + WS_STAT_C2);
    k_final<<<1024, 256, 0, stream>>>(c2o, input, ws, cbn2_g, cbn2_b, prelu2, dst);
}

// Round 15
// 308.044 us; speedup vs baseline: 1.3352x; 1.0533x over previous
//
#include <hip/hip_runtime.h>

#define EPS 1e-5f
#define SP 16   // stat padding stride: one float per 64B line
#define SWA(x) ((((x) >> 2) & 3) << 3)

typedef __attribute__((ext_vector_type(4))) _Float16 h4;
typedef __attribute__((ext_vector_type(8))) _Float16 h8;
typedef __attribute__((ext_vector_type(4))) float f4;
typedef __attribute__((ext_vector_type(4))) unsigned int u4;

// ---- workspace float offsets. Stat arrays are SP-strided; coef arrays dense.
#define WS_SB1        0
#define WS_SB2        128
#define WS_STAT_C1    256
#define WS_STAT_QKV0  2304
#define WS_STAT_QKV1  6400
#define WS_STAT_SIM0  10496
#define WS_STAT_SIM1  10880
#define WS_STAT_OUT0  11264
#define WS_STAT_OUT1  15360
#define WS_STAT_C2    19456
#define WS_STAT_END   21504
#define WS_COEFQ0     21504   // 256 floats: A[128], B[128]
#define WS_COEFQ1     21760

// ---- buffer regions (float offsets) ----
#define WS_R1  32768
#define WS_R2  (WS_R1 + 8388608)
#define WS_R3  (WS_R2 + 8388608)

// sim-stat sample count: n % 8 == 0 -> 64 n * 16384 elems
#define SIM_CNT_INV (1.f / 1048576.f)

// ---- pass-kernel LDS byte offsets (80 KiB -> 2 blocks/CU) ----
#define L_QEA 0
#define L_KEB 32768
#define L_RET 65536
#define L_AQ  73728
#define L_AK  77824
#define L_V   73728

__device__ __forceinline__ float wred(float v) {
    #pragma unroll
    for (int off = 32; off > 0; off >>= 1) v += __shfl_down(v, off, 64);
    return v;
}

__global__ void k_prep0(const float* __restrict__ lin1, const float* __restrict__ lin2,
                        const float* __restrict__ latent, float* __restrict__ ws) {
    int t = threadIdx.x;
    for (int i = 256 + t; i < WS_STAT_END; i += 256) ws[i] = 0.f;
    const float* lin = (t < 128) ? lin1 : lin2;
    int row = t & 127;
    float s = 0.f;
    for (int l = 0; l < 256; ++l) s += lin[row * 256 + l] * latent[l];
    ws[(t < 128 ? WS_SB1 : WS_SB2) + row] = s;
}

// conv1, o-split x2 + fused out0-stats
__global__ __launch_bounds__(256) void k_conv1(const float* __restrict__ in,
                                               const float* __restrict__ w,
                                               float* __restrict__ out,
                                               float* __restrict__ stat) {
    __shared__ float ws_[2048];
    __shared__ float sred[2][4][32];
    int t = threadIdx.x;
    int lane = t & 63, wv = t >> 6;
    int oh = blockIdx.x & 1;
    int pb = blockIdx.x >> 1;
    for (int i = t; i < 2048; i += 256) ws_[i] = w[oh * 2048 + i];
    __syncthreads();
    int p  = pb * 256 + t;
    int b  = p >> 14, hw = p & 16383;
    const float* ip = in + b * 64 * 16384 + hw;
    float x[64];
    #pragma unroll
    for (int c = 0; c < 64; ++c) x[c] = ip[c * 16384];
    float* op = out + b * 64 * 16384 + hw + oh * 32 * 16384;
    for (int o2 = 0; o2 < 32; ++o2) {
        float acc = 0.f;
        #pragma unroll
        for (int c = 0; c < 64; ++c) acc += ws_[o2 * 64 + c] * x[c];
        op[o2 * 16384] = acc;
        float s = wred(acc), ss = wred(acc * acc);
        if (lane == 0) { sred[0][wv][o2] = s; sred[1][wv][o2] = ss; }
    }
    __syncthreads();
    if (t < 64) {
        int o2 = t & 31, st = t >> 5;
        float v = sred[st][0][o2] + sred[st][1][o2] + sred[st][2][o2] + sred[st][3][o2];
        atomicAdd(&stat[(st * 64 + oh * 32 + o2) * SP], v);
    }
}

// out0[b][c][h][w] -> t1t[b][w][c][h], inline cbn1 coef + prelu
__global__ __launch_bounds__(256) void k_t1t(const float* __restrict__ src, float* __restrict__ dst,
                                             const float* __restrict__ ws,
                                             const float* __restrict__ g1,
                                             const float* __restrict__ b1,
                                             const float* __restrict__ prelu1) {
    __shared__ float tile[32][33];
    int bid = blockIdx.x;
    int wt = bid & 3, ht = (bid >> 2) & 3, c = (bid >> 4) & 63, b = bid >> 10;
    float mean = ws[WS_STAT_C1 + c * SP] * (1.f / 65536.f);
    float var  = ws[WS_STAT_C1 + (64 + c) * SP] * (1.f / 65536.f) - mean * mean;
    float ab = g1[c] * rsqrtf(var + EPS);
    float sc = ws[WS_SB1 + c], bi = ws[WS_SB1 + 64 + c];
    float A = sc * ab;
    float Bb = sc * (b1[c] - mean * ab) + bi;
    float slope = *prelu1;
    int tx = threadIdx.x & 31, ty = threadIdx.x >> 5;
    const float* sp = src + ((b * 64 + c) * 128 + ht * 32) * 128 + wt * 32;
    for (int r = 0; r < 4; ++r) {
        float v = sp[(ty + r * 8) * 128 + tx];
        v = A * v + Bb;
        v = v >= 0.f ? v : slope * v;
        tile[ty + r * 8][tx] = v;
    }
    __syncthreads();
    float* dp = dst + b * 1048576 + (wt * 32) * 8192 + c * 128 + ht * 32;
    for (int r = 0; r < 4; ++r)
        dp[(ty + r * 8) * 8192 + tx] = tile[tx][ty + r * 8];
}

// MFMA qkv GEMM + fused SP-padded stats; XCD-swizzled n
__global__ __launch_bounds__(256) void k_qkvm(const float* __restrict__ x, const float* __restrict__ w,
                                              _Float16* __restrict__ out, float* __restrict__ statq,
                                              int SB, int SR, int SC) {
    __shared__ __align__(16) _Float16 Wh[8192];
    __shared__ __align__(16) _Float16 Xt[8192];
    int t = threadIdx.x;
    int lane = t & 63, wv = t >> 6;
    int l15 = lane & 15, g4 = lane >> 4;
    int n = (blockIdx.x & 7) * 64 + (blockIdx.x >> 3);
    int b = n >> 7, r = n & 127;
    for (int i = t; i < 8192; i += 256) {
        int o = i >> 6, c = i & 63;
        Wh[o * 64 + (c ^ ((o & 7) << 3))] = (_Float16)w[i];
    }
    const float* xp = x + b * SB + r * SR;
    for (int i = t; i < 8192; i += 256) {
        int c = i >> 7, a = i & 127;
        Xt[a * 64 + (c ^ ((a & 7) << 3))] = (_Float16)xp[c * SC + a];
    }
    __syncthreads();
    _Float16* op = out + n * 16384;
    float sA[2][4] = {{0.f,0.f,0.f,0.f},{0.f,0.f,0.f,0.f}};
    float qA[2][4] = {{0.f,0.f,0.f,0.f},{0.f,0.f,0.f,0.f}};
    #pragma unroll
    for (int ot2 = 0; ot2 < 2; ++ot2) {
        int orow = (wv * 2 + ot2) * 16 + l15;
        h8 af[2];
        #pragma unroll
        for (int kk = 0; kk < 2; ++kk)
            af[kk] = *(const h8*)&Wh[orow * 64 + ((kk * 32 + g4 * 8) ^ ((orow & 7) << 3))];
        #pragma unroll
        for (int at = 0; at < 8; ++at) {
            int arow = at * 16 + l15;
            f4 c4 = {0.f, 0.f, 0.f, 0.f};
            #pragma unroll
            for (int kk = 0; kk < 2; ++kk) {
                h8 bf = *(const h8*)&Xt[arow * 64 + ((kk * 32 + g4 * 8) ^ ((arow & 7) << 3))];
                c4 = __builtin_amdgcn_mfma_f32_16x16x32_f16(af[kk], bf, c4, 0, 0, 0);
            }
            #pragma unroll
            for (int r4 = 0; r4 < 4; ++r4) {
                int o = (wv * 2 + ot2) * 16 + g4 * 4 + r4;
                float v = c4[r4];
                op[o * 128 + at * 16 + l15] = (_Float16)v;
                sA[ot2][r4] += v; qA[ot2][r4] += v * v;
            }
        }
    }
    #pragma unroll
    for (int ot2 = 0; ot2 < 2; ++ot2)
        #pragma unroll
        for (int r4 = 0; r4 < 4; ++r4) {
            float s = sA[ot2][r4], ss = qA[ot2][r4];
            #pragma unroll
            for (int msk = 1; msk < 16; msk <<= 1) {
                s += __shfl_xor(s, msk, 64); ss += __shfl_xor(ss, msk, 64);
            }
            if (l15 == 0) {
                int o = (wv * 2 + ot2) * 16 + g4 * 4 + r4;
                atomicAdd(&statq[o * SP], s);
                atomicAdd(&statq[(128 + o) * SP], ss);
            }
        }
}

// qkv BN coef table
__global__ void k_coefq(const float* __restrict__ statq, const float* __restrict__ qg,
                        const float* __restrict__ qb, float* __restrict__ cq) {
    int c = threadIdx.x; if (c >= 128) return;
    float mean = statq[c * SP] * (1.f / 65536.f);
    float var  = statq[(128 + c) * SP] * (1.f / 65536.f) - mean * mean;
    float A = qg[c] * rsqrtf(var + EPS);
    cq[c] = A;
    cq[128 + c] = qb[c] - mean * A;
}

// ---- pass helpers (512 threads) ----
__device__ __forceinline__ void stage_aqk(unsigned char* L, const _Float16* qkv,
                                          const float* cq, int n, int g, int t) {
    const _Float16* qp = qkv + n * 16384 + g * 32 * 128;
    #pragma unroll
    for (int k = 0; k < 4; ++k) {
        int i = t + k * 512;
        int a = i & 127, cc = i >> 7;
        int ch = g * 32 + cc;
        float v = cq[ch] * (float)qp[cc * 128 + a] + cq[128 + ch];
        _Float16 h = (_Float16)v;
        int off = a * 32 + ((cc * 2) ^ SWA(a));
        *(_Float16*)(L + L_AQ + off) = (cc < 8) ? h : (_Float16)0.f;
        *(_Float16*)(L + L_AK + off) = (cc < 8) ? (_Float16)0.f : h;
    }
}

__device__ __forceinline__ void stage_ret(unsigned char* L, const float* remb, int crow0, int t) {
    #pragma unroll
    for (int k = 0; k < 8; ++k) {
        int i = t + k * 512;
        int d = i & 255, c = i >> 8;
        float v = (d < 255) ? remb[(crow0 + c) * 255 + d] : 0.f;
        *(_Float16*)(L + L_RET + d * 32 + ((c * 2) ^ SWA(d))) = (_Float16)v;
    }
}

template <bool STATS>
__device__ __forceinline__ void build_emb(unsigned char* L, int w, int l15, int g4, float* s) {
    int at = w;
    int arow = at * 16 + l15;
    int aoff = arow * 32 + ((g4 * 8) ^ SWA(arow));
    h4 aq = *(const h4*)(L + L_AQ + aoff);
    h4 ak = *(const h4*)(L + L_AK + aoff);
    int abase = at * 16 + g4 * 4;
    #pragma unroll
    for (int m = 0; m < 9; ++m) {
        int drow = (at + m) * 16 + l15;
        h4 bf = *(const h4*)(L + L_RET + drow * 32 + ((g4 * 8) ^ SWA(drow)));
        f4 z = {0.f, 0.f, 0.f, 0.f};
        f4 dq = __builtin_amdgcn_mfma_f32_16x16x16f16(aq, bf, z, 0, 0, 0);
        f4 dk = __builtin_amdgcn_mfma_f32_16x16x16f16(ak, bf, z, 0, 0, 0);
        #pragma unroll
        for (int r = 0; r < 4; ++r) {
            int a = abase + r;
            int b = 127 + a - drow;
            bool ok = (m == 0 || m == 8) ? (b >= 0 && b < 128) : true;
            if (ok) {
                int off = b * 256 + ((a * 2) ^ ((b & 7) << 4));
                *(_Float16*)(L + L_QEA + off) = (_Float16)dq[r];
                *(_Float16*)(L + L_KEB + off) = (_Float16)dk[r];
                if (STATS) {
                    s[0] += dq[r]; s[1] += dq[r] * dq[r];
                    s[2] += dk[r]; s[3] += dk[r] * dk[r];
                }
            }
        }
    }
}

__device__ __forceinline__ void qk_mfma(unsigned char* L, int i0, int l15, int g4, f4 acc[8]) {
    h8 af[4];
    #pragma unroll
    for (int ks = 0; ks < 4; ++ks) {
        int row = i0 + l15;
        af[ks] = *(const h8*)(L + L_QEA + row * 256 + ((ks * 64 + g4 * 16) ^ ((row & 7) << 4)));
    }
    #pragma unroll
    for (int tj = 0; tj < 8; ++tj) {
        h8 bf[4];
        #pragma unroll
        for (int ks = 0; ks < 4; ++ks) {
            int row = tj * 16 + l15;
            bf[ks] = *(const h8*)(L + L_KEB + row * 256 + ((ks * 64 + g4 * 16) ^ ((row & 7) << 4)));
        }
        f4 c = {0.f, 0.f, 0.f, 0.f};
        #pragma unroll
        for (int ks = 0; ks < 4; ++ks)
            c = __builtin_amdgcn_mfma_f32_16x16x32_f16(af[ks], bf[ks], c, 0, 0, 0);
        acc[tj] = c;
    }
}

// passA (SAMPLED 1/8): 256 blocks
__global__ __launch_bounds__(512, 4) void k_passA(const _Float16* __restrict__ qkv,
                                                  const float* __restrict__ remb,
                                                  const float* __restrict__ cq,
                                                  float* __restrict__ statsim) {
    __shared__ __align__(16) unsigned char L[81920];
    int t = threadIdx.x;
    int lane = t & 63, w = t >> 6;
    int l15 = lane & 15, g4 = lane >> 4;
    int ts = (blockIdx.x & 7) * 32 + (blockIdx.x >> 3);
    int n = (ts >> 2) * 8, g = ts & 3;

    stage_aqk(L, qkv, cq, n, g, t);
    stage_ret(L, remb, 0, t);
    __syncthreads();

    float es[4] = {0.f, 0.f, 0.f, 0.f};
    build_emb<true>(L, w, l15, g4, es);
    __syncthreads();

    float* red = (float*)(L + L_AK);
    #pragma unroll
    for (int k = 0; k < 4; ++k) es[k] = wred(es[k]);
    if (lane == 0) {
        red[w * 4 + 0] = es[0]; red[w * 4 + 1] = es[1];
        red[w * 4 + 2] = es[2]; red[w * 4 + 3] = es[3];
    }

    f4 acc[8];
    qk_mfma(L, w * 16, l15, g4, acc);

    float s = 0.f, ss = 0.f;
    #pragma unroll
    for (int tj = 0; tj < 8; ++tj)
        #pragma unroll
        for (int r = 0; r < 4; ++r) { float x = acc[tj][r]; s += x; ss += x * x; }
    s = wred(s); ss = wred(ss);
    if (lane == 0) { red[32 + w * 2] = s; red[33 + w * 2] = ss; }
    __syncthreads();

    if (t < 6) {
        float v = 0.f;
        int dst;
        if (t == 0)      { for (int k = 0; k < 8; ++k) v += red[32 + 2 * k]; dst = g; }
        else if (t == 1) { for (int k = 0; k < 8; ++k) v += red[33 + 2 * k]; dst = 12 + g; }
        else if (t == 2) { for (int k = 0; k < 8; ++k) v += red[k * 4 + 0];  dst = 4 + g; }
        else if (t == 3) { for (int k = 0; k < 8; ++k) v += red[k * 4 + 1];  dst = 16 + g; }
        else if (t == 4) { for (int k = 0; k < 8; ++k) v += red[k * 4 + 2];  dst = 8 + g; }
        else             { for (int k = 0; k < 8; ++k) v += red[k * 4 + 3];  dst = 20 + g; }
        atomicAdd(&statsim[dst * SP], v);
    }
}

// passB: 5-barrier schedule + slot-trimmed ame + setprio on qk cluster
__global__ __launch_bounds__(512, 4) void k_passB(const _Float16* __restrict__ qkv,
                                                  const float* __restrict__ remb,
                                                  const float* __restrict__ cq,
                                                  const float* __restrict__ statsim,
                                                  const float* __restrict__ simg,
                                                  const float* __restrict__ simb,
                                                  unsigned int* __restrict__ att2,
                                                  float* __restrict__ statout) {
    __shared__ __align__(16) unsigned char L[81920];
    int t = threadIdx.x;
    int lane = t & 63, w = t >> 6;
    int l15 = lane & 15, g4 = lane >> 4;
    int s0 = (blockIdx.x & 7) * 256 + (blockIdx.x >> 3);
    int n = s0 >> 2, g = s0 & 3;

    stage_aqk(L, qkv, cq, n, g, t);
    stage_ret(L, remb, 0, t);
    __syncthreads();                               // B1

    build_emb<false>(L, w, l15, g4, nullptr);
    __syncthreads();                               // B2

    #pragma unroll
    for (int k = 0; k < 4; ++k) {
        int i = t + k * 512;
        int j = i & 127, c = i >> 7;
        int ch = g * 32 + 16 + c;
        float v = cq[ch] * (float)qkv[n * 16384 + ch * 128 + j] + cq[128 + ch];
        *(_Float16*)(L + L_V + c * 256 + ((j * 2) ^ ((c & 7) << 4))) = (_Float16)v;
    }
    #pragma unroll
    for (int k = 0; k < 8; ++k) {
        int i = t + k * 512;
        int d = i & 255, c = i >> 8;
        float v = (d < 255) ? remb[(16 + c) * 255 + d] : 0.f;
        *(_Float16*)(L + L_RET + c * 512 + ((d * 2) ^ ((c & 7) << 4))) = (_Float16)v;
    }

    int i0 = w * 16;
    f4 acc[8];
    __builtin_amdgcn_s_setprio(1);
    qk_mfma(L, i0, l15, g4, acc);
    __builtin_amdgcn_s_setprio(0);

    float Aqk, Aqe, Ake, Cst = 0.f;
    {
        float A3[3];
        #pragma unroll
        for (int k = 0; k < 3; ++k) {
            int ch = k * 4 + g;
            float mean = statsim[ch * SP] * SIM_CNT_INV;
            float var  = statsim[(12 + ch) * SP] * SIM_CNT_INV - mean * mean;
            float A = simg[ch] * rsqrtf(var + EPS);
            A3[k] = A;
            Cst += simb[ch] - mean * A;
        }
        Aqk = A3[0]; Aqe = A3[1]; Ake = A3[2];
    }
    int ib = (i0 + g4 * 4) * 2;
    #pragma unroll
    for (int tj = 0; tj < 8; ++tj) {
        int j = tj * 16 + l15;
        h4 q4 = *(const h4*)(L + L_QEA + j * 256 + (ib ^ ((j & 7) << 4)));
        h4 k4 = *(const h4*)(L + L_KEB + j * 256 + (ib ^ ((j & 7) << 4)));
        #pragma unroll
        for (int r = 0; r < 4; ++r)
            acc[tj][r] = Aqk * acc[tj][r] + Aqe * (float)q4[r] + Ake * (float)k4[r] + Cst;
    }

    float inv4[4];
    #pragma unroll
    for (int r = 0; r < 4; ++r) {
        float m = acc[0][r];
        #pragma unroll
        for (int tj = 1; tj < 8; ++tj) m = fmaxf(m, acc[tj][r]);
        #pragma unroll
        for (int msk = 1; msk < 16; msk <<= 1) m = fmaxf(m, __shfl_xor(m, msk, 64));
        float s = 0.f;
        #pragma unroll
        for (int tj = 0; tj < 8; ++tj) {
            float e = __expf(acc[tj][r] - m);
            acc[tj][r] = e; s += e;
        }
        #pragma unroll
        for (int msk = 1; msk < 16; msk <<= 1) s += __shfl_xor(s, msk, 64);
        inv4[r] = 1.f / s;
    }

    _Float16 ph[4][8];
    #pragma unroll
    for (int r = 0; r < 4; ++r)
        #pragma unroll
        for (int tj = 0; tj < 8; ++tj)
            ph[r][tj] = (_Float16)(acc[tj][r] * inv4[r]);
    __syncthreads();                               // B3

    int lo = w >> 1;
    int lo2 = (w >> 2) << 1;

    #pragma unroll
    for (int r = 0; r < 4; ++r) {
        int i = i0 + g4 * 4 + r;
        int swz = (i & 7) << 4;
        #pragma unroll
        for (int tj = 0; tj < 8; ++tj) {
            int j = tj * 16 + l15;
            *(_Float16*)(L + L_QEA + i * 256 + ((j * 2) ^ swz)) = ph[r][tj];
        }
    }
    if (w >= 4) {
        #pragma unroll
        for (int u = 0; u < 6; ++u) {
            u4 zz = {0u, 0u, 0u, 0u};
            *(u4*)(L + w * 8192 + (lane >> 2) * 512 + lo2 * 64 + ((u * 4 + (lane & 3)) << 4)) = zz;
        }
        #pragma unroll
        for (int r = 0; r < 4; ++r) {
            int i = i0 + g4 * 4 + r;
            int swz = (i & 7) << 4;
            #pragma unroll
            for (int tj = 0; tj < 8; ++tj) {
                int j = tj * 16 + l15;
                int d = 127 + i - j;
                *(_Float16*)(L + i * 512 + ((d * 2) ^ swz)) = ph[r][tj];
            }
        }
    }
    // no barrier: am reads only own-wave P rows

    h8 vf[4];
    #pragma unroll
    for (int ks = 0; ks < 4; ++ks)
        vf[ks] = *(const h8*)(L + L_V + l15 * 256 + ((ks * 64 + g4 * 16) ^ ((l15 & 7) << 4)));
    int row = i0 + l15;
    int sw = (row & 7) << 4;
    f4 cam = {0.f, 0.f, 0.f, 0.f};
    #pragma unroll
    for (int ks = 0; ks < 4; ++ks) {
        h8 pf = *(const h8*)(L + L_QEA + row * 256 + ((ks * 64 + g4 * 16) ^ sw));
        cam = __builtin_amdgcn_mfma_f32_16x16x32_f16(vf[ks], pf, cam, 0, 0, 0);
    }
    __syncthreads();   // B4

    if (w < 4) {
        #pragma unroll
        for (int u = 0; u < 6; ++u) {
            u4 zz = {0u, 0u, 0u, 0u};
            *(u4*)(L + w * 8192 + (lane >> 2) * 512 + lo2 * 64 + ((u * 4 + (lane & 3)) << 4)) = zz;
        }
        #pragma unroll
        for (int r = 0; r < 4; ++r) {
            int i = i0 + g4 * 4 + r;
            int swz = (i & 7) << 4;
            #pragma unroll
            for (int tj = 0; tj < 8; ++tj) {
                int j = tj * 16 + l15;
                int d = 127 + i - j;
                *(_Float16*)(L + i * 512 + ((d * 2) ^ swz)) = ph[r][tj];
            }
        }
    }
    // no barrier: ame reads only own-wave Pd rows

    h8 vef[5];
    #pragma unroll
    for (int u = 0; u < 5; ++u) {
        int ks = lo + u;
        vef[u] = *(const h8*)(L + L_RET + l15 * 512 + ((ks * 64 + g4 * 16) ^ ((l15 & 7) << 4)));
    }
    f4 cae = {0.f, 0.f, 0.f, 0.f};
    #pragma unroll
    for (int u = 0; u < 5; ++u) {
        int ks = lo + u;
        h8 phf = *(const h8*)(L + row * 512 + ((ks * 64 + g4 * 16) ^ sw));
        cae = __builtin_amdgcn_mfma_f32_16x16x32_f16(vef[u], phf, cae, 0, 0, 0);
    }

    unsigned int* attL = (unsigned int*)(L + L_V);
    int i = i0 + l15;
    #pragma unroll
    for (int r = 0; r < 4; ++r) {
        union { _Float16 h[2]; unsigned int u; } pk;
        pk.h[0] = (_Float16)cam[r];
        pk.h[1] = (_Float16)cae[r];
        attL[(g4 * 4 + r) * 128 + i] = pk.u;
    }

    float* sredW = (float*)(L + w * 8192);
    #pragma unroll
    for (int r = 0; r < 4; ++r) {
        float sa = cam[r], qa = cam[r] * cam[r];
        float se = cae[r], qe = cae[r] * cae[r];
        #pragma unroll
        for (int msk = 1; msk < 16; msk <<= 1) {
            sa += __shfl_xor(sa, msk, 64); qa += __shfl_xor(qa, msk, 64);
            se += __shfl_xor(se, msk, 64); qe += __shfl_xor(qe, msk, 64);
        }
        if (l15 == 0) {
            int base = g4 * 16 + r * 4;
            sredW[base + 0] = sa; sredW[base + 1] = qa;
            sredW[base + 2] = se; sredW[base + 3] = qe;
        }
    }
    __syncthreads();                               // B5

    unsigned int* ab = att2 + n * 8192 + g * 2048;
    *(u4*)(ab + t * 4) = *(const u4*)(attL + t * 4);

    if (t < 64) {
        int lc = t & 31, stat = t >> 5;
        int c = lc >> 1, s = lc & 1;
        int gg4 = c >> 2, r = c & 3;
        float v = 0.f;
        #pragma unroll
        for (int ww = 0; ww < 8; ++ww)
            v += ((const float*)L)[ww * 2048 + gg4 * 16 + r * 4 + 2 * s + stat];
        atomicAdd(&statout[(stat * 128 + g * 32 + lc) * SP], v);
    }
}

// axial0 finish
__global__ __launch_bounds__(256) void k_finish0(const unsigned int* __restrict__ att2,
                                                 const float* __restrict__ statout,
                                                 const float* __restrict__ og,
                                                 const float* __restrict__ ob,
                                                 float* __restrict__ t2) {
    __shared__ float tile[8][32][33];
    __shared__ float cf[256];
    int t = threadIdx.x;
    if (t < 128) {
        float mean = statout[t * SP] * (1.f / 65536.f);
        float var  = statout[(128 + t) * SP] * (1.f / 65536.f) - mean * mean;
        float A = og[t] * rsqrtf(var + EPS);
        cf[t] = A;
        cf[128 + t] = ob[t] - mean * A;
    }
    __syncthreads();
    int bid = blockIdx.x;
    int wt = bid & 3, ht = (bid >> 2) & 3, cg = (bid >> 4) & 7, b = bid >> 7;
    for (int i = t; i < 8192; i += 256) {
        int h = i & 31, w = (i >> 5) & 31, cl = i >> 10;
        int c_out = cg * 8 + cl;
        int chg = (c_out >> 4) * 32 + (c_out & 15) * 2;
        int p = chg >> 1;
        union { unsigned int u; _Float16 h2[2]; } pk;
        pk.u = att2[((b * 128 + wt * 32 + w) * 64 + p) * 128 + ht * 32 + h];
        tile[cl][w][h] = cf[chg] * (float)pk.h2[0] + cf[128 + chg]
                       + cf[chg + 1] * (float)pk.h2[1] + cf[129 + chg];
    }
    __syncthreads();
    for (int i = t; i < 8192; i += 256) {
        int w = i & 31, h = (i >> 5) & 31, cl = i >> 10;
        t2[((b * 64 + cg * 8 + cl) * 128 + ht * 32 + h) * 128 + wt * 32 + w] = tile[cl][w][h];
    }
}

// conv2 fused, 4-wave version: xcs LDS stage, each wave owns 16 o-channels
__global__ __launch_bounds__(256) void k_conv2f(const unsigned int* __restrict__ att2,
                                                const float* __restrict__ statout,
                                                const float* __restrict__ og,
                                                const float* __restrict__ ob,
                                                const float* __restrict__ w,
                                                float* __restrict__ out,
                                                float* __restrict__ statc2) {
    __shared__ float ws_[4096];
    __shared__ float cf[4][64];
    __shared__ float xcs[64][64];   // [c][px]
    int t = threadIdx.x;
    int lane = t & 63, wv = t >> 6;
    for (int i = t; i < 4096; i += 256) ws_[i] = w[i];
    if (t < 64) {
        int chg = (t >> 4) * 32 + (t & 15) * 2;
        float m0 = statout[chg * SP] * (1.f / 65536.f);
        float v0 = statout[(128 + chg) * SP] * (1.f / 65536.f) - m0 * m0;
        float A0 = og[chg] * rsqrtf(v0 + EPS);
        cf[0][t] = A0; cf[1][t] = ob[chg] - m0 * A0;
        float m1 = statout[(chg + 1) * SP] * (1.f / 65536.f);
        float v1 = statout[(129 + chg) * SP] * (1.f / 65536.f) - m1 * m1;
        float A1 = og[chg + 1] * rsqrtf(v1 + EPS);
        cf[2][t] = A1; cf[3][t] = ob[chg + 1] - m1 * A1;
    }
    __syncthreads();
    int p0 = blockIdx.x * 64;                 // block = one (b, y) row, px = x
    int b = p0 >> 12;
    int y = (p0 & 4095) >> 6;
    const unsigned int* aprow = att2 + (b * 128 + 2 * y) * 8192;
    // stage xcs[c][px]: 4096 entries / 256 threads = 16 each
    #pragma unroll
    for (int k = 0; k < 16; ++k) {
        int e = t + k * 256;
        int px = e & 63, c = e >> 6;
        const unsigned int* q = aprow + c * 128 + 2 * px;
        union { unsigned int u; _Float16 h2[2]; } a0, a1, a2, a3;
        a0.u = q[0]; a1.u = q[1]; a2.u = q[8192]; a3.u = q[8193];
        float s0 = (float)a0.h2[0] + (float)a1.h2[0] + (float)a2.h2[0] + (float)a3.h2[0];
        float s1 = (float)a0.h2[1] + (float)a1.h2[1] + (float)a2.h2[1] + (float)a3.h2[1];
        xcs[c][px] = 0.25f * (cf[0][c] * s0 + cf[2][c] * s1) + cf[1][c] + cf[3][c];
    }
    __syncthreads();
    int yx = (p0 + lane) & 4095;
    float acc[16];
    #pragma unroll
    for (int u = 0; u < 16; ++u) acc[u] = 0.f;
    for (int c = 0; c < 64; ++c) {
        float xv = xcs[c][lane];
        #pragma unroll
        for (int u = 0; u < 16; ++u)
            acc[u] += ws_[(wv * 16 + u) * 64 + c] * xv;
    }
    float* ob_ = out + b * 262144 + yx;
    #pragma unroll
    for (int u = 0; u < 16; ++u) {
        int o = wv * 16 + u;
        ob_[o * 4096] = acc[u];
        float s = wred(acc[u]), ss = wred(acc[u] * acc[u]);
        if (lane == 0) {
            atomicAdd(&statc2[o * SP], s);
            atomicAdd(&statc2[(64 + o) * SP], ss);
        }
    }
}

// final: cbn2 + residual + prelu, 4x vectorized
__global__ __launch_bounds__(256) void k_final(const float* __restrict__ c2out,
                                               const float* __restrict__ input,
                                               const float* __restrict__ ws,
                                               const float* __restrict__ g2,
                                               const float* __restrict__ b2,
                                               const float* __restrict__ prelu2,
                                               float* __restrict__ out) {
    int q = blockIdx.x * 256 + threadIdx.x;
    int x4 = (q & 15) << 2, y = (q >> 4) & 63, o = (q >> 10) & 63, b = q >> 16;
    float mean = ws[WS_STAT_C2 + o * SP] * (1.f / 16384.f);
    float var  = ws[WS_STAT_C2 + (64 + o) * SP] * (1.f / 16384.f) - mean * mean;
    float ab = g2[o] * rsqrtf(var + EPS);
    float sc = ws[WS_SB2 + o], bi = ws[WS_SB2 + 64 + o];
    float A = sc * ab;
    float B = sc * (b2[o] - mean * ab) + bi;
    float slope = *prelu2;
    int base = ((b * 64 + o) * 64 + y) * 64 + x4;
    float4 c = *(const float4*)&c2out[base];
    const float* ip = input + ((b * 64 + o) * 128 + 2 * y) * 128 + 2 * x4;
    float4 r0a = *(const float4*)&ip[0];
    float4 r0b = *(const float4*)&ip[4];
    float4 r1a = *(const float4*)&ip[128];
    float4 r1b = *(const float4*)&ip[132];
    float4 r;
    float v0 = A * c.x + B + 0.25f * (r0a.x + r0a.y + r1a.x + r1a.y);
    float v1 = A * c.y + B + 0.25f * (r0a.z + r0a.w + r1a.z + r1a.w);
    float v2 = A * c.z + B + 0.25f * (r0b.x + r0b.y + r1b.x + r1b.y);
    float v3 = A * c.w + B + 0.25f * (r0b.z + r0b.w + r1b.z + r1b.w);
    r.x = v0 >= 0.f ? v0 : slope * v0;
    r.y = v1 >= 0.f ? v1 : slope * v1;
    r.z = v2 >= 0.f ? v2 : slope * v2;
    r.w = v3 >= 0.f ? v3 : slope * v3;
    *(float4*)&out[base] = r;
}

extern "C" void kernel_launch(void* const* d_in, const int* in_sizes, int n_in,
                              void* d_out, int out_size, void* d_ws, size_t ws_size,
                              hipStream_t stream) {
    const float* input    = (const float*)d_in[0];
    const float* latent   = (const float*)d_in[1];
    const float* w_in     = (const float*)d_in[2];
    const float* cbn1_g   = (const float*)d_in[3];
    const float* cbn1_b   = (const float*)d_in[4];
    const float* cbn1_lin = (const float*)d_in[5];
    const float* prelu1   = (const float*)d_in[6];
    const float* ax_qkv_w[2] = {(const float*)d_in[7],  (const float*)d_in[15]};
    const float* ax_qkv_g[2] = {(const float*)d_in[8],  (const float*)d_in[16]};
    const float* ax_qkv_b[2] = {(const float*)d_in[9],  (const float*)d_in[17]};
    const float* ax_sim_g[2] = {(const float*)d_in[10], (const float*)d_in[18]};
    const float* ax_sim_b[2] = {(const float*)d_in[11], (const float*)d_in[19]};
    const float* ax_rel[2]   = {(const float*)d_in[12], (const float*)d_in[20]};
    const float* ax_out_g[2] = {(const float*)d_in[13], (const float*)d_in[21]};
    const float* ax_out_b[2] = {(const float*)d_in[14], (const float*)d_in[22]};
    const float* w_out    = (const float*)d_in[23];
    const float* cbn2_g   = (const float*)d_in[24];
    const float* cbn2_b   = (const float*)d_in[25];
    const float* cbn2_lin = (const float*)d_in[26];
    const float* prelu2   = (const float*)d_in[27];

    float* ws    = (float*)d_ws;
    float* out0  = ws + WS_R1;
    float* t1t   = ws + WS_R1 + 4194304;
    unsigned int* att2 = (unsigned int*)(ws + WS_R1);
    _Float16* qkvh = (_Float16*)(ws + WS_R2);
    float* t23   = ws + WS_R3;
    float* c2o   = ws + WS_R3;
    float* dst   = (float*)d_out;

    k_prep0<<<1, 256, 0, stream>>>(cbn1_lin, cbn2_lin, latent, ws);
    k_conv1<<<512, 256, 0, stream>>>(input, w_in, out0, ws + WS_STAT_C1);
    k_t1t<<<4096, 256, 0, stream>>>(out0, t1t, ws, cbn1_g, cbn1_b, prelu1);

    // axial 0 (n = b*128 + w, a = h)
    k_qkvm<<<512, 256, 0, stream>>>(t1t, ax_qkv_w[0], qkvh, ws + WS_STAT_QKV0,
                                    1048576, 8192, 128);
    k_coefq<<<1, 128, 0, stream>>>(ws + WS_STAT_QKV0, ax_qkv_g[0], ax_qkv_b[0], ws + WS_COEFQ0);
    k_passA<<<256, 512, 0, stream>>>(qkvh, ax_rel[0], ws + WS_COEFQ0, ws + WS_STAT_SIM0);
    k_passB<<<2048, 512, 0, stream>>>(qkvh, ax_rel[0], ws + WS_COEFQ0, ws + WS_STAT_SIM0,
                                      ax_sim_g[0], ax_sim_b[0], att2, ws + WS_STAT_OUT0);
    k_finish0<<<512, 256, 0, stream>>>(att2, ws + WS_STAT_OUT0, ax_out_g[0], ax_out_b[0], t23);

    // axial 1 (n = b*128 + h, a = w)
    k_qkvm<<<512, 256, 0, stream>>>(t23, ax_qkv_w[1], qkvh, ws + WS_STAT_QKV1,
                                    1048576, 128, 16384);
    k_coefq<<<1, 128, 0, stream>>>(ws + WS_STAT_QKV1, ax_qkv_g[1], ax_qkv_b[1], ws + WS_COEFQ1);
    k_passA<<<256, 512, 0, stream>>>(qkvh, ax_rel[1], ws + WS_COEFQ1, ws + WS_STAT_SIM1);
    k_passB<<<2048, 512, 0, stream>>>(qkvh, ax_rel[1], ws + WS_COEFQ1, ws + WS_STAT_SIM1,
                                      ax_sim_g[1], ax_sim_b[1], att2, ws + WS_STAT_OUT1);

    // tail
    k_conv2f<<<256, 256, 0, stream>>>(att2, ws + WS_STAT_OUT1, ax_out_g[1], ax_out_b[1],
                                      w_out, c2o, ws + WS_STAT_C2);
    k_final<<<1024, 256, 0, stream>>>(c2o, input, ws, cbn2_g, cbn2_b, prelu2, dst);
}